// Round 4
// baseline (43280.783 us; speedup 1.0000x reference)
//
#include <hip/hip_runtime.h>
#include <hip/hip_bf16.h>

namespace {

constexpr int B_  = 128;
constexpr int TL  = 50, CL = 200, NNODE = 250;
constexpr int H_  = 256, D_ = 512;

// ---------------- generic fp32 tiled GEMM ----------------
struct GemmArgs {
  const float* A; const int* idx; const float* B; const float* bias; const float* Res;
  void* C;
  long aStride, bStride, biasStride, cStride, rStride;
  int M, N, K, lda, ldb, ldc;
};

constexpr int GBM = 128, GBN = 128, GBK = 32;

// C[z] = A[z] @ op(B[z]) (+bias | +res,relu).  BNT: B is N x K row-major (dot along K).
template<bool GATHER, bool BNT, bool OBF16, int EPI>  // EPI 0=none 1=+bias 2=+res,relu
__global__ __launch_bounds__(256) void gemm_k(GemmArgs g) {
  __shared__ float As[GBK][GBM + 4];
  __shared__ float Bs[GBK][GBN + 4];
  const int z  = blockIdx.z;
  const int m0 = blockIdx.x * GBM;
  const int n0 = blockIdx.y * GBN;
  const int tid = threadIdx.x;
  const int tx = tid & 15, ty = tid >> 4;
  const float* Abase = GATHER ? g.A : (g.A + (long)z * g.aStride);
  const float* Bbase = g.B + (long)z * g.bStride;
  float acc[8][8];
  #pragma unroll
  for (int i = 0; i < 8; ++i)
    #pragma unroll
    for (int j = 0; j < 8; ++j) acc[i][j] = 0.f;
  const int c8 = tid & 7, r32 = tid >> 3;

  for (int k0 = 0; k0 < g.K; k0 += GBK) {
    const bool ktail = (k0 + GBK > g.K);
    __syncthreads();
    // ---- A tile (M x K row-major, store transposed As[k][m]) ----
    #pragma unroll
    for (int p = 0; p < 4; ++p) {
      int mr = p * 32 + r32;
      int row = m0 + mr;
      float4 v = make_float4(0.f, 0.f, 0.f, 0.f);
      if (row < g.M) {
        long aoff = GATHER ? ((long)g.idx[row] * g.lda) : ((long)row * g.lda);
        const float* src = Abase + aoff + k0 + c8 * 4;
        if (!ktail) v = *(const float4*)src;
        else {
          int kb = k0 + c8 * 4;
          if (kb + 0 < g.K) v.x = src[0];
          if (kb + 1 < g.K) v.y = src[1];
          if (kb + 2 < g.K) v.z = src[2];
          if (kb + 3 < g.K) v.w = src[3];
        }
      }
      As[c8 * 4 + 0][mr] = v.x; As[c8 * 4 + 1][mr] = v.y;
      As[c8 * 4 + 2][mr] = v.z; As[c8 * 4 + 3][mr] = v.w;
    }
    // ---- B tile ----
    if (BNT) {
      #pragma unroll
      for (int p = 0; p < 4; ++p) {
        int nr = p * 32 + r32;
        int col = n0 + nr;
        float4 v = make_float4(0.f, 0.f, 0.f, 0.f);
        if (col < g.N) {
          const float* src = Bbase + (long)col * g.ldb + k0 + c8 * 4;
          if (!ktail) v = *(const float4*)src;
          else {
            int kb = k0 + c8 * 4;
            if (kb + 0 < g.K) v.x = src[0];
            if (kb + 1 < g.K) v.y = src[1];
            if (kb + 2 < g.K) v.z = src[2];
            if (kb + 3 < g.K) v.w = src[3];
          }
        }
        Bs[c8 * 4 + 0][nr] = v.x; Bs[c8 * 4 + 1][nr] = v.y;
        Bs[c8 * 4 + 2][nr] = v.z; Bs[c8 * 4 + 3][nr] = v.w;
      }
    } else {
      const int c32 = tid & 31, r8 = tid >> 5;
      #pragma unroll
      for (int p = 0; p < 4; ++p) {
        int kr = p * 8 + r8;
        int kg = k0 + kr;
        float4 v = make_float4(0.f, 0.f, 0.f, 0.f);
        int col = n0 + c32 * 4;
        if (kg < g.K) {
          const float* src = Bbase + (long)kg * g.ldb + col;
          if (col + 3 < g.N) v = *(const float4*)src;
          else {
            if (col + 0 < g.N) v.x = src[0];
            if (col + 1 < g.N) v.y = src[1];
            if (col + 2 < g.N) v.z = src[2];
            if (col + 3 < g.N) v.w = src[3];
          }
        }
        *(float4*)&Bs[kr][c32 * 4] = v;
      }
    }
    __syncthreads();
    #pragma unroll 8
    for (int kk = 0; kk < GBK; ++kk) {
      float4 a0 = *(const float4*)&As[kk][ty * 8];
      float4 a1 = *(const float4*)&As[kk][ty * 8 + 4];
      float4 b0 = *(const float4*)&Bs[kk][tx * 8];
      float4 b1 = *(const float4*)&Bs[kk][tx * 8 + 4];
      float av[8] = {a0.x, a0.y, a0.z, a0.w, a1.x, a1.y, a1.z, a1.w};
      float bv[8] = {b0.x, b0.y, b0.z, b0.w, b1.x, b1.y, b1.z, b1.w};
      #pragma unroll
      for (int i = 0; i < 8; ++i)
        #pragma unroll
        for (int j = 0; j < 8; ++j)
          acc[i][j] = fmaf(av[i], bv[j], acc[i][j]);
    }
  }
  // ---- epilogue ----
  #pragma unroll
  for (int i = 0; i < 8; ++i) {
    int row = m0 + ty * 8 + i;
    if (row < g.M) {
      long cbase = (long)z * g.cStride + (long)row * g.ldc;
      #pragma unroll
      for (int j = 0; j < 8; ++j) {
        int col = n0 + tx * 8 + j;
        if (col < g.N) {
          float v = acc[i][j];
          if (EPI == 1) v += g.bias[(long)z * g.biasStride + col];
          if (EPI == 2) {
            v += g.Res[(long)z * g.rStride + (long)row * g.ldc + col];
            v = fmaxf(v, 0.f);
          }
          if (OBF16) ((__hip_bfloat16*)g.C)[cbase + col] = __float2bfloat16(v);
          else       ((float*)g.C)[cbase + col] = v;
        }
      }
    }
  }
}

// ---------------- Whh -> bf16 conversion (all 8 dir-matrices) ----------------
__global__ __launch_bounds__(256) void convwhh_k(const float* tt, const float* tc,
                                                 const float* st, const float* sc,
                                                 __hip_bfloat16* o) {
  long i = (long)blockIdx.x * blockDim.x + threadIdx.x;
  const long per = 768L * 256;
  if (i >= 8 * per) return;
  int z = (int)(i / per);
  long rem = i - (long)z * per;
  const float* src = (z < 2) ? tt : (z < 4) ? tc : (z < 6) ? st : sc;
  o[i] = __float2bfloat16(src[(long)(z & 1) * per + rem]);
}

// ---------------- GRU recurrence (one side: target + claim, 2 dirs) ---------
// grid (64, 1, 4), block 768 = 12 waves. z = sq*2 + dir. Block owns RBC batch
// rows for all 768 gate-outputs: thread o owns gate g=o>>8, unit u=o&255, and
// keeps its 256-wide bf16 Whh row in 128 packed VGPRs (loaded once). h is fp32
// in LDS, read wave-uniform (broadcast). Gates recombined via LDS exchange.
struct RecArgs {
  const __hip_bfloat16* whh4;     // side base: [4][768][256]  (z = sq*2+dir)
  const __hip_bfloat16* gi_t;     // [2][B*TL][768]
  const __hip_bfloat16* gi_c;     // [2][B*CL][768]
  const float* bhh_t;             // [2][768]
  const float* bhh_c;             // [2][768]
  float* node;                    // [B][250][512]
};

constexpr int RBC = 2;

__global__ __launch_bounds__(768, 3) void gru_rec_k(RecArgs a) {
  __shared__ float hs[RBC][256];
  __shared__ float exch[768][RBC];
  __shared__ float ginS[256][RBC];
  const int z = blockIdx.z;
  const int sq = z >> 1, dir = z & 1;
  const int T = sq ? CL : TL;
  const int toff = sq ? TL : 0;
  const __hip_bfloat16* gi = (sq ? a.gi_c : a.gi_t) + (long)dir * B_ * T * 768;
  const float* bhh = (sq ? a.bhh_c : a.bhh_t) + dir * 768;
  const int o = threadIdx.x;          // 0..767: gate g = o>>8, unit u = o&255
  const int b0 = blockIdx.x * RBC;
  const float bb = bhh[o];
  // ---- Whh row resident in registers (128 packed bf16 pairs) ----
  const __hip_bfloat16* wrow = a.whh4 + ((long)z * 768 + o) * 256;
  unsigned wreg[128];
  #pragma unroll
  for (int i = 0; i < 32; ++i) {
    uint4 v = *(const uint4*)(wrow + i * 8);
    wreg[i * 4 + 0] = v.x; wreg[i * 4 + 1] = v.y;
    wreg[i * 4 + 2] = v.z; wreg[i * 4 + 3] = v.w;
  }
  if (o < 256) {
    #pragma unroll
    for (int r = 0; r < RBC; ++r) hs[r][o] = 0.f;
  }
  __syncthreads();

  for (int t = 0; t < T; ++t) {
    const int tt = dir ? (T - 1 - t) : t;
    // prefetch gi for this step (used only after the FMA loop)
    float gv[RBC];
    #pragma unroll
    for (int r = 0; r < RBC; ++r)
      gv[r] = __bfloat162float(gi[((long)(b0 + r) * T + tt) * 768 + o]);
    float acc[RBC];
    #pragma unroll
    for (int r = 0; r < RBC; ++r) acc[r] = 0.f;
    #pragma unroll
    for (int kq = 0; kq < 64; ++kq) {
      unsigned w0 = wreg[kq * 2], w1 = wreg[kq * 2 + 1];
      union { unsigned u; float f; } e0, e1, e2, e3;
      e0.u = w0 << 16; e1.u = w0 & 0xFFFF0000u;
      e2.u = w1 << 16; e3.u = w1 & 0xFFFF0000u;
      #pragma unroll
      for (int r = 0; r < RBC; ++r) {
        float4 hv = *(const float4*)&hs[r][kq * 4];
        acc[r] = fmaf(e0.f, hv.x, fmaf(e1.f, hv.y,
                 fmaf(e2.f, hv.z, fmaf(e3.f, hv.w, acc[r]))));
      }
    }
    // ---- gate exchange ----
    const int g = o >> 8, u = o & 255;
    #pragma unroll
    for (int r = 0; r < RBC; ++r) {
      if (g == 2) { exch[o][r] = acc[r] + bb; ginS[u][r] = gv[r]; }
      else          exch[o][r] = gv[r] + acc[r] + bb;
    }
    __syncthreads();   // exch ready; all hs reads of this step done
    if (o < 256) {
      #pragma unroll
      for (int r = 0; r < RBC; ++r) {
        float rr = 1.f / (1.f + expf(-exch[o][r]));
        float zz = 1.f / (1.f + expf(-exch[256 + o][r]));
        float nn = tanhf(ginS[o][r] + rr * exch[512 + o][r]);
        float hold = hs[r][o];
        float hnew = (1.f - zz) * nn + zz * hold;
        hs[r][o] = hnew;
        a.node[((long)(b0 + r) * NNODE + toff + tt) * D_ + dir * H_ + o] = hnew;
      }
    }
    __syncthreads();   // hs updated before next step's reads
  }
}

// ---------------- attention over claims (one side) ----------------
__global__ __launch_bounds__(256) void attn_k(const float* node, float* w) {
  int b = blockIdx.x;
  __shared__ float tl[512];
  __shared__ float sc[CL];
  int tid = threadIdx.x;
  tl[tid]       = node[((long)b * NNODE + (TL - 1)) * D_ + tid];
  tl[tid + 256] = node[((long)b * NNODE + (TL - 1)) * D_ + 256 + tid];
  __syncthreads();
  int wid = tid >> 6, lane = tid & 63;
  for (int c = wid; c < CL; c += 4) {
    const float* row = node + ((long)b * NNODE + TL + c) * D_;
    float acc = 0.f;
    for (int d = lane; d < D_; d += 64) acc += row[d] * tl[d];
    #pragma unroll
    for (int o = 32; o; o >>= 1) acc += __shfl_xor(acc, o, 64);
    if (lane == 0) sc[c] = acc;
  }
  __syncthreads();
  if (wid == 0) {
    float v[4]; float m = -1e30f;
    #pragma unroll
    for (int i = 0; i < 4; ++i) {
      int c = lane + 64 * i;
      v[i] = (c < CL) ? sc[c] : -1e30f;
      m = fmaxf(m, v[i]);
    }
    #pragma unroll
    for (int o = 32; o; o >>= 1) m = fmaxf(m, __shfl_xor(m, o, 64));
    float s = 0.f;
    #pragma unroll
    for (int i = 0; i < 4; ++i) {
      int c = lane + 64 * i;
      v[i] = (c < CL) ? expf(v[i] - m) : 0.f;
      s += v[i];
    }
    #pragma unroll
    for (int o = 32; o; o >>= 1) s += __shfl_xor(s, o, 64);
    float inv = 1.f / s;
    #pragma unroll
    for (int i = 0; i < 4; ++i) {
      int c = lane + 64 * i;
      if (c < CL) w[(long)b * CL + c] = v[i] * inv;
    }
  }
}

// ---------------- row softmax (corr) ----------------
__global__ __launch_bounds__(256) void softmax_k(float* data, int rows, int len, int ld) {
  int row = blockIdx.x * 4 + (threadIdx.x >> 6);
  int lane = threadIdx.x & 63;
  if (row >= rows) return;
  float* p = data + (long)row * ld;
  float v[4]; float m = -1e30f;
  #pragma unroll
  for (int i = 0; i < 4; ++i) {
    int c = lane + i * 64;
    v[i] = (c < len) ? p[c] : -1e30f;
    m = fmaxf(m, v[i]);
  }
  #pragma unroll
  for (int o = 32; o; o >>= 1) m = fmaxf(m, __shfl_xor(m, o, 64));
  float s = 0.f;
  #pragma unroll
  for (int i = 0; i < 4; ++i) {
    int c = lane + i * 64;
    if (c < len) { v[i] = expf(v[i] - m); s += v[i]; }
  }
  #pragma unroll
  for (int o = 32; o; o >>= 1) s += __shfl_xor(s, o, 64);
  float inv = 1.f / s;
  #pragma unroll
  for (int i = 0; i < 4; ++i) {
    int c = lane + i * 64;
    if (c < len) p[c] = v[i] * inv;
  }
}

// ---------------- weighted claim pooling (one side) ----------------
__global__ __launch_bounds__(256) void rep_k(const float* node, const float* w,
                                             float* repSide) {
  int b = blockIdx.x;
  __shared__ float wl[CL];
  int tid = threadIdx.x;
  if (tid < CL) wl[tid] = w[(long)b * CL + tid];
  __syncthreads();
  #pragma unroll
  for (int h = 0; h < 2; ++h) {
    int d = tid + h * 256;
    float acc = 0.f;
    for (int c = 0; c < CL; ++c)
      acc = fmaf(wl[c], node[((long)b * NNODE + TL + c) * D_ + d], acc);
    repSide[(long)b * D_ + d] = acc;
  }
}

// ---------------- final linear ----------------
__global__ __launch_bounds__(256) void final_k(const float* rep, const float* linW,
                                               const float* linb, float* out) {
  int b = blockIdx.x, tid = threadIdx.x;
  float a0 = 0.f, a1 = 0.f, a2 = 0.f;
  for (int d = tid; d < 1024; d += 256) {
    float x = rep[(long)(d >> 9) * (B_ * D_) + (long)b * D_ + (d & 511)];
    a0 = fmaf(x, linW[d], a0);
    a1 = fmaf(x, linW[1024 + d], a1);
    a2 = fmaf(x, linW[2048 + d], a2);
  }
  #pragma unroll
  for (int o = 32; o; o >>= 1) {
    a0 += __shfl_xor(a0, o, 64);
    a1 += __shfl_xor(a1, o, 64);
    a2 += __shfl_xor(a2, o, 64);
  }
  __shared__ float red[3][4];
  int wid = tid >> 6, lane = tid & 63;
  if (lane == 0) { red[0][wid] = a0; red[1][wid] = a1; red[2][wid] = a2; }
  __syncthreads();
  if (tid == 0) {
    out[b * 3 + 0] = red[0][0] + red[0][1] + red[0][2] + red[0][3] + linb[0];
    out[b * 3 + 1] = red[1][0] + red[1][1] + red[1][2] + red[1][3] + linb[1];
    out[b * 3 + 2] = red[2][0] + red[2][1] + red[2][2] + red[2][3] + linb[2];
  }
}

// ---------------- diagnostic: encode ws_size (MB) into out if ws too small ----
__global__ void diag_k(float* out, int n, float v) {
  int i = blockIdx.x * blockDim.x + threadIdx.x;
  if (i < n) out[i] = v;
}

} // namespace

extern "C" void kernel_launch(void* const* d_in, const int* in_sizes, int n_in,
                              void* d_out, int out_size, void* d_ws, size_t ws_size,
                              hipStream_t stream) {
  const int* task_target   = (const int*)d_in[1];
  const int* shared_target = (const int*)d_in[2];
  const int* task_claim    = (const int*)d_in[3];
  const int* shared_claim  = (const int*)d_in[4];
  const float* emb      = (const float*)d_in[9];
  const float* tgt_wih  = (const float*)d_in[10];
  const float* tgt_whh  = (const float*)d_in[11];
  const float* tgt_bih  = (const float*)d_in[12];
  const float* tgt_bhh  = (const float*)d_in[13];
  const float* tgc_wih  = (const float*)d_in[14];
  const float* tgc_whh  = (const float*)d_in[15];
  const float* tgc_bih  = (const float*)d_in[16];
  const float* tgc_bhh  = (const float*)d_in[17];
  const float* sgt_wih  = (const float*)d_in[18];
  const float* sgt_whh  = (const float*)d_in[19];
  const float* sgt_bih  = (const float*)d_in[20];
  const float* sgt_bhh  = (const float*)d_in[21];
  const float* sgc_wih  = (const float*)d_in[22];
  const float* sgc_whh  = (const float*)d_in[23];
  const float* sgc_bih  = (const float*)d_in[24];
  const float* sgc_bhh  = (const float*)d_in[25];
  const float* gcnW_task   = (const float*)d_in[26];
  const float* gcnW_shared = (const float*)d_in[27];
  const float* linW = (const float*)d_in[28];
  const float* linb = (const float*)d_in[29];
  float* out = (float*)d_out;

  // ---- workspace carve-up: two sequential side-phases share one arena ----
  const size_t SZ_WHH   = 8ULL * 768 * 256 * 2;            //   3.1 MB (all 8 dirs)
  const size_t SZ_GI_T  = 2ULL * 6400  * 768 * 2;          //  19.7 MB (per side)
  const size_t SZ_GI_C  = 2ULL * 25600 * 768 * 2;          //  78.6 MB (per side)
  const size_t SZ_TMP   = 128ULL * 250 * 512 * 4;          //  65.5 MB
  const size_t SZ_CORR  = 128ULL * 250 * 256 * 4;          //  32.8 MB
  const size_t SZ_TRANS = 128ULL * 250 * 512 * 4;          //  65.5 MB
  const size_t SZ_ARENA = SZ_TMP + SZ_CORR + SZ_TRANS;     // 163.8 MB >= gi 98.3 MB
  const size_t SZ_NODE  = 128ULL * 250 * 512 * 4;          //  65.5 MB (task then shared)
  const size_t SZ_W     = 128ULL * 200 * 4;
  const size_t SZ_REP   = 2ULL * 128 * 512 * 4;
  const size_t NEED = SZ_WHH + SZ_ARENA + SZ_NODE + 2 * SZ_W + SZ_REP + 4096;

  if (ws_size < NEED) {   // report actual budget (MB) via absmax
    diag_k<<<(out_size + 255) / 256, 256, 0, stream>>>(out, out_size,
                                                       (float)(ws_size >> 20));
    return;
  }

  char* p = (char*)d_ws;
  auto alloc = [&](size_t bytes) { char* r = p; p += (bytes + 255) & ~(size_t)255; return r; };
  __hip_bfloat16* whhbf = (__hip_bfloat16*)alloc(SZ_WHH);
  char* arena = alloc(SZ_ARENA);
  __hip_bfloat16* gi_t = (__hip_bfloat16*)(arena);                 // phase: projections+rec
  __hip_bfloat16* gi_c = (__hip_bfloat16*)(arena + SZ_GI_T);
  float* tmp   = (float*)(arena);                                  // phase: GCN (gi dead)
  float* corr  = (float*)(arena + SZ_TMP);
  float* trans = (float*)(arena + SZ_TMP + SZ_CORR);
  float* node  = (float*)alloc(SZ_NODE);
  float* wT  = (float*)alloc(SZ_W);
  float* wS  = (float*)alloc(SZ_W);
  float* rep = (float*)alloc(SZ_REP);

  // 1) Whh -> bf16 (z order: tgt0,tgt1, tgc0,tgc1, sgt0,sgt1, sgc0,sgc1)
  convwhh_k<<<6144, 256, 0, stream>>>(tgt_whh, tgc_whh, sgt_whh, sgc_whh, whhbf);

  auto projLaunch = [&](const int* idx, const float* wih, const float* bih,
                        __hip_bfloat16* gi, int Mrows) {
    GemmArgs ga{};
    ga.A = emb; ga.idx = idx; ga.B = wih; ga.bias = bih; ga.C = gi;
    ga.aStride = 0; ga.bStride = 768L * 300; ga.biasStride = 768;
    ga.cStride = (long)Mrows * 768; ga.rStride = 0;
    ga.M = Mrows; ga.N = 768; ga.K = 300; ga.lda = 300; ga.ldb = 300; ga.ldc = 768;
    dim3 grid((Mrows + GBM - 1) / GBM, 6, 2);
    gemm_k<true, true, true, 1><<<grid, 256, 0, stream>>>(ga);
  };

  auto runSide = [&](const int* tgtTok, const int* clmTok,
                     const float* wih_t, const float* bih_t, const float* bhh_t,
                     const float* wih_c, const float* bih_c, const float* bhh_c,
                     const __hip_bfloat16* whh4, const float* gcnW,
                     float* w, float* repSide) {
    // projections: gi = emb[tok] @ Wih^T + bih  (bf16 out)
    projLaunch(tgtTok, wih_t, bih_t, gi_t, 6400);
    projLaunch(clmTok, wih_c, bih_c, gi_c, 25600);
    // recurrence: 4 dirs of this side
    RecArgs ra{whh4, gi_t, gi_c, bhh_t, bhh_c, node};
    gru_rec_k<<<dim3(64, 1, 4), 768, 0, stream>>>(ra);
    // stance attention on pre-GCN nodes
    attn_k<<<dim3(128), 256, 0, stream>>>(node, w);
    // GCN 2 layers (scratch aliases dead gi)
    for (int layer = 0; layer < 2; ++layer) {
      const float* in = layer ? (const float*)tmp : (const float*)node;
      float* outp = layer ? node : tmp;
      const float* Wlayer = gcnW + (long)layer * 512 * 512;
      GemmArgs ca{};   // S = node @ node^T
      ca.A = in; ca.B = in; ca.C = corr;
      ca.aStride = 128000; ca.bStride = 128000; ca.cStride = 64000;
      ca.M = 250; ca.N = 250; ca.K = 512; ca.lda = 512; ca.ldb = 512; ca.ldc = 256;
      gemm_k<false, true, false, 0><<<dim3(2, 2, 128), 256, 0, stream>>>(ca);
      softmax_k<<<dim3(8000), 256, 0, stream>>>(corr, 32000, 250, 256);
      GemmArgs ta{};   // trans = node @ W^T
      ta.A = in; ta.B = Wlayer; ta.C = trans;
      ta.aStride = 128000; ta.bStride = 0; ta.cStride = 128000;
      ta.M = 250; ta.N = 512; ta.K = 512; ta.lda = 512; ta.ldb = 512; ta.ldc = 512;
      gemm_k<false, true, false, 0><<<dim3(2, 4, 128), 256, 0, stream>>>(ta);
      GemmArgs aa{};   // out = relu(node + corr @ trans)
      aa.A = corr; aa.B = trans; aa.C = outp; aa.Res = in;
      aa.aStride = 64000; aa.bStride = 128000; aa.cStride = 128000; aa.rStride = 128000;
      aa.M = 250; aa.N = 512; aa.K = 250; aa.lda = 256; aa.ldb = 512; aa.ldc = 512;
      gemm_k<false, false, false, 2><<<dim3(2, 4, 128), 256, 0, stream>>>(aa);
    }
    // attention-weighted claim pooling (post-GCN nodes)
    rep_k<<<dim3(128), 256, 0, stream>>>(node, w, repSide);
  };

  // task side, then shared side (node/arena reused)
  runSide(task_target, task_claim,
          tgt_wih, tgt_bih, tgt_bhh, tgc_wih, tgc_bih, tgc_bhh,
          whhbf, gcnW_task, wT, rep);
  runSide(shared_target, shared_claim,
          sgt_wih, sgt_bih, sgt_bhh, sgc_wih, sgc_bih, sgc_bhh,
          whhbf + 4L * 768 * 256, gcnW_shared, wS, rep + 128L * 512);

  // final linear
  final_k<<<dim3(128), 256, 0, stream>>>(rep, linW, linb, out);
}

// Round 5
// 5414.787 us; speedup vs baseline: 7.9931x; 7.9931x over previous
//
#include <hip/hip_runtime.h>
#include <hip/hip_bf16.h>

namespace {

constexpr int B_  = 128;
constexpr int TL  = 50, CL = 200, NNODE = 250;
constexpr int H_  = 256, D_ = 512;

typedef __attribute__((ext_vector_type(8))) short bf16x8;
typedef __attribute__((ext_vector_type(4))) float f32x4;

__device__ inline float bits2f(unsigned v) { union { unsigned u; float f; } c; c.u = v; return c.f; }
__device__ inline unsigned short bfbits(float x) {
  __hip_bfloat16 b = __float2bfloat16(x);
  return *(unsigned short*)&b;
}

// ---------------- generic fp32 tiled GEMM ----------------
struct GemmArgs {
  const float* A; const int* idx; const float* B; const float* bias; const float* Res;
  void* C;
  long aStride, bStride, biasStride, cStride, rStride;
  int M, N, K, lda, ldb, ldc;
};

constexpr int GBM = 128, GBN = 128, GBK = 32;

template<bool GATHER, bool BNT, bool OBF16, int EPI>  // EPI 0=none 1=+bias 2=+res,relu
__global__ __launch_bounds__(256) void gemm_k(GemmArgs g) {
  __shared__ float As[GBK][GBM + 4];
  __shared__ float Bs[GBK][GBN + 4];
  const int z  = blockIdx.z;
  const int m0 = blockIdx.x * GBM;
  const int n0 = blockIdx.y * GBN;
  const int tid = threadIdx.x;
  const int tx = tid & 15, ty = tid >> 4;
  const float* Abase = GATHER ? g.A : (g.A + (long)z * g.aStride);
  const float* Bbase = g.B + (long)z * g.bStride;
  float acc[8][8];
  #pragma unroll
  for (int i = 0; i < 8; ++i)
    #pragma unroll
    for (int j = 0; j < 8; ++j) acc[i][j] = 0.f;
  const int c8 = tid & 7, r32 = tid >> 3;

  for (int k0 = 0; k0 < g.K; k0 += GBK) {
    const bool ktail = (k0 + GBK > g.K);
    __syncthreads();
    #pragma unroll
    for (int p = 0; p < 4; ++p) {
      int mr = p * 32 + r32;
      int row = m0 + mr;
      float4 v = make_float4(0.f, 0.f, 0.f, 0.f);
      if (row < g.M) {
        long aoff = GATHER ? ((long)g.idx[row] * g.lda) : ((long)row * g.lda);
        const float* src = Abase + aoff + k0 + c8 * 4;
        if (!ktail) v = *(const float4*)src;
        else {
          int kb = k0 + c8 * 4;
          if (kb + 0 < g.K) v.x = src[0];
          if (kb + 1 < g.K) v.y = src[1];
          if (kb + 2 < g.K) v.z = src[2];
          if (kb + 3 < g.K) v.w = src[3];
        }
      }
      As[c8 * 4 + 0][mr] = v.x; As[c8 * 4 + 1][mr] = v.y;
      As[c8 * 4 + 2][mr] = v.z; As[c8 * 4 + 3][mr] = v.w;
    }
    if (BNT) {
      #pragma unroll
      for (int p = 0; p < 4; ++p) {
        int nr = p * 32 + r32;
        int col = n0 + nr;
        float4 v = make_float4(0.f, 0.f, 0.f, 0.f);
        if (col < g.N) {
          const float* src = Bbase + (long)col * g.ldb + k0 + c8 * 4;
          if (!ktail) v = *(const float4*)src;
          else {
            int kb = k0 + c8 * 4;
            if (kb + 0 < g.K) v.x = src[0];
            if (kb + 1 < g.K) v.y = src[1];
            if (kb + 2 < g.K) v.z = src[2];
            if (kb + 3 < g.K) v.w = src[3];
          }
        }
        Bs[c8 * 4 + 0][nr] = v.x; Bs[c8 * 4 + 1][nr] = v.y;
        Bs[c8 * 4 + 2][nr] = v.z; Bs[c8 * 4 + 3][nr] = v.w;
      }
    } else {
      const int c32 = tid & 31, r8 = tid >> 5;
      #pragma unroll
      for (int p = 0; p < 4; ++p) {
        int kr = p * 8 + r8;
        int kg = k0 + kr;
        float4 v = make_float4(0.f, 0.f, 0.f, 0.f);
        int col = n0 + c32 * 4;
        if (kg < g.K) {
          const float* src = Bbase + (long)kg * g.ldb + col;
          if (col + 3 < g.N) v = *(const float4*)src;
          else {
            if (col + 0 < g.N) v.x = src[0];
            if (col + 1 < g.N) v.y = src[1];
            if (col + 2 < g.N) v.z = src[2];
            if (col + 3 < g.N) v.w = src[3];
          }
        }
        *(float4*)&Bs[kr][c32 * 4] = v;
      }
    }
    __syncthreads();
    #pragma unroll 8
    for (int kk = 0; kk < GBK; ++kk) {
      float4 a0 = *(const float4*)&As[kk][ty * 8];
      float4 a1 = *(const float4*)&As[kk][ty * 8 + 4];
      float4 b0 = *(const float4*)&Bs[kk][tx * 8];
      float4 b1 = *(const float4*)&Bs[kk][tx * 8 + 4];
      float av[8] = {a0.x, a0.y, a0.z, a0.w, a1.x, a1.y, a1.z, a1.w};
      float bv[8] = {b0.x, b0.y, b0.z, b0.w, b1.x, b1.y, b1.z, b1.w};
      #pragma unroll
      for (int i = 0; i < 8; ++i)
        #pragma unroll
        for (int j = 0; j < 8; ++j)
          acc[i][j] = fmaf(av[i], bv[j], acc[i][j]);
    }
  }
  #pragma unroll
  for (int i = 0; i < 8; ++i) {
    int row = m0 + ty * 8 + i;
    if (row < g.M) {
      long cbase = (long)z * g.cStride + (long)row * g.ldc;
      #pragma unroll
      for (int j = 0; j < 8; ++j) {
        int col = n0 + tx * 8 + j;
        if (col < g.N) {
          float v = acc[i][j];
          if (EPI == 1) v += g.bias[(long)z * g.biasStride + col];
          if (EPI == 2) {
            v += g.Res[(long)z * g.rStride + (long)row * g.ldc + col];
            v = fmaxf(v, 0.f);
          }
          if (OBF16) ((__hip_bfloat16*)g.C)[cbase + col] = __float2bfloat16(v);
          else       ((float*)g.C)[cbase + col] = v;
        }
      }
    }
  }
}

// ---------------- Whh -> bf16 conversion (all 8 dir-matrices) ----------------
__global__ __launch_bounds__(256) void convwhh_k(const float* tt, const float* tc,
                                                 const float* st, const float* sc,
                                                 __hip_bfloat16* o) {
  long i = (long)blockIdx.x * blockDim.x + threadIdx.x;
  const long per = 768L * 256;
  if (i >= 8 * per) return;
  int z = (int)(i / per);
  long rem = i - (long)z * per;
  const float* src = (z < 2) ? tt : (z < 4) ? tc : (z < 6) ? st : sc;
  o[i] = __float2bfloat16(src[(long)(z & 1) * per + rem]);
}

// ---------------- GRU recurrence: MFMA persistent-RNN ----------------
// grid (8, 1, 4): z = sq*2+dir, blockIdx.x = batch-group (16 rows).
// Block = 512 thr (8 waves, 2/SIMD). Whole Whh (768x256 bf16) lives in
// A-fragments: 192 VGPR/lane. h carried as bf16 hi+lo in swizzled LDS
// (dual-MFMA => ~16-bit mantissa on the recurrent state). Per step:
// 96 MFMA/wave -> gh dump to LDS -> activation (thread owns (batch, 8 units))
// with gi prefetched one step ahead into regs.
struct RecArgs {
  const __hip_bfloat16* whh4;     // side base: [4][768][256]
  const __hip_bfloat16* gi_t;     // [2][B*TL][768]
  const __hip_bfloat16* gi_c;     // [2][B*CL][768]
  const float* bhh_t;             // [2][768]
  const float* bhh_c;             // [2][768]
  float* node;                    // [B][250][512]
};

__global__ __launch_bounds__(512, 2) void gru_rec_k(RecArgs a) {
  __shared__ __align__(16) __hip_bfloat16 ghS[768 * 17];   // [row 0..767][b 0..15]
  __shared__ __align__(16) __hip_bfloat16 hhi[16 * 256];   // [b][k] swizzled
  __shared__ __align__(16) __hip_bfloat16 hlo[16 * 256];
  __shared__ float bhhS[768];
  const int z = blockIdx.z;
  const int sq = z >> 1, dir = z & 1;
  const int T = sq ? CL : TL;
  const int toff = sq ? TL : 0;
  const __hip_bfloat16* gi = (sq ? a.gi_c : a.gi_t) + (long)dir * B_ * T * 768;
  const float* bhh = (sq ? a.bhh_c : a.bhh_t) + dir * 768;
  const __hip_bfloat16* whh = a.whh4 + (long)z * 768 * 256;
  const int b0 = blockIdx.x * 16;
  const int tid = threadIdx.x;
  const int lane = tid & 63, wv = tid >> 6;
  const int ab = tid >> 5, auq = tid & 31;       // activation: batch, unit-octet

  // ---- prologue: A-fragments (whole Whh), h=0, bhh to LDS ----
  bf16x8 Af[6][8];
  #pragma unroll
  for (int ot = 0; ot < 6; ++ot)
    #pragma unroll
    for (int kt = 0; kt < 8; ++kt) {
      int row = wv * 96 + ot * 16 + (lane & 15);
      int col = kt * 32 + (lane >> 4) * 8;
      Af[ot][kt] = *(const bf16x8*)(whh + (long)row * 256 + col);
    }
  *(uint4*)((char*)hhi + tid * 16) = make_uint4(0, 0, 0, 0);
  *(uint4*)((char*)hlo + tid * 16) = make_uint4(0, 0, 0, 0);
  for (int i = tid; i < 768; i += 512) bhhS[i] = bhh[i];

  // gi prefetch for t=0
  long growp = ((long)(b0 + ab) * T + (dir ? T - 1 : 0)) * 768 + auq * 8;
  uint4 g0 = *(const uint4*)(gi + growp);
  uint4 g1 = *(const uint4*)(gi + growp + 256);
  uint4 g2 = *(const uint4*)(gi + growp + 512);
  __syncthreads();

  const int hb = (ab * 512 + auq * 16) ^ ((ab & 7) << 4);  // this thread's h slot

  for (int t = 0; t < T; ++t) {
    const int tt = dir ? (T - 1 - t) : t;
    // ---- MFMA phase: gh = Whh @ (h_hi + h_lo) ----
    f32x4 c[6];
    #pragma unroll
    for (int ot = 0; ot < 6; ++ot) c[ot] = (f32x4){0.f, 0.f, 0.f, 0.f};
    #pragma unroll
    for (int kt = 0; kt < 8; ++kt) {
      int bbyte = (lane & 15) * 512 + kt * 64 + (lane >> 4) * 16;
      int sbyte = bbyte ^ (((lane & 15) & 7) << 4);
      bf16x8 bh = *(const bf16x8*)((const char*)hhi + sbyte);
      bf16x8 bl = *(const bf16x8*)((const char*)hlo + sbyte);
      #pragma unroll
      for (int ot = 0; ot < 6; ++ot) {
        c[ot] = __builtin_amdgcn_mfma_f32_16x16x32_bf16(Af[ot][kt], bh, c[ot], 0, 0, 0);
        c[ot] = __builtin_amdgcn_mfma_f32_16x16x32_bf16(Af[ot][kt], bl, c[ot], 0, 0, 0);
      }
    }
    // dump gh (bf16) : D layout col=lane&15 (batch), row=(lane>>4)*4+r
    #pragma unroll
    for (int ot = 0; ot < 6; ++ot) {
      int row = wv * 96 + ot * 16 + (lane >> 4) * 4;
      #pragma unroll
      for (int r = 0; r < 4; ++r)
        ghS[(row + r) * 17 + (lane & 15)] = __float2bfloat16(c[ot][r]);
    }
    __syncthreads();

    // ---- activation phase ----
    uint4 hh = *(const uint4*)((const char*)hhi + hb);
    uint4 hl = *(const uint4*)((const char*)hlo + hb);
    float hnew[8];
    #pragma unroll
    for (int j = 0; j < 8; ++j) {
      int u = auq * 8 + j;
      float ghr = __bfloat162float(ghS[u * 17 + ab]);
      float ghz = __bfloat162float(ghS[(256 + u) * 17 + ab]);
      float ghn = __bfloat162float(ghS[(512 + u) * 17 + ab]);
      unsigned w0 = (j < 2) ? g0.x : (j < 4) ? g0.y : (j < 6) ? g0.z : g0.w;
      unsigned w1 = (j < 2) ? g1.x : (j < 4) ? g1.y : (j < 6) ? g1.z : g1.w;
      unsigned w2 = (j < 2) ? g2.x : (j < 4) ? g2.y : (j < 6) ? g2.z : g2.w;
      float gir = bits2f((j & 1) ? (w0 & 0xFFFF0000u) : (w0 << 16));
      float giz = bits2f((j & 1) ? (w1 & 0xFFFF0000u) : (w1 << 16));
      float gin = bits2f((j & 1) ? (w2 & 0xFFFF0000u) : (w2 << 16));
      unsigned hw = (j < 2) ? hh.x : (j < 4) ? hh.y : (j < 6) ? hh.z : hh.w;
      unsigned lw = (j < 2) ? hl.x : (j < 4) ? hl.y : (j < 6) ? hl.z : hl.w;
      float hold = bits2f((j & 1) ? (hw & 0xFFFF0000u) : (hw << 16)) +
                   bits2f((j & 1) ? (lw & 0xFFFF0000u) : (lw << 16));
      float rr = 1.f / (1.f + expf(-(gir + ghr + bhhS[u])));
      float zz = 1.f / (1.f + expf(-(giz + ghz + bhhS[256 + u])));
      float nn = tanhf(gin + rr * (ghn + bhhS[512 + u]));
      hnew[j] = (1.f - zz) * nn + zz * hold;
    }
    // prefetch gi for t+1 (in flight across next MFMA phase)
    {
      int tn = (t + 1 < T) ? t + 1 : t;
      int ttn = dir ? (T - 1 - tn) : tn;
      long grow = ((long)(b0 + ab) * T + ttn) * 768 + auq * 8;
      g0 = *(const uint4*)(gi + grow);
      g1 = *(const uint4*)(gi + grow + 256);
      g2 = *(const uint4*)(gi + grow + 512);
    }
    // pack h hi/lo and store; write node (fp32)
    unsigned ph[4], pl[4];
    #pragma unroll
    for (int q = 0; q < 4; ++q) {
      float f0 = hnew[q * 2], f1 = hnew[q * 2 + 1];
      unsigned short h0 = bfbits(f0);
      unsigned short h1 = bfbits(f1);
      float r0 = f0 - bits2f((unsigned)h0 << 16);
      float r1 = f1 - bits2f((unsigned)h1 << 16);
      ph[q] = (unsigned)h0 | ((unsigned)h1 << 16);
      pl[q] = (unsigned)bfbits(r0) | ((unsigned)bfbits(r1) << 16);
    }
    *(uint4*)((char*)hhi + hb) = make_uint4(ph[0], ph[1], ph[2], ph[3]);
    *(uint4*)((char*)hlo + hb) = make_uint4(pl[0], pl[1], pl[2], pl[3]);
    float* np = &a.node[((long)(b0 + ab) * NNODE + toff + tt) * D_ + dir * H_ + auq * 8];
    *(float4*)np       = make_float4(hnew[0], hnew[1], hnew[2], hnew[3]);
    *(float4*)(np + 4) = make_float4(hnew[4], hnew[5], hnew[6], hnew[7]);
    __syncthreads();
  }
}

// ---------------- attention over claims (one side) ----------------
__global__ __launch_bounds__(256) void attn_k(const float* node, float* w) {
  int b = blockIdx.x;
  __shared__ float tl[512];
  __shared__ float sc[CL];
  int tid = threadIdx.x;
  tl[tid]       = node[((long)b * NNODE + (TL - 1)) * D_ + tid];
  tl[tid + 256] = node[((long)b * NNODE + (TL - 1)) * D_ + 256 + tid];
  __syncthreads();
  int wid = tid >> 6, lane = tid & 63;
  for (int c = wid; c < CL; c += 4) {
    const float* row = node + ((long)b * NNODE + TL + c) * D_;
    float acc = 0.f;
    for (int d = lane; d < D_; d += 64) acc += row[d] * tl[d];
    #pragma unroll
    for (int o = 32; o; o >>= 1) acc += __shfl_xor(acc, o, 64);
    if (lane == 0) sc[c] = acc;
  }
  __syncthreads();
  if (wid == 0) {
    float v[4]; float m = -1e30f;
    #pragma unroll
    for (int i = 0; i < 4; ++i) {
      int c = lane + 64 * i;
      v[i] = (c < CL) ? sc[c] : -1e30f;
      m = fmaxf(m, v[i]);
    }
    #pragma unroll
    for (int o = 32; o; o >>= 1) m = fmaxf(m, __shfl_xor(m, o, 64));
    float s = 0.f;
    #pragma unroll
    for (int i = 0; i < 4; ++i) {
      int c = lane + 64 * i;
      v[i] = (c < CL) ? expf(v[i] - m) : 0.f;
      s += v[i];
    }
    #pragma unroll
    for (int o = 32; o; o >>= 1) s += __shfl_xor(s, o, 64);
    float inv = 1.f / s;
    #pragma unroll
    for (int i = 0; i < 4; ++i) {
      int c = lane + 64 * i;
      if (c < CL) w[(long)b * CL + c] = v[i] * inv;
    }
  }
}

// ---------------- row softmax (corr) ----------------
__global__ __launch_bounds__(256) void softmax_k(float* data, int rows, int len, int ld) {
  int row = blockIdx.x * 4 + (threadIdx.x >> 6);
  int lane = threadIdx.x & 63;
  if (row >= rows) return;
  float* p = data + (long)row * ld;
  float v[4]; float m = -1e30f;
  #pragma unroll
  for (int i = 0; i < 4; ++i) {
    int c = lane + i * 64;
    v[i] = (c < len) ? p[c] : -1e30f;
    m = fmaxf(m, v[i]);
  }
  #pragma unroll
  for (int o = 32; o; o >>= 1) m = fmaxf(m, __shfl_xor(m, o, 64));
  float s = 0.f;
  #pragma unroll
  for (int i = 0; i < 4; ++i) {
    int c = lane + i * 64;
    if (c < len) { v[i] = expf(v[i] - m); s += v[i]; }
  }
  #pragma unroll
  for (int o = 32; o; o >>= 1) s += __shfl_xor(s, o, 64);
  float inv = 1.f / s;
  #pragma unroll
  for (int i = 0; i < 4; ++i) {
    int c = lane + i * 64;
    if (c < len) p[c] = v[i] * inv;
  }
}

// ---------------- weighted claim pooling (one side) ----------------
__global__ __launch_bounds__(256) void rep_k(const float* node, const float* w,
                                             float* repSide) {
  int b = blockIdx.x;
  __shared__ float wl[CL];
  int tid = threadIdx.x;
  if (tid < CL) wl[tid] = w[(long)b * CL + tid];
  __syncthreads();
  #pragma unroll
  for (int h = 0; h < 2; ++h) {
    int d = tid + h * 256;
    float acc = 0.f;
    for (int c = 0; c < CL; ++c)
      acc = fmaf(wl[c], node[((long)b * NNODE + TL + c) * D_ + d], acc);
    repSide[(long)b * D_ + d] = acc;
  }
}

// ---------------- final linear ----------------
__global__ __launch_bounds__(256) void final_k(const float* rep, const float* linW,
                                               const float* linb, float* out) {
  int b = blockIdx.x, tid = threadIdx.x;
  float a0 = 0.f, a1 = 0.f, a2 = 0.f;
  for (int d = tid; d < 1024; d += 256) {
    float x = rep[(long)(d >> 9) * (B_ * D_) + (long)b * D_ + (d & 511)];
    a0 = fmaf(x, linW[d], a0);
    a1 = fmaf(x, linW[1024 + d], a1);
    a2 = fmaf(x, linW[2048 + d], a2);
  }
  #pragma unroll
  for (int o = 32; o; o >>= 1) {
    a0 += __shfl_xor(a0, o, 64);
    a1 += __shfl_xor(a1, o, 64);
    a2 += __shfl_xor(a2, o, 64);
  }
  __shared__ float red[3][4];
  int wid = tid >> 6, lane = tid & 63;
  if (lane == 0) { red[0][wid] = a0; red[1][wid] = a1; red[2][wid] = a2; }
  __syncthreads();
  if (tid == 0) {
    out[b * 3 + 0] = red[0][0] + red[0][1] + red[0][2] + red[0][3] + linb[0];
    out[b * 3 + 1] = red[1][0] + red[1][1] + red[1][2] + red[1][3] + linb[1];
    out[b * 3 + 2] = red[2][0] + red[2][1] + red[2][2] + red[2][3] + linb[2];
  }
}

// ---------------- diagnostic ----------------
__global__ void diag_k(float* out, int n, float v) {
  int i = blockIdx.x * blockDim.x + threadIdx.x;
  if (i < n) out[i] = v;
}

} // namespace

extern "C" void kernel_launch(void* const* d_in, const int* in_sizes, int n_in,
                              void* d_out, int out_size, void* d_ws, size_t ws_size,
                              hipStream_t stream) {
  const int* task_target   = (const int*)d_in[1];
  const int* shared_target = (const int*)d_in[2];
  const int* task_claim    = (const int*)d_in[3];
  const int* shared_claim  = (const int*)d_in[4];
  const float* emb      = (const float*)d_in[9];
  const float* tgt_wih  = (const float*)d_in[10];
  const float* tgt_whh  = (const float*)d_in[11];
  const float* tgt_bih  = (const float*)d_in[12];
  const float* tgt_bhh  = (const float*)d_in[13];
  const float* tgc_wih  = (const float*)d_in[14];
  const float* tgc_whh  = (const float*)d_in[15];
  const float* tgc_bih  = (const float*)d_in[16];
  const float* tgc_bhh  = (const float*)d_in[17];
  const float* sgt_wih  = (const float*)d_in[18];
  const float* sgt_whh  = (const float*)d_in[19];
  const float* sgt_bih  = (const float*)d_in[20];
  const float* sgt_bhh  = (const float*)d_in[21];
  const float* sgc_wih  = (const float*)d_in[22];
  const float* sgc_whh  = (const float*)d_in[23];
  const float* sgc_bih  = (const float*)d_in[24];
  const float* sgc_bhh  = (const float*)d_in[25];
  const float* gcnW_task   = (const float*)d_in[26];
  const float* gcnW_shared = (const float*)d_in[27];
  const float* linW = (const float*)d_in[28];
  const float* linb = (const float*)d_in[29];
  float* out = (float*)d_out;

  // ---- workspace carve-up: two sequential side-phases share one arena ----
  const size_t SZ_WHH   = 8ULL * 768 * 256 * 2;
  const size_t SZ_GI_T  = 2ULL * 6400  * 768 * 2;
  const size_t SZ_GI_C  = 2ULL * 25600 * 768 * 2;
  const size_t SZ_TMP   = 128ULL * 250 * 512 * 4;
  const size_t SZ_CORR  = 128ULL * 250 * 256 * 4;
  const size_t SZ_TRANS = 128ULL * 250 * 512 * 4;
  const size_t SZ_ARENA = SZ_TMP + SZ_CORR + SZ_TRANS;
  const size_t SZ_NODE  = 128ULL * 250 * 512 * 4;
  const size_t SZ_W     = 128ULL * 200 * 4;
  const size_t SZ_REP   = 2ULL * 128 * 512 * 4;
  const size_t NEED = SZ_WHH + SZ_ARENA + SZ_NODE + 2 * SZ_W + SZ_REP + 4096;

  if (ws_size < NEED) {
    diag_k<<<(out_size + 255) / 256, 256, 0, stream>>>(out, out_size,
                                                       (float)(ws_size >> 20));
    return;
  }

  char* p = (char*)d_ws;
  auto alloc = [&](size_t bytes) { char* r = p; p += (bytes + 255) & ~(size_t)255; return r; };
  __hip_bfloat16* whhbf = (__hip_bfloat16*)alloc(SZ_WHH);
  char* arena = alloc(SZ_ARENA);
  __hip_bfloat16* gi_t = (__hip_bfloat16*)(arena);
  __hip_bfloat16* gi_c = (__hip_bfloat16*)(arena + SZ_GI_T);
  float* tmp   = (float*)(arena);
  float* corr  = (float*)(arena + SZ_TMP);
  float* trans = (float*)(arena + SZ_TMP + SZ_CORR);
  float* node  = (float*)alloc(SZ_NODE);
  float* wT  = (float*)alloc(SZ_W);
  float* wS  = (float*)alloc(SZ_W);
  float* rep = (float*)alloc(SZ_REP);

  convwhh_k<<<6144, 256, 0, stream>>>(tgt_whh, tgc_whh, sgt_whh, sgc_whh, whhbf);

  auto projLaunch = [&](const int* idx, const float* wih, const float* bih,
                        __hip_bfloat16* gi, int Mrows) {
    GemmArgs ga{};
    ga.A = emb; ga.idx = idx; ga.B = wih; ga.bias = bih; ga.C = gi;
    ga.aStride = 0; ga.bStride = 768L * 300; ga.biasStride = 768;
    ga.cStride = (long)Mrows * 768; ga.rStride = 0;
    ga.M = Mrows; ga.N = 768; ga.K = 300; ga.lda = 300; ga.ldb = 300; ga.ldc = 768;
    dim3 grid((Mrows + GBM - 1) / GBM, 6, 2);
    gemm_k<true, true, true, 1><<<grid, 256, 0, stream>>>(ga);
  };

  auto runSide = [&](const int* tgtTok, const int* clmTok,
                     const float* wih_t, const float* bih_t, const float* bhh_t,
                     const float* wih_c, const float* bih_c, const float* bhh_c,
                     const __hip_bfloat16* whh4, const float* gcnW,
                     float* w, float* repSide) {
    projLaunch(tgtTok, wih_t, bih_t, gi_t, 6400);
    projLaunch(clmTok, wih_c, bih_c, gi_c, 25600);
    RecArgs ra{whh4, gi_t, gi_c, bhh_t, bhh_c, node};
    gru_rec_k<<<dim3(8, 1, 4), 512, 0, stream>>>(ra);
    attn_k<<<dim3(128), 256, 0, stream>>>(node, w);
    for (int layer = 0; layer < 2; ++layer) {
      const float* in = layer ? (const float*)tmp : (const float*)node;
      float* outp = layer ? node : tmp;
      const float* Wlayer = gcnW + (long)layer * 512 * 512;
      GemmArgs ca{};   // S = node @ node^T
      ca.A = in; ca.B = in; ca.C = corr;
      ca.aStride = 128000; ca.bStride = 128000; ca.cStride = 64000;
      ca.M = 250; ca.N = 250; ca.K = 512; ca.lda = 512; ca.ldb = 512; ca.ldc = 256;
      gemm_k<false, true, false, 0><<<dim3(2, 2, 128), 256, 0, stream>>>(ca);
      softmax_k<<<dim3(8000), 256, 0, stream>>>(corr, 32000, 250, 256);
      GemmArgs ta{};   // trans = node @ W^T
      ta.A = in; ta.B = Wlayer; ta.C = trans;
      ta.aStride = 128000; ta.bStride = 0; ta.cStride = 128000;
      ta.M = 250; ta.N = 512; ta.K = 512; ta.lda = 512; ta.ldb = 512; ta.ldc = 512;
      gemm_k<false, true, false, 0><<<dim3(2, 4, 128), 256, 0, stream>>>(ta);
      GemmArgs aa{};   // out = relu(node + corr @ trans)
      aa.A = corr; aa.B = trans; aa.C = outp; aa.Res = in;
      aa.aStride = 64000; aa.bStride = 128000; aa.cStride = 128000; aa.rStride = 128000;
      aa.M = 250; aa.N = 512; aa.K = 250; aa.lda = 256; aa.ldb = 512; aa.ldc = 512;
      gemm_k<false, false, false, 2><<<dim3(2, 4, 128), 256, 0, stream>>>(aa);
    }
    rep_k<<<dim3(128), 256, 0, stream>>>(node, w, repSide);
  };

  runSide(task_target, task_claim,
          tgt_wih, tgt_bih, tgt_bhh, tgc_wih, tgc_bih, tgc_bhh,
          whhbf, gcnW_task, wT, rep);
  runSide(shared_target, shared_claim,
          sgt_wih, sgt_bih, sgt_bhh, sgc_wih, sgc_bih, sgc_bhh,
          whhbf + 4L * 768 * 256, gcnW_shared, wS, rep + 128L * 512);

  final_k<<<dim3(128), 256, 0, stream>>>(rep, linW, linb, out);
}

// Round 6
// 5053.308 us; speedup vs baseline: 8.5648x; 1.0715x over previous
//
#include <hip/hip_runtime.h>
#include <hip/hip_bf16.h>

namespace {

constexpr int B_  = 128;
constexpr int TL  = 50, CL = 200, NNODE = 250;
constexpr int H_  = 256, D_ = 512;

typedef __attribute__((ext_vector_type(8))) short bf16x8;
typedef __attribute__((ext_vector_type(4))) float f32x4;

__device__ inline float bits2f(unsigned v) { union { unsigned u; float f; } c; c.u = v; return c.f; }
__device__ inline unsigned short bfbits(float x) {
  __hip_bfloat16 b = __float2bfloat16(x);
  return *(unsigned short*)&b;
}
__device__ inline float bfsel(uint2 v, int r) {        // r-th bf16 of a 4-pack
  unsigned w = (r < 2) ? v.x : v.y;
  return bits2f((r & 1) ? (w & 0xFFFF0000u) : (w << 16));
}
__device__ inline float sigf(float x)  { return 1.f / (1.f + __expf(-x)); }
__device__ inline float tanhf_(float x){ return 1.f - 2.f / (__expf(2.f * x) + 1.f); }

// ---------------- generic fp32 tiled GEMM ----------------
struct GemmArgs {
  const float* A; const int* idx; const float* B; const float* bias; const float* Res;
  void* C;
  long aStride, bStride, biasStride, cStride, rStride;
  int M, N, K, lda, ldb, ldc;
};

constexpr int GBM = 128, GBN = 128, GBK = 32;

template<bool GATHER, bool BNT, bool OBF16, int EPI>  // EPI 0=none 1=+bias 2=+res,relu
__global__ __launch_bounds__(256) void gemm_k(GemmArgs g) {
  __shared__ float As[GBK][GBM + 4];
  __shared__ float Bs[GBK][GBN + 4];
  const int z  = blockIdx.z;
  const int m0 = blockIdx.x * GBM;
  const int n0 = blockIdx.y * GBN;
  const int tid = threadIdx.x;
  const int tx = tid & 15, ty = tid >> 4;
  const float* Abase = GATHER ? g.A : (g.A + (long)z * g.aStride);
  const float* Bbase = g.B + (long)z * g.bStride;
  float acc[8][8];
  #pragma unroll
  for (int i = 0; i < 8; ++i)
    #pragma unroll
    for (int j = 0; j < 8; ++j) acc[i][j] = 0.f;
  const int c8 = tid & 7, r32 = tid >> 3;

  for (int k0 = 0; k0 < g.K; k0 += GBK) {
    const bool ktail = (k0 + GBK > g.K);
    __syncthreads();
    #pragma unroll
    for (int p = 0; p < 4; ++p) {
      int mr = p * 32 + r32;
      int row = m0 + mr;
      float4 v = make_float4(0.f, 0.f, 0.f, 0.f);
      if (row < g.M) {
        long aoff = GATHER ? ((long)g.idx[row] * g.lda) : ((long)row * g.lda);
        const float* src = Abase + aoff + k0 + c8 * 4;
        if (!ktail) v = *(const float4*)src;
        else {
          int kb = k0 + c8 * 4;
          if (kb + 0 < g.K) v.x = src[0];
          if (kb + 1 < g.K) v.y = src[1];
          if (kb + 2 < g.K) v.z = src[2];
          if (kb + 3 < g.K) v.w = src[3];
        }
      }
      As[c8 * 4 + 0][mr] = v.x; As[c8 * 4 + 1][mr] = v.y;
      As[c8 * 4 + 2][mr] = v.z; As[c8 * 4 + 3][mr] = v.w;
    }
    if (BNT) {
      #pragma unroll
      for (int p = 0; p < 4; ++p) {
        int nr = p * 32 + r32;
        int col = n0 + nr;
        float4 v = make_float4(0.f, 0.f, 0.f, 0.f);
        if (col < g.N) {
          const float* src = Bbase + (long)col * g.ldb + k0 + c8 * 4;
          if (!ktail) v = *(const float4*)src;
          else {
            int kb = k0 + c8 * 4;
            if (kb + 0 < g.K) v.x = src[0];
            if (kb + 1 < g.K) v.y = src[1];
            if (kb + 2 < g.K) v.z = src[2];
            if (kb + 3 < g.K) v.w = src[3];
          }
        }
        Bs[c8 * 4 + 0][nr] = v.x; Bs[c8 * 4 + 1][nr] = v.y;
        Bs[c8 * 4 + 2][nr] = v.z; Bs[c8 * 4 + 3][nr] = v.w;
      }
    } else {
      const int c32 = tid & 31, r8 = tid >> 5;
      #pragma unroll
      for (int p = 0; p < 4; ++p) {
        int kr = p * 8 + r8;
        int kg = k0 + kr;
        float4 v = make_float4(0.f, 0.f, 0.f, 0.f);
        int col = n0 + c32 * 4;
        if (kg < g.K) {
          const float* src = Bbase + (long)kg * g.ldb + col;
          if (col + 3 < g.N) v = *(const float4*)src;
          else {
            if (col + 0 < g.N) v.x = src[0];
            if (col + 1 < g.N) v.y = src[1];
            if (col + 2 < g.N) v.z = src[2];
            if (col + 3 < g.N) v.w = src[3];
          }
        }
        *(float4*)&Bs[kr][c32 * 4] = v;
      }
    }
    __syncthreads();
    #pragma unroll 8
    for (int kk = 0; kk < GBK; ++kk) {
      float4 a0 = *(const float4*)&As[kk][ty * 8];
      float4 a1 = *(const float4*)&As[kk][ty * 8 + 4];
      float4 b0 = *(const float4*)&Bs[kk][tx * 8];
      float4 b1 = *(const float4*)&Bs[kk][tx * 8 + 4];
      float av[8] = {a0.x, a0.y, a0.z, a0.w, a1.x, a1.y, a1.z, a1.w};
      float bv[8] = {b0.x, b0.y, b0.z, b0.w, b1.x, b1.y, b1.z, b1.w};
      #pragma unroll
      for (int i = 0; i < 8; ++i)
        #pragma unroll
        for (int j = 0; j < 8; ++j)
          acc[i][j] = fmaf(av[i], bv[j], acc[i][j]);
    }
  }
  #pragma unroll
  for (int i = 0; i < 8; ++i) {
    int row = m0 + ty * 8 + i;
    if (row < g.M) {
      long cbase = (long)z * g.cStride + (long)row * g.ldc;
      #pragma unroll
      for (int j = 0; j < 8; ++j) {
        int col = n0 + tx * 8 + j;
        if (col < g.N) {
          float v = acc[i][j];
          if (EPI == 1) v += g.bias[(long)z * g.biasStride + col];
          if (EPI == 2) {
            v += g.Res[(long)z * g.rStride + (long)row * g.ldc + col];
            v = fmaxf(v, 0.f);
          }
          if (OBF16) ((__hip_bfloat16*)g.C)[cbase + col] = __float2bfloat16(v);
          else       ((float*)g.C)[cbase + col] = v;
        }
      }
    }
  }
}

// ---------------- Whh -> bf16 conversion (all 8 dir-matrices) ----------------
__global__ __launch_bounds__(256) void convwhh_k(const float* tt, const float* tc,
                                                 const float* st, const float* sc,
                                                 __hip_bfloat16* o) {
  long i = (long)blockIdx.x * blockDim.x + threadIdx.x;
  const long per = 768L * 256;
  if (i >= 8 * per) return;
  int z = (int)(i / per);
  long rem = i - (long)z * per;
  const float* src = (z < 2) ? tt : (z < 4) ? tc : (z < 6) ? st : sc;
  o[i] = __float2bfloat16(src[(long)(z & 1) * per + rem]);
}

// ---------------- GRU recurrence: MFMA persistent-RNN, in-register gates -----
// grid (8,1,4): z = sq*2+dir, blockIdx.x = 16-batch group. Block 512 thr
// (8 waves, 2/SIMD, 256 unified VGPR+AGPR). Wave wv owns units
// [wv*32, wv*32+32) for ALL 3 gates (6 MFMA tiles) -> gates land in-lane in
// the D-fragments: no gh LDS exchange, ONE barrier/step (lgkmcnt-only wait;
// node stores + gi loads stay in flight across it). h = bf16 hi+lo pair in
// double-buffered XOR-swizzled LDS (fp32-quality recurrent state).
struct RecArgs {
  const __hip_bfloat16* whh4;     // side base: [4][768][256]
  const __hip_bfloat16* gi_t;     // [2][B*TL][768]
  const __hip_bfloat16* gi_c;     // [2][B*CL][768]
  const float* bhh_t;             // [2][768]
  const float* bhh_c;             // [2][768]
  float* node;                    // [B][250][512]
};

__global__ __launch_bounds__(512, 2) void gru_rec_k(RecArgs a) {
  __shared__ __align__(16) char hbuf[2][2][8192];   // [buf][hi/lo][batch 16][k 256] bf16, swizzled
  __shared__ __align__(16) float bhhS[768];
  const int z = blockIdx.z;
  const int sq = z >> 1, dir = z & 1;
  const int T = sq ? CL : TL;
  const int toff = sq ? TL : 0;
  const __hip_bfloat16* gi = (sq ? a.gi_c : a.gi_t) + (long)dir * B_ * T * 768;
  const float* bhh = (sq ? a.bhh_c : a.bhh_t) + dir * 768;
  const __hip_bfloat16* whh = a.whh4 + (long)z * 768 * 256;
  const int b0 = blockIdx.x * 16;
  const int tid = threadIdx.x;
  const int lane = tid & 63, wv = tid >> 6;
  const int bcol = lane & 15, g4 = lane >> 4;
  const int u0 = wv * 32 + g4 * 4;            // unit base (h adds 16)
  const int swz = (bcol & 7) << 4;

  // ---- prologue: A-fragments (this wave's 6 tiles x 8 k-slices) ----
  bf16x8 Af[3][2][8];
  #pragma unroll
  for (int g = 0; g < 3; ++g)
    #pragma unroll
    for (int h = 0; h < 2; ++h)
      #pragma unroll
      for (int kt = 0; kt < 8; ++kt) {
        int row = g * 256 + wv * 32 + h * 16 + bcol;
        int col = kt * 32 + g4 * 8;
        Af[g][h][kt] = *(const bf16x8*)(whh + (long)row * 256 + col);
      }
  *(uint4*)&hbuf[0][0][tid * 16] = make_uint4(0, 0, 0, 0);
  *(uint4*)&hbuf[0][1][tid * 16] = make_uint4(0, 0, 0, 0);
  for (int i = tid; i < 768; i += 512) bhhS[i] = bhh[i];
  __syncthreads();

  const __hip_bfloat16* gip = gi + ((long)(b0 + bcol) * T + (dir ? T - 1 : 0)) * 768 + u0;
  float* np = a.node + ((long)(b0 + bcol) * NNODE + toff + (dir ? T - 1 : 0)) * D_ + dir * H_ + u0;
  const long gistep = (dir ? -768L : 768L);
  const long nstep  = (dir ? -(long)D_ : (long)D_);
  int cur = 0;

  for (int t = 0; t < T; ++t) {
    // gi prefetch (6 x b64, consumed after MFMA phase)
    uint2 gv[3][2];
    #pragma unroll
    for (int g = 0; g < 3; ++g)
      #pragma unroll
      for (int h = 0; h < 2; ++h)
        gv[g][h] = *(const uint2*)(gip + g * 256 + h * 16);

    // ---- MFMA: gates for (this wave's 32 units) x (16 batch) ----
    const char* hib = &hbuf[cur][0][0];
    const char* lob = &hbuf[cur][1][0];
    f32x4 c[3][2];
    #pragma unroll
    for (int g = 0; g < 3; ++g)
      #pragma unroll
      for (int h = 0; h < 2; ++h) c[g][h] = (f32x4){0.f, 0.f, 0.f, 0.f};
    const int rb = bcol * 512 + g4 * 16;
    #pragma unroll
    for (int kt = 0; kt < 8; ++kt) {
      bf16x8 bh = *(const bf16x8*)(hib + ((rb + kt * 64) ^ swz));
      bf16x8 bl = *(const bf16x8*)(lob + ((rb + kt * 64) ^ swz));
      #pragma unroll
      for (int g = 0; g < 3; ++g)
        #pragma unroll
        for (int h = 0; h < 2; ++h) {
          c[g][h] = __builtin_amdgcn_mfma_f32_16x16x32_bf16(Af[g][h][kt], bh, c[g][h], 0, 0, 0);
          c[g][h] = __builtin_amdgcn_mfma_f32_16x16x32_bf16(Af[g][h][kt], bl, c[g][h], 0, 0, 0);
        }
    }

    // ---- activation (all in-register; D-frag: col=batch=lane&15, row=g4*4+r) ----
    const int ob0 = bcol * 512 + u0 * 2;
    uint2 hh0 = *(const uint2*)(hib + (ob0 ^ swz));
    uint2 hl0 = *(const uint2*)(lob + (ob0 ^ swz));
    uint2 hh1 = *(const uint2*)(hib + ((ob0 + 32) ^ swz));
    uint2 hl1 = *(const uint2*)(lob + ((ob0 + 32) ^ swz));
    float hn[2][4];
    #pragma unroll
    for (int h = 0; h < 2; ++h) {
      float4 br = *(const float4*)&bhhS[u0 + h * 16];
      float4 bz = *(const float4*)&bhhS[256 + u0 + h * 16];
      float4 bn = *(const float4*)&bhhS[512 + u0 + h * 16];
      uint2 hh = h ? hh1 : hh0;
      uint2 hl = h ? hl1 : hl0;
      #pragma unroll
      for (int r = 0; r < 4; ++r) {
        float brv = (r == 0) ? br.x : (r == 1) ? br.y : (r == 2) ? br.z : br.w;
        float bzv = (r == 0) ? bz.x : (r == 1) ? bz.y : (r == 2) ? bz.z : bz.w;
        float bnv = (r == 0) ? bn.x : (r == 1) ? bn.y : (r == 2) ? bn.z : bn.w;
        float hold = bfsel(hh, r) + bfsel(hl, r);
        float rr = sigf(bfsel(gv[0][h], r) + c[0][h][r] + brv);
        float zz = sigf(bfsel(gv[1][h], r) + c[1][h][r] + bzv);
        float nn = tanhf_(bfsel(gv[2][h], r) + rr * (c[2][h][r] + bnv));
        hn[h][r] = (1.f - zz) * nn + zz * hold;
      }
    }
    // node stores (fire-and-forget; drained at kernel end, not per step)
    *(float4*)np        = make_float4(hn[0][0], hn[0][1], hn[0][2], hn[0][3]);
    *(float4*)(np + 16) = make_float4(hn[1][0], hn[1][1], hn[1][2], hn[1][3]);
    // pack hi/lo and write into the other h-buffer
    char* hibn = &hbuf[cur ^ 1][0][0];
    char* lobn = &hbuf[cur ^ 1][1][0];
    #pragma unroll
    for (int h = 0; h < 2; ++h) {
      unsigned short s0 = bfbits(hn[h][0]), s1 = bfbits(hn[h][1]);
      unsigned short s2 = bfbits(hn[h][2]), s3 = bfbits(hn[h][3]);
      float r0 = hn[h][0] - bits2f((unsigned)s0 << 16);
      float r1 = hn[h][1] - bits2f((unsigned)s1 << 16);
      float r2 = hn[h][2] - bits2f((unsigned)s2 << 16);
      float r3 = hn[h][3] - bits2f((unsigned)s3 << 16);
      uint2 hiw, low;
      hiw.x = (unsigned)s0 | ((unsigned)s1 << 16);
      hiw.y = (unsigned)s2 | ((unsigned)s3 << 16);
      low.x = (unsigned)bfbits(r0) | ((unsigned)bfbits(r1) << 16);
      low.y = (unsigned)bfbits(r2) | ((unsigned)bfbits(r3) << 16);
      *(uint2*)(hibn + ((ob0 + h * 32) ^ swz)) = hiw;
      *(uint2*)(lobn + ((ob0 + h * 32) ^ swz)) = low;
    }
    gip += gistep;
    np  += nstep;
    asm volatile("s_waitcnt lgkmcnt(0)" ::: "memory");
    __builtin_amdgcn_sched_barrier(0);
    __builtin_amdgcn_s_barrier();
    cur ^= 1;
  }
}

// ---------------- attention over claims (one side) ----------------
__global__ __launch_bounds__(256) void attn_k(const float* node, float* w) {
  int b = blockIdx.x;
  __shared__ float tl[512];
  __shared__ float sc[CL];
  int tid = threadIdx.x;
  tl[tid]       = node[((long)b * NNODE + (TL - 1)) * D_ + tid];
  tl[tid + 256] = node[((long)b * NNODE + (TL - 1)) * D_ + 256 + tid];
  __syncthreads();
  int wid = tid >> 6, lane = tid & 63;
  for (int c = wid; c < CL; c += 4) {
    const float* row = node + ((long)b * NNODE + TL + c) * D_;
    float acc = 0.f;
    for (int d = lane; d < D_; d += 64) acc += row[d] * tl[d];
    #pragma unroll
    for (int o = 32; o; o >>= 1) acc += __shfl_xor(acc, o, 64);
    if (lane == 0) sc[c] = acc;
  }
  __syncthreads();
  if (wid == 0) {
    float v[4]; float m = -1e30f;
    #pragma unroll
    for (int i = 0; i < 4; ++i) {
      int c = lane + 64 * i;
      v[i] = (c < CL) ? sc[c] : -1e30f;
      m = fmaxf(m, v[i]);
    }
    #pragma unroll
    for (int o = 32; o; o >>= 1) m = fmaxf(m, __shfl_xor(m, o, 64));
    float s = 0.f;
    #pragma unroll
    for (int i = 0; i < 4; ++i) {
      int c = lane + 64 * i;
      v[i] = (c < CL) ? expf(v[i] - m) : 0.f;
      s += v[i];
    }
    #pragma unroll
    for (int o = 32; o; o >>= 1) s += __shfl_xor(s, o, 64);
    float inv = 1.f / s;
    #pragma unroll
    for (int i = 0; i < 4; ++i) {
      int c = lane + 64 * i;
      if (c < CL) w[(long)b * CL + c] = v[i] * inv;
    }
  }
}

// ---------------- row softmax (corr) ----------------
__global__ __launch_bounds__(256) void softmax_k(float* data, int rows, int len, int ld) {
  int row = blockIdx.x * 4 + (threadIdx.x >> 6);
  int lane = threadIdx.x & 63;
  if (row >= rows) return;
  float* p = data + (long)row * ld;
  float v[4]; float m = -1e30f;
  #pragma unroll
  for (int i = 0; i < 4; ++i) {
    int c = lane + i * 64;
    v[i] = (c < len) ? p[c] : -1e30f;
    m = fmaxf(m, v[i]);
  }
  #pragma unroll
  for (int o = 32; o; o >>= 1) m = fmaxf(m, __shfl_xor(m, o, 64));
  float s = 0.f;
  #pragma unroll
  for (int i = 0; i < 4; ++i) {
    int c = lane + i * 64;
    if (c < len) { v[i] = expf(v[i] - m); s += v[i]; }
  }
  #pragma unroll
  for (int o = 32; o; o >>= 1) s += __shfl_xor(s, o, 64);
  float inv = 1.f / s;
  #pragma unroll
  for (int i = 0; i < 4; ++i) {
    int c = lane + i * 64;
    if (c < len) p[c] = v[i] * inv;
  }
}

// ---------------- weighted claim pooling (one side) ----------------
__global__ __launch_bounds__(256) void rep_k(const float* node, const float* w,
                                             float* repSide) {
  int b = blockIdx.x;
  __shared__ float wl[CL];
  int tid = threadIdx.x;
  if (tid < CL) wl[tid] = w[(long)b * CL + tid];
  __syncthreads();
  #pragma unroll
  for (int h = 0; h < 2; ++h) {
    int d = tid + h * 256;
    float acc = 0.f;
    for (int c = 0; c < CL; ++c)
      acc = fmaf(wl[c], node[((long)b * NNODE + TL + c) * D_ + d], acc);
    repSide[(long)b * D_ + d] = acc;
  }
}

// ---------------- final linear ----------------
__global__ __launch_bounds__(256) void final_k(const float* rep, const float* linW,
                                               const float* linb, float* out) {
  int b = blockIdx.x, tid = threadIdx.x;
  float a0 = 0.f, a1 = 0.f, a2 = 0.f;
  for (int d = tid; d < 1024; d += 256) {
    float x = rep[(long)(d >> 9) * (B_ * D_) + (long)b * D_ + (d & 511)];
    a0 = fmaf(x, linW[d], a0);
    a1 = fmaf(x, linW[1024 + d], a1);
    a2 = fmaf(x, linW[2048 + d], a2);
  }
  #pragma unroll
  for (int o = 32; o; o >>= 1) {
    a0 += __shfl_xor(a0, o, 64);
    a1 += __shfl_xor(a1, o, 64);
    a2 += __shfl_xor(a2, o, 64);
  }
  __shared__ float red[3][4];
  int wid = tid >> 6, lane = tid & 63;
  if (lane == 0) { red[0][wid] = a0; red[1][wid] = a1; red[2][wid] = a2; }
  __syncthreads();
  if (tid == 0) {
    out[b * 3 + 0] = red[0][0] + red[0][1] + red[0][2] + red[0][3] + linb[0];
    out[b * 3 + 1] = red[1][0] + red[1][1] + red[1][2] + red[1][3] + linb[1];
    out[b * 3 + 2] = red[2][0] + red[2][1] + red[2][2] + red[2][3] + linb[2];
  }
}

// ---------------- diagnostic ----------------
__global__ void diag_k(float* out, int n, float v) {
  int i = blockIdx.x * blockDim.x + threadIdx.x;
  if (i < n) out[i] = v;
}

} // namespace

extern "C" void kernel_launch(void* const* d_in, const int* in_sizes, int n_in,
                              void* d_out, int out_size, void* d_ws, size_t ws_size,
                              hipStream_t stream) {
  const int* task_target   = (const int*)d_in[1];
  const int* shared_target = (const int*)d_in[2];
  const int* task_claim    = (const int*)d_in[3];
  const int* shared_claim  = (const int*)d_in[4];
  const float* emb      = (const float*)d_in[9];
  const float* tgt_wih  = (const float*)d_in[10];
  const float* tgt_whh  = (const float*)d_in[11];
  const float* tgt_bih  = (const float*)d_in[12];
  const float* tgt_bhh  = (const float*)d_in[13];
  const float* tgc_wih  = (const float*)d_in[14];
  const float* tgc_whh  = (const float*)d_in[15];
  const float* tgc_bih  = (const float*)d_in[16];
  const float* tgc_bhh  = (const float*)d_in[17];
  const float* sgt_wih  = (const float*)d_in[18];
  const float* sgt_whh  = (const float*)d_in[19];
  const float* sgt_bih  = (const float*)d_in[20];
  const float* sgt_bhh  = (const float*)d_in[21];
  const float* sgc_wih  = (const float*)d_in[22];
  const float* sgc_whh  = (const float*)d_in[23];
  const float* sgc_bih  = (const float*)d_in[24];
  const float* sgc_bhh  = (const float*)d_in[25];
  const float* gcnW_task   = (const float*)d_in[26];
  const float* gcnW_shared = (const float*)d_in[27];
  const float* linW = (const float*)d_in[28];
  const float* linb = (const float*)d_in[29];
  float* out = (float*)d_out;

  // ---- workspace carve-up: two sequential side-phases share one arena ----
  const size_t SZ_WHH   = 8ULL * 768 * 256 * 2;
  const size_t SZ_GI_T  = 2ULL * 6400  * 768 * 2;
  const size_t SZ_GI_C  = 2ULL * 25600 * 768 * 2;
  const size_t SZ_TMP   = 128ULL * 250 * 512 * 4;
  const size_t SZ_CORR  = 128ULL * 250 * 256 * 4;
  const size_t SZ_TRANS = 128ULL * 250 * 512 * 4;
  const size_t SZ_ARENA = SZ_TMP + SZ_CORR + SZ_TRANS;
  const size_t SZ_NODE  = 128ULL * 250 * 512 * 4;
  const size_t SZ_W     = 128ULL * 200 * 4;
  const size_t SZ_REP   = 2ULL * 128 * 512 * 4;
  const size_t NEED = SZ_WHH + SZ_ARENA + SZ_NODE + 2 * SZ_W + SZ_REP + 4096;

  if (ws_size < NEED) {
    diag_k<<<(out_size + 255) / 256, 256, 0, stream>>>(out, out_size,
                                                       (float)(ws_size >> 20));
    return;
  }

  char* p = (char*)d_ws;
  auto alloc = [&](size_t bytes) { char* r = p; p += (bytes + 255) & ~(size_t)255; return r; };
  __hip_bfloat16* whhbf = (__hip_bfloat16*)alloc(SZ_WHH);
  char* arena = alloc(SZ_ARENA);
  __hip_bfloat16* gi_t = (__hip_bfloat16*)(arena);
  __hip_bfloat16* gi_c = (__hip_bfloat16*)(arena + SZ_GI_T);
  float* tmp   = (float*)(arena);
  float* corr  = (float*)(arena + SZ_TMP);
  float* trans = (float*)(arena + SZ_TMP + SZ_CORR);
  float* node  = (float*)alloc(SZ_NODE);
  float* wT  = (float*)alloc(SZ_W);
  float* wS  = (float*)alloc(SZ_W);
  float* rep = (float*)alloc(SZ_REP);

  convwhh_k<<<6144, 256, 0, stream>>>(tgt_whh, tgc_whh, sgt_whh, sgc_whh, whhbf);

  auto projLaunch = [&](const int* idx, const float* wih, const float* bih,
                        __hip_bfloat16* gi, int Mrows) {
    GemmArgs ga{};
    ga.A = emb; ga.idx = idx; ga.B = wih; ga.bias = bih; ga.C = gi;
    ga.aStride = 0; ga.bStride = 768L * 300; ga.biasStride = 768;
    ga.cStride = (long)Mrows * 768; ga.rStride = 0;
    ga.M = Mrows; ga.N = 768; ga.K = 300; ga.lda = 300; ga.ldb = 300; ga.ldc = 768;
    dim3 grid((Mrows + GBM - 1) / GBM, 6, 2);
    gemm_k<true, true, true, 1><<<grid, 256, 0, stream>>>(ga);
  };

  auto runSide = [&](const int* tgtTok, const int* clmTok,
                     const float* wih_t, const float* bih_t, const float* bhh_t,
                     const float* wih_c, const float* bih_c, const float* bhh_c,
                     const __hip_bfloat16* whh4, const float* gcnW,
                     float* w, float* repSide) {
    projLaunch(tgtTok, wih_t, bih_t, gi_t, 6400);
    projLaunch(clmTok, wih_c, bih_c, gi_c, 25600);
    RecArgs ra{whh4, gi_t, gi_c, bhh_t, bhh_c, node};
    gru_rec_k<<<dim3(8, 1, 4), 512, 0, stream>>>(ra);
    attn_k<<<dim3(128), 256, 0, stream>>>(node, w);
    for (int layer = 0; layer < 2; ++layer) {
      const float* in = layer ? (const float*)tmp : (const float*)node;
      float* outp = layer ? node : tmp;
      const float* Wlayer = gcnW + (long)layer * 512 * 512;
      GemmArgs ca{};   // S = node @ node^T
      ca.A = in; ca.B = in; ca.C = corr;
      ca.aStride = 128000; ca.bStride = 128000; ca.cStride = 64000;
      ca.M = 250; ca.N = 250; ca.K = 512; ca.lda = 512; ca.ldb = 512; ca.ldc = 256;
      gemm_k<false, true, false, 0><<<dim3(2, 2, 128), 256, 0, stream>>>(ca);
      softmax_k<<<dim3(8000), 256, 0, stream>>>(corr, 32000, 250, 256);
      GemmArgs ta{};   // trans = node @ W^T
      ta.A = in; ta.B = Wlayer; ta.C = trans;
      ta.aStride = 128000; ta.bStride = 0; ta.cStride = 128000;
      ta.M = 250; ta.N = 512; ta.K = 512; ta.lda = 512; ta.ldb = 512; ta.ldc = 512;
      gemm_k<false, true, false, 0><<<dim3(2, 4, 128), 256, 0, stream>>>(ta);
      GemmArgs aa{};   // out = relu(node + corr @ trans)
      aa.A = corr; aa.B = trans; aa.C = outp; aa.Res = in;
      aa.aStride = 64000; aa.bStride = 128000; aa.cStride = 128000; aa.rStride = 128000;
      aa.M = 250; aa.N = 512; aa.K = 250; aa.lda = 256; aa.ldb = 512; aa.ldc = 512;
      gemm_k<false, false, false, 2><<<dim3(2, 4, 128), 256, 0, stream>>>(aa);
    }
    rep_k<<<dim3(128), 256, 0, stream>>>(node, w, repSide);
  };

  runSide(task_target, task_claim,
          tgt_wih, tgt_bih, tgt_bhh, tgc_wih, tgc_bih, tgc_bhh,
          whhbf, gcnW_task, wT, rep);
  runSide(shared_target, shared_claim,
          sgt_wih, sgt_bih, sgt_bhh, sgc_wih, sgc_bih, sgc_bhh,
          whhbf + 4L * 768 * 256, gcnW_shared, wS, rep + 128L * 512);

  final_k<<<dim3(128), 256, 0, stream>>>(rep, linW, linb, out);
}

// Round 7
// 3134.735 us; speedup vs baseline: 13.8068x; 1.6120x over previous
//
#include <hip/hip_runtime.h>
#include <hip/hip_bf16.h>

namespace {

constexpr int B_  = 128;
constexpr int TL  = 50, CL = 200, NNODE = 250;
constexpr int H_  = 256, D_ = 512;

typedef __attribute__((ext_vector_type(8))) short bf16x8;
typedef __attribute__((ext_vector_type(4))) float f32x4;

__device__ inline float bits2f(unsigned v) { union { unsigned u; float f; } c; c.u = v; return c.f; }
__device__ inline unsigned short bfbits(float x) {
  __hip_bfloat16 b = __float2bfloat16(x);
  return *(unsigned short*)&b;
}
__device__ inline float bfsel(uint2 v, int r) {        // r-th bf16 of a 4-pack
  unsigned w = (r < 2) ? v.x : v.y;
  return bits2f((r & 1) ? (w & 0xFFFF0000u) : (w << 16));
}
__device__ inline float sigf(float x)  { return 1.f / (1.f + __expf(-x)); }
__device__ inline float tanhf_(float x){ return 1.f - 2.f / (__expf(2.f * x) + 1.f); }

// =============== bf16 MFMA GEMM: C[z] = A[z] @ B[z]^T (B is [N][K]) ===========
// OUT 0: f32 out. 1: +bias -> bf16. 2: +Res, relu -> f32 C AND bf16 C2.
// 3: bf16 out, zero-fill cols [N, 256) (for k-padded consumers).
struct BGemmArgs {
  const __hip_bfloat16* A; const __hip_bfloat16* B;
  const int* idx; const float* bias; const float* Res;
  void* C; void* C2;
  long aStride, bStride, biasStride, cStride, c2Stride, rStride;
  int M, N, Kreal, lda, ldb, ldc;
};

template<bool GATHER, int OUT>
__global__ __launch_bounds__(256) void bgemm_k(BGemmArgs g) {
  __shared__ __align__(16) __hip_bfloat16 As[128 * 64];   // [r][k] XOR-swizzled
  __shared__ __align__(16) __hip_bfloat16 Bs[128 * 64];
  const int z = blockIdx.z;
  const int m0 = blockIdx.x * 128, n0 = blockIdx.y * 128;
  const int tid = threadIdx.x;
  const int lane = tid & 63, wv = tid >> 6;
  const int wr = wv >> 1, wc = wv & 1;                    // wave -> 64x64 quadrant
  const __hip_bfloat16* Ab = GATHER ? g.A : g.A + (long)z * g.aStride;
  const __hip_bfloat16* Bb = g.B + (long)z * g.bStride;
  const int sr = tid >> 3, so = tid & 7;                  // staging: row, col-octet
  f32x4 acc[4][4];
  #pragma unroll
  for (int i = 0; i < 4; ++i)
    #pragma unroll
    for (int j = 0; j < 4; ++j) acc[i][j] = (f32x4){0.f, 0.f, 0.f, 0.f};

  const int ktiles = (g.Kreal + 63) >> 6;
  for (int kt = 0; kt < ktiles; ++kt) {
    const int k0 = kt * 64;
    __syncthreads();
    #pragma unroll
    for (int p = 0; p < 4; ++p) {           // A tile 128x64
      int r = p * 32 + sr;
      int row = m0 + r;
      int kg = k0 + so * 8;
      uint4 v = make_uint4(0, 0, 0, 0);
      if (row < g.M && kg + 8 <= g.Kreal) {
        long ao = GATHER ? (long)g.idx[row] * g.lda : (long)row * g.lda;
        v = *(const uint4*)(Ab + ao + kg);
      }
      *(uint4*)((char*)As + ((r * 128 + so * 16) ^ ((r & 7) << 4))) = v;
    }
    #pragma unroll
    for (int p = 0; p < 4; ++p) {           // B tile 128x64 (rows = n)
      int r = p * 32 + sr;
      int row = n0 + r;
      int kg = k0 + so * 8;
      uint4 v = make_uint4(0, 0, 0, 0);
      if (row < g.N && kg + 8 <= g.Kreal)
        v = *(const uint4*)(Bb + (long)row * g.ldb + kg);
      *(uint4*)((char*)Bs + ((r * 128 + so * 16) ^ ((r & 7) << 4))) = v;
    }
    __syncthreads();
    #pragma unroll
    for (int ks = 0; ks < 2; ++ks) {
      bf16x8 af[4], bfr[4];
      #pragma unroll
      for (int i = 0; i < 4; ++i) {
        int ra = wr * 64 + i * 16 + (lane & 15);
        af[i] = *(const bf16x8*)((const char*)As +
                 ((ra * 128 + ks * 64 + (lane >> 4) * 16) ^ ((ra & 7) << 4)));
        int rb = wc * 64 + i * 16 + (lane & 15);
        bfr[i] = *(const bf16x8*)((const char*)Bs +
                 ((rb * 128 + ks * 64 + (lane >> 4) * 16) ^ ((rb & 7) << 4)));
      }
      #pragma unroll
      for (int i = 0; i < 4; ++i)
        #pragma unroll
        for (int j = 0; j < 4; ++j)
          acc[i][j] = __builtin_amdgcn_mfma_f32_16x16x32_bf16(af[i], bfr[j], acc[i][j], 0, 0, 0);
    }
  }
  // ---- epilogue: D col = lane&15 (n), row = (lane>>4)*4 + r (m) ----
  const long cz = (long)z * g.cStride;
  #pragma unroll
  for (int i = 0; i < 4; ++i) {
    int rbase = m0 + wr * 64 + i * 16 + ((lane >> 4) << 2);
    #pragma unroll
    for (int j = 0; j < 4; ++j) {
      int col = n0 + wc * 64 + j * 16 + (lane & 15);
      #pragma unroll
      for (int r = 0; r < 4; ++r) {
        int row = rbase + r;
        float v = acc[i][j][r];
        if (OUT == 0) {
          if (row < g.M && col < g.N)
            ((float*)g.C)[cz + (long)row * g.ldc + col] = v;
        } else if (OUT == 1) {
          if (row < g.M && col < g.N) {
            v += g.bias[(long)z * g.biasStride + col];
            ((__hip_bfloat16*)g.C)[cz + (long)row * g.ldc + col] = __float2bfloat16(v);
          }
        } else if (OUT == 2) {
          if (row < g.M && col < g.N) {
            v += g.Res[(long)z * g.rStride + (long)row * g.ldc + col];
            v = fmaxf(v, 0.f);
            ((float*)g.C)[cz + (long)row * g.ldc + col] = v;
            ((__hip_bfloat16*)g.C2)[(long)z * g.c2Stride + (long)row * g.ldc + col] =
                __float2bfloat16(v);
          }
        } else {  // OUT == 3
          if (row < g.M)
            ((__hip_bfloat16*)g.C)[cz + (long)row * g.ldc + col] =
                __float2bfloat16(col < g.N ? v : 0.f);
        }
      }
    }
  }
}

// ---------------- conversions ----------------
__global__ __launch_bounds__(256) void convwhh_k(const float* tt, const float* tc,
                                                 const float* st, const float* sc,
                                                 __hip_bfloat16* o) {
  long i = (long)blockIdx.x * blockDim.x + threadIdx.x;
  const long per = 768L * 256;
  if (i >= 8 * per) return;
  int z = (int)(i / per);
  long rem = i - (long)z * per;
  const float* src = (z < 2) ? tt : (z < 4) ? tc : (z < 6) ? st : sc;
  o[i] = __float2bfloat16(src[(long)(z & 1) * per + rem]);
}

__global__ __launch_bounds__(256) void convpad_k(const float* src, __hip_bfloat16* dst,
                                                 int K, int Kp) {
  int c = blockIdx.x * 256 + threadIdx.x;
  long r = blockIdx.y;
  if (c < Kp) dst[r * Kp + c] = __float2bfloat16(c < K ? src[r * K + c] : 0.f);
}

__global__ __launch_bounds__(256) void convf2b4_k(const float* src, __hip_bfloat16* dst,
                                                  long n4) {
  long i = (long)blockIdx.x * 256 + threadIdx.x;
  if (i >= n4) return;
  float4 v = ((const float4*)src)[i];
  ushort4 o;
  o.x = bfbits(v.x); o.y = bfbits(v.y); o.z = bfbits(v.z); o.w = bfbits(v.w);
  ((ushort4*)dst)[i] = o;
}

// ---------------- GRU recurrence: MFMA persistent-RNN (unchanged from R6) -----
struct RecArgs {
  const __hip_bfloat16* whh4;
  const __hip_bfloat16* gi_t;
  const __hip_bfloat16* gi_c;
  const float* bhh_t;
  const float* bhh_c;
  float* node;
};

__global__ __launch_bounds__(512, 2) void gru_rec_k(RecArgs a) {
  __shared__ __align__(16) char hbuf[2][2][8192];
  __shared__ __align__(16) float bhhS[768];
  const int z = blockIdx.z;
  const int sq = z >> 1, dir = z & 1;
  const int T = sq ? CL : TL;
  const int toff = sq ? TL : 0;
  const __hip_bfloat16* gi = (sq ? a.gi_c : a.gi_t) + (long)dir * B_ * T * 768;
  const float* bhh = (sq ? a.bhh_c : a.bhh_t) + dir * 768;
  const __hip_bfloat16* whh = a.whh4 + (long)z * 768 * 256;
  const int b0 = blockIdx.x * 16;
  const int tid = threadIdx.x;
  const int lane = tid & 63, wv = tid >> 6;
  const int bcol = lane & 15, g4 = lane >> 4;
  const int u0 = wv * 32 + g4 * 4;
  const int swz = (bcol & 7) << 4;

  bf16x8 Af[3][2][8];
  #pragma unroll
  for (int g = 0; g < 3; ++g)
    #pragma unroll
    for (int h = 0; h < 2; ++h)
      #pragma unroll
      for (int kt = 0; kt < 8; ++kt) {
        int row = g * 256 + wv * 32 + h * 16 + bcol;
        int col = kt * 32 + g4 * 8;
        Af[g][h][kt] = *(const bf16x8*)(whh + (long)row * 256 + col);
      }
  *(uint4*)&hbuf[0][0][tid * 16] = make_uint4(0, 0, 0, 0);
  *(uint4*)&hbuf[0][1][tid * 16] = make_uint4(0, 0, 0, 0);
  for (int i = tid; i < 768; i += 512) bhhS[i] = bhh[i];
  __syncthreads();

  const __hip_bfloat16* gip = gi + ((long)(b0 + bcol) * T + (dir ? T - 1 : 0)) * 768 + u0;
  float* np = a.node + ((long)(b0 + bcol) * NNODE + toff + (dir ? T - 1 : 0)) * D_ + dir * H_ + u0;
  const long gistep = (dir ? -768L : 768L);
  const long nstep  = (dir ? -(long)D_ : (long)D_);
  int cur = 0;

  for (int t = 0; t < T; ++t) {
    uint2 gv[3][2];
    #pragma unroll
    for (int g = 0; g < 3; ++g)
      #pragma unroll
      for (int h = 0; h < 2; ++h)
        gv[g][h] = *(const uint2*)(gip + g * 256 + h * 16);

    const char* hib = &hbuf[cur][0][0];
    const char* lob = &hbuf[cur][1][0];
    f32x4 c[3][2];
    #pragma unroll
    for (int g = 0; g < 3; ++g)
      #pragma unroll
      for (int h = 0; h < 2; ++h) c[g][h] = (f32x4){0.f, 0.f, 0.f, 0.f};
    const int rb = bcol * 512 + g4 * 16;
    #pragma unroll
    for (int kt = 0; kt < 8; ++kt) {
      bf16x8 bh = *(const bf16x8*)(hib + ((rb + kt * 64) ^ swz));
      bf16x8 bl = *(const bf16x8*)(lob + ((rb + kt * 64) ^ swz));
      #pragma unroll
      for (int g = 0; g < 3; ++g)
        #pragma unroll
        for (int h = 0; h < 2; ++h) {
          c[g][h] = __builtin_amdgcn_mfma_f32_16x16x32_bf16(Af[g][h][kt], bh, c[g][h], 0, 0, 0);
          c[g][h] = __builtin_amdgcn_mfma_f32_16x16x32_bf16(Af[g][h][kt], bl, c[g][h], 0, 0, 0);
        }
    }

    const int ob0 = bcol * 512 + u0 * 2;
    uint2 hh0 = *(const uint2*)(hib + (ob0 ^ swz));
    uint2 hl0 = *(const uint2*)(lob + (ob0 ^ swz));
    uint2 hh1 = *(const uint2*)(hib + ((ob0 + 32) ^ swz));
    uint2 hl1 = *(const uint2*)(lob + ((ob0 + 32) ^ swz));
    float hn[2][4];
    #pragma unroll
    for (int h = 0; h < 2; ++h) {
      float4 br = *(const float4*)&bhhS[u0 + h * 16];
      float4 bz = *(const float4*)&bhhS[256 + u0 + h * 16];
      float4 bn = *(const float4*)&bhhS[512 + u0 + h * 16];
      uint2 hh = h ? hh1 : hh0;
      uint2 hl = h ? hl1 : hl0;
      #pragma unroll
      for (int r = 0; r < 4; ++r) {
        float brv = (r == 0) ? br.x : (r == 1) ? br.y : (r == 2) ? br.z : br.w;
        float bzv = (r == 0) ? bz.x : (r == 1) ? bz.y : (r == 2) ? bz.z : bz.w;
        float bnv = (r == 0) ? bn.x : (r == 1) ? bn.y : (r == 2) ? bn.z : bn.w;
        float hold = bfsel(hh, r) + bfsel(hl, r);
        float rr = sigf(bfsel(gv[0][h], r) + c[0][h][r] + brv);
        float zz = sigf(bfsel(gv[1][h], r) + c[1][h][r] + bzv);
        float nn = tanhf_(bfsel(gv[2][h], r) + rr * (c[2][h][r] + bnv));
        hn[h][r] = (1.f - zz) * nn + zz * hold;
      }
    }
    *(float4*)np        = make_float4(hn[0][0], hn[0][1], hn[0][2], hn[0][3]);
    *(float4*)(np + 16) = make_float4(hn[1][0], hn[1][1], hn[1][2], hn[1][3]);
    char* hibn = &hbuf[cur ^ 1][0][0];
    char* lobn = &hbuf[cur ^ 1][1][0];
    #pragma unroll
    for (int h = 0; h < 2; ++h) {
      unsigned short s0 = bfbits(hn[h][0]), s1 = bfbits(hn[h][1]);
      unsigned short s2 = bfbits(hn[h][2]), s3 = bfbits(hn[h][3]);
      float r0 = hn[h][0] - bits2f((unsigned)s0 << 16);
      float r1 = hn[h][1] - bits2f((unsigned)s1 << 16);
      float r2 = hn[h][2] - bits2f((unsigned)s2 << 16);
      float r3 = hn[h][3] - bits2f((unsigned)s3 << 16);
      uint2 hiw, low;
      hiw.x = (unsigned)s0 | ((unsigned)s1 << 16);
      hiw.y = (unsigned)s2 | ((unsigned)s3 << 16);
      low.x = (unsigned)bfbits(r0) | ((unsigned)bfbits(r1) << 16);
      low.y = (unsigned)bfbits(r2) | ((unsigned)bfbits(r3) << 16);
      *(uint2*)(hibn + ((ob0 + h * 32) ^ swz)) = hiw;
      *(uint2*)(lobn + ((ob0 + h * 32) ^ swz)) = low;
    }
    gip += gistep;
    np  += nstep;
    asm volatile("s_waitcnt lgkmcnt(0)" ::: "memory");
    __builtin_amdgcn_sched_barrier(0);
    __builtin_amdgcn_s_barrier();
    cur ^= 1;
  }
}

// ---------------- attention over claims (one side) ----------------
__global__ __launch_bounds__(256) void attn_k(const float* node, float* w) {
  int b = blockIdx.x;
  __shared__ float tl[512];
  __shared__ float sc[CL];
  int tid = threadIdx.x;
  tl[tid]       = node[((long)b * NNODE + (TL - 1)) * D_ + tid];
  tl[tid + 256] = node[((long)b * NNODE + (TL - 1)) * D_ + 256 + tid];
  __syncthreads();
  int wid = tid >> 6, lane = tid & 63;
  for (int c = wid; c < CL; c += 4) {
    const float* row = node + ((long)b * NNODE + TL + c) * D_;
    float acc = 0.f;
    for (int d = lane; d < D_; d += 64) acc += row[d] * tl[d];
    #pragma unroll
    for (int o = 32; o; o >>= 1) acc += __shfl_xor(acc, o, 64);
    if (lane == 0) sc[c] = acc;
  }
  __syncthreads();
  if (wid == 0) {
    float v[4]; float m = -1e30f;
    #pragma unroll
    for (int i = 0; i < 4; ++i) {
      int c = lane + 64 * i;
      v[i] = (c < CL) ? sc[c] : -1e30f;
      m = fmaxf(m, v[i]);
    }
    #pragma unroll
    for (int o = 32; o; o >>= 1) m = fmaxf(m, __shfl_xor(m, o, 64));
    float s = 0.f;
    #pragma unroll
    for (int i = 0; i < 4; ++i) {
      int c = lane + 64 * i;
      v[i] = (c < CL) ? expf(v[i] - m) : 0.f;
      s += v[i];
    }
    #pragma unroll
    for (int o = 32; o; o >>= 1) s += __shfl_xor(s, o, 64);
    float inv = 1.f / s;
    #pragma unroll
    for (int i = 0; i < 4; ++i) {
      int c = lane + 64 * i;
      if (c < CL) w[(long)b * CL + c] = v[i] * inv;
    }
  }
}

// ---------------- row softmax: f32 in (ld 256, len 250) -> bf16 out, 0-pad ----
__global__ __launch_bounds__(256) void softmaxbf_k(const float* in, __hip_bfloat16* out) {
  int row = blockIdx.x * 4 + (threadIdx.x >> 6);
  int lane = threadIdx.x & 63;
  const float* p = in + (long)row * 256;
  __hip_bfloat16* q = out + (long)row * 256;
  float v[4]; float m = -1e30f;
  #pragma unroll
  for (int i = 0; i < 4; ++i) {
    int c = lane + i * 64;
    v[i] = (c < 250) ? p[c] : -1e30f;
    m = fmaxf(m, v[i]);
  }
  #pragma unroll
  for (int o = 32; o; o >>= 1) m = fmaxf(m, __shfl_xor(m, o, 64));
  float s = 0.f;
  #pragma unroll
  for (int i = 0; i < 4; ++i) {
    int c = lane + i * 64;
    if (c < 250) { v[i] = __expf(v[i] - m); s += v[i]; }
  }
  #pragma unroll
  for (int o = 32; o; o >>= 1) s += __shfl_xor(s, o, 64);
  float inv = 1.f / s;
  #pragma unroll
  for (int i = 0; i < 4; ++i) {
    int c = lane + i * 64;
    q[c] = __float2bfloat16((c < 250) ? v[i] * inv : 0.f);
  }
}

// ---------------- weighted claim pooling (one side) ----------------
__global__ __launch_bounds__(256) void rep_k(const float* node, const float* w,
                                             float* repSide) {
  int b = blockIdx.x;
  __shared__ float wl[CL];
  int tid = threadIdx.x;
  if (tid < CL) wl[tid] = w[(long)b * CL + tid];
  __syncthreads();
  #pragma unroll
  for (int h = 0; h < 2; ++h) {
    int d = tid + h * 256;
    float acc = 0.f;
    for (int c = 0; c < CL; ++c)
      acc = fmaf(wl[c], node[((long)b * NNODE + TL + c) * D_ + d], acc);
    repSide[(long)b * D_ + d] = acc;
  }
}

// ---------------- final linear ----------------
__global__ __launch_bounds__(256) void final_k(const float* rep, const float* linW,
                                               const float* linb, float* out) {
  int b = blockIdx.x, tid = threadIdx.x;
  float a0 = 0.f, a1 = 0.f, a2 = 0.f;
  for (int d = tid; d < 1024; d += 256) {
    float x = rep[(long)(d >> 9) * (B_ * D_) + (long)b * D_ + (d & 511)];
    a0 = fmaf(x, linW[d], a0);
    a1 = fmaf(x, linW[1024 + d], a1);
    a2 = fmaf(x, linW[2048 + d], a2);
  }
  #pragma unroll
  for (int o = 32; o; o >>= 1) {
    a0 += __shfl_xor(a0, o, 64);
    a1 += __shfl_xor(a1, o, 64);
    a2 += __shfl_xor(a2, o, 64);
  }
  __shared__ float red[3][4];
  int wid = tid >> 6, lane = tid & 63;
  if (lane == 0) { red[0][wid] = a0; red[1][wid] = a1; red[2][wid] = a2; }
  __syncthreads();
  if (tid == 0) {
    out[b * 3 + 0] = red[0][0] + red[0][1] + red[0][2] + red[0][3] + linb[0];
    out[b * 3 + 1] = red[1][0] + red[1][1] + red[1][2] + red[1][3] + linb[1];
    out[b * 3 + 2] = red[2][0] + red[2][1] + red[2][2] + red[2][3] + linb[2];
  }
}

// ---------------- diagnostic ----------------
__global__ void diag_k(float* out, int n, float v) {
  int i = blockIdx.x * blockDim.x + threadIdx.x;
  if (i < n) out[i] = v;
}

} // namespace

extern "C" void kernel_launch(void* const* d_in, const int* in_sizes, int n_in,
                              void* d_out, int out_size, void* d_ws, size_t ws_size,
                              hipStream_t stream) {
  const int* task_target   = (const int*)d_in[1];
  const int* shared_target = (const int*)d_in[2];
  const int* task_claim    = (const int*)d_in[3];
  const int* shared_claim  = (const int*)d_in[4];
  const float* emb      = (const float*)d_in[9];
  const float* tgt_wih  = (const float*)d_in[10];
  const float* tgt_whh  = (const float*)d_in[11];
  const float* tgt_bih  = (const float*)d_in[12];
  const float* tgt_bhh  = (const float*)d_in[13];
  const float* tgc_wih  = (const float*)d_in[14];
  const float* tgc_whh  = (const float*)d_in[15];
  const float* tgc_bih  = (const float*)d_in[16];
  const float* tgc_bhh  = (const float*)d_in[17];
  const float* sgt_wih  = (const float*)d_in[18];
  const float* sgt_whh  = (const float*)d_in[19];
  const float* sgt_bih  = (const float*)d_in[20];
  const float* sgt_bhh  = (const float*)d_in[21];
  const float* sgc_wih  = (const float*)d_in[22];
  const float* sgc_whh  = (const float*)d_in[23];
  const float* sgc_bih  = (const float*)d_in[24];
  const float* sgc_bhh  = (const float*)d_in[25];
  const float* gcnW_task   = (const float*)d_in[26];
  const float* gcnW_shared = (const float*)d_in[27];
  const float* linW = (const float*)d_in[28];
  const float* linb = (const float*)d_in[29];
  float* out = (float*)d_out;

  // ---- workspace plan (bytes) ----
  const size_t SZ_WHH   = 3145728;      // 8 x 768x256 bf16
  const size_t SZ_GCNW  = 2097152;      // 2 sides x 2 x 512x512 bf16
  const size_t SZ_ARENA = 181010432;    // max(proj-phase 118.4MB, gcn-phase 181.0MB)
  const size_t SZ_NODE  = 65536000;     // 128x250x512 f32
  const size_t SZ_W     = 102400;
  const size_t SZ_REP   = 524288;
  const size_t NEED = SZ_WHH + SZ_GCNW + SZ_ARENA + SZ_NODE + 2 * SZ_W + SZ_REP + 8192;

  if (ws_size < NEED) {
    diag_k<<<(out_size + 255) / 256, 256, 0, stream>>>(out, out_size,
                                                       (float)(ws_size >> 20));
    return;
  }

  char* p = (char*)d_ws;
  auto alloc = [&](size_t bytes) { char* r = p; p += (bytes + 255) & ~(size_t)255; return r; };
  __hip_bfloat16* whhbf  = (__hip_bfloat16*)alloc(SZ_WHH);
  __hip_bfloat16* gcnWbf = (__hip_bfloat16*)alloc(SZ_GCNW);  // [side][layer][512][512]
  char* arena = alloc(SZ_ARENA);
  float* node = (float*)alloc(SZ_NODE);
  float* wT   = (float*)alloc(SZ_W);
  float* wS   = (float*)alloc(SZ_W);
  float* rep  = (float*)alloc(SZ_REP);

  // phase-A (projections + rec) views of arena
  __hip_bfloat16* gi_t    = (__hip_bfloat16*)(arena);
  __hip_bfloat16* gi_c    = (__hip_bfloat16*)(arena + 19660800);
  __hip_bfloat16* embbf   = (__hip_bfloat16*)(arena + 98304000);   // [30000][304]
  __hip_bfloat16* wihbf_t = (__hip_bfloat16*)(arena + 116544000);  // [2][768][304]
  __hip_bfloat16* wihbf_c = (__hip_bfloat16*)(arena + 117477888);
  // phase-B (GCN) views of arena
  float*          tmpF   = (float*)(arena);                        // [z][250][512] f32
  __hip_bfloat16* tmpbf  = (__hip_bfloat16*)(arena + 65536000);
  __hip_bfloat16* corrbf = (__hip_bfloat16*)(arena + 98304000);    // [z][250][256]
  __hip_bfloat16* transT = (__hip_bfloat16*)(arena + 114688000);   // [z][512][256]
  __hip_bfloat16* nodebf = (__hip_bfloat16*)(arena + 148242432);   // [z][250][512]

  // once: Whh + GCN weights to bf16
  convwhh_k<<<6144, 256, 0, stream>>>(tgt_whh, tgc_whh, sgt_whh, sgc_whh, whhbf);
  convf2b4_k<<<512, 256, 0, stream>>>(gcnW_task,   whhbf ? (gcnWbf)          : nullptr, 131072);
  convf2b4_k<<<512, 256, 0, stream>>>(gcnW_shared, (__hip_bfloat16*)gcnWbf + 524288, 131072);

  auto runSide = [&](const int* tgtTok, const int* clmTok,
                     const float* wih_t, const float* bih_t, const float* bhh_t,
                     const float* wih_c, const float* bih_c, const float* bhh_c,
                     const __hip_bfloat16* whh4, const __hip_bfloat16* gcnWbf_side,
                     float* w, float* repSide) {
    // conversions (arena phase-A; re-run per side since GCN phase overwrites)
    convpad_k<<<dim3(2, 30000), 256, 0, stream>>>(emb, embbf, 300, 304);
    convpad_k<<<dim3(2, 1536), 256, 0, stream>>>(wih_t, wihbf_t, 300, 304);
    convpad_k<<<dim3(2, 1536), 256, 0, stream>>>(wih_c, wihbf_c, 300, 304);
    // projections: gi = emb[tok] @ Wih^T + bih  (bf16 out)
    {
      BGemmArgs ga{};
      ga.A = embbf; ga.idx = tgtTok; ga.B = wihbf_t; ga.bias = bih_t; ga.C = gi_t;
      ga.aStride = 0; ga.bStride = 768L * 304; ga.biasStride = 768;
      ga.cStride = 6400L * 768;
      ga.M = 6400; ga.N = 768; ga.Kreal = 304; ga.lda = 304; ga.ldb = 304; ga.ldc = 768;
      bgemm_k<true, 1><<<dim3(50, 6, 2), 256, 0, stream>>>(ga);
      ga.idx = clmTok; ga.B = wihbf_c; ga.bias = bih_c; ga.C = gi_c;
      ga.cStride = 25600L * 768; ga.M = 25600;
      bgemm_k<true, 1><<<dim3(200, 6, 2), 256, 0, stream>>>(ga);
    }
    // recurrence
    RecArgs ra{whh4, gi_t, gi_c, bhh_t, bhh_c, node};
    gru_rec_k<<<dim3(8, 1, 4), 512, 0, stream>>>(ra);
    // bf16 mirror of node + stance attention (pre-GCN)
    convf2b4_k<<<16000, 256, 0, stream>>>(node, nodebf, 4096000);
    attn_k<<<dim3(128), 256, 0, stream>>>(node, w);
    // GCN 2 layers
    for (int layer = 0; layer < 2; ++layer) {
      const __hip_bfloat16* inbf = layer ? tmpbf : nodebf;
      const float* resF = layer ? tmpF : node;
      float* outF = layer ? node : tmpF;
      __hip_bfloat16* outbf = layer ? nodebf : tmpbf;
      float* corrF = layer ? node : tmpF;   // dead region reused as f32 scratch
      // corr = node @ node^T (f32 out)
      BGemmArgs ca{};
      ca.A = inbf; ca.B = inbf; ca.C = corrF;
      ca.aStride = 128000; ca.bStride = 128000; ca.cStride = 64000;
      ca.M = 250; ca.N = 250; ca.Kreal = 512; ca.lda = 512; ca.ldb = 512; ca.ldc = 256;
      bgemm_k<false, 0><<<dim3(2, 2, 128), 256, 0, stream>>>(ca);
      softmaxbf_k<<<8000, 256, 0, stream>>>(corrF, corrbf);
      // trans^T = W @ node^T  (bf16 out, zero-pad cols 250..255)
      BGemmArgs ta{};
      ta.A = gcnWbf_side + (long)layer * 512 * 512; ta.B = inbf; ta.C = transT;
      ta.aStride = 0; ta.bStride = 128000; ta.cStride = 131072;
      ta.M = 512; ta.N = 250; ta.Kreal = 512; ta.lda = 512; ta.ldb = 512; ta.ldc = 256;
      bgemm_k<false, 3><<<dim3(4, 2, 128), 256, 0, stream>>>(ta);
      // out = relu(res + corr @ trans)  (f32 + bf16 dual write)
      BGemmArgs aa{};
      aa.A = corrbf; aa.B = transT; aa.C = outF; aa.C2 = outbf; aa.Res = resF;
      aa.aStride = 64000; aa.bStride = 131072; aa.cStride = 128000;
      aa.c2Stride = 128000; aa.rStride = 128000;
      aa.M = 250; aa.N = 512; aa.Kreal = 256; aa.lda = 256; aa.ldb = 256; aa.ldc = 512;
      bgemm_k<false, 2><<<dim3(2, 4, 128), 256, 0, stream>>>(aa);
    }
    // attention-weighted claim pooling (post-GCN node f32)
    rep_k<<<dim3(128), 256, 0, stream>>>(node, w, repSide);
  };

  runSide(task_target, task_claim,
          tgt_wih, tgt_bih, tgt_bhh, tgc_wih, tgc_bih, tgc_bhh,
          whhbf, gcnWbf, wT, rep);
  runSide(shared_target, shared_claim,
          sgt_wih, sgt_bih, sgt_bhh, sgc_wih, sgc_bih, sgc_bhh,
          whhbf + 4L * 768 * 256, gcnWbf + 524288, wS, rep + 128L * 512);

  final_k<<<dim3(128), 256, 0, stream>>>(rep, linW, linb, out);
}

// Round 8
// 2026.622 us; speedup vs baseline: 21.3561x; 1.5468x over previous
//
#include <hip/hip_runtime.h>
#include <hip/hip_bf16.h>

namespace {

constexpr int B_  = 128;
constexpr int TL  = 50, CL = 200, NNODE = 250;
constexpr int H_  = 256, D_ = 512;
constexpr long NODE_ELE = 128L * 250 * 512;   // per side

typedef __attribute__((ext_vector_type(8))) short bf16x8;
typedef __attribute__((ext_vector_type(4))) float f32x4;

__device__ inline float bits2f(unsigned v) { union { unsigned u; float f; } c; c.u = v; return c.f; }
__device__ inline unsigned short bfbits(float x) {
  __hip_bfloat16 b = __float2bfloat16(x);
  return *(unsigned short*)&b;
}
__device__ inline float bfsel(uint2 v, int r) {        // r-th bf16 of a 4-pack
  unsigned w = (r < 2) ? v.x : v.y;
  return bits2f((r & 1) ? (w & 0xFFFF0000u) : (w << 16));
}
__device__ inline float sigf(float x)  { return 1.f / (1.f + __expf(-x)); }
__device__ inline float tanhf_(float x){ return 1.f - 2.f / (__expf(2.f * x) + 1.f); }

// =============== bf16 MFMA GEMM: C[z] = A[z] @ B[z]^T (B is [N][K]) ===========
// OUT 0: f32 out. 1: +bias -> bf16. 2: +bf16 Res, relu -> f32 C AND bf16 C2.
// 3: bf16 out, zero-fill cols [N, 256). 4: +f32 Res, relu -> f32 C (in-place ok).
struct BGemmArgs {
  const __hip_bfloat16* A; const __hip_bfloat16* B;
  const int* idx; const float* bias; const void* Res;
  void* C; void* C2;
  long aStride, bStride, biasStride, cStride, c2Stride, rStride;
  int M, N, Kreal, lda, ldb, ldc;
};

template<bool GATHER, int OUT>
__global__ __launch_bounds__(256) void bgemm_k(BGemmArgs g) {
  __shared__ __align__(16) __hip_bfloat16 As[128 * 64];   // [r][k] XOR-swizzled
  __shared__ __align__(16) __hip_bfloat16 Bs[128 * 64];
  const int z = blockIdx.z;
  const int m0 = blockIdx.x * 128, n0 = blockIdx.y * 128;
  const int tid = threadIdx.x;
  const int lane = tid & 63, wv = tid >> 6;
  const int wr = wv >> 1, wc = wv & 1;                    // wave -> 64x64 quadrant
  const __hip_bfloat16* Ab = GATHER ? g.A : g.A + (long)z * g.aStride;
  const __hip_bfloat16* Bb = g.B + (long)z * g.bStride;
  const int sr = tid >> 3, so = tid & 7;                  // staging: row, col-octet
  f32x4 acc[4][4];
  #pragma unroll
  for (int i = 0; i < 4; ++i)
    #pragma unroll
    for (int j = 0; j < 4; ++j) acc[i][j] = (f32x4){0.f, 0.f, 0.f, 0.f};

  const int ktiles = (g.Kreal + 63) >> 6;
  for (int kt = 0; kt < ktiles; ++kt) {
    const int k0 = kt * 64;
    __syncthreads();
    #pragma unroll
    for (int p = 0; p < 4; ++p) {           // A tile 128x64
      int r = p * 32 + sr;
      int row = m0 + r;
      int kg = k0 + so * 8;
      uint4 v = make_uint4(0, 0, 0, 0);
      if (row < g.M && kg + 8 <= g.Kreal) {
        long ao = GATHER ? (long)g.idx[row] * g.lda : (long)row * g.lda;
        v = *(const uint4*)(Ab + ao + kg);
      }
      *(uint4*)((char*)As + ((r * 128 + so * 16) ^ ((r & 7) << 4))) = v;
    }
    #pragma unroll
    for (int p = 0; p < 4; ++p) {           // B tile 128x64 (rows = n)
      int r = p * 32 + sr;
      int row = n0 + r;
      int kg = k0 + so * 8;
      uint4 v = make_uint4(0, 0, 0, 0);
      if (row < g.N && kg + 8 <= g.Kreal)
        v = *(const uint4*)(Bb + (long)row * g.ldb + kg);
      *(uint4*)((char*)Bs + ((r * 128 + so * 16) ^ ((r & 7) << 4))) = v;
    }
    __syncthreads();
    #pragma unroll
    for (int ks = 0; ks < 2; ++ks) {
      bf16x8 af[4], bfr[4];
      #pragma unroll
      for (int i = 0; i < 4; ++i) {
        int ra = wr * 64 + i * 16 + (lane & 15);
        af[i] = *(const bf16x8*)((const char*)As +
                 ((ra * 128 + ks * 64 + (lane >> 4) * 16) ^ ((ra & 7) << 4)));
        int rb = wc * 64 + i * 16 + (lane & 15);
        bfr[i] = *(const bf16x8*)((const char*)Bs +
                 ((rb * 128 + ks * 64 + (lane >> 4) * 16) ^ ((rb & 7) << 4)));
      }
      #pragma unroll
      for (int i = 0; i < 4; ++i)
        #pragma unroll
        for (int j = 0; j < 4; ++j)
          acc[i][j] = __builtin_amdgcn_mfma_f32_16x16x32_bf16(af[i], bfr[j], acc[i][j], 0, 0, 0);
    }
  }
  // ---- epilogue: D col = lane&15 (n), row = (lane>>4)*4 + r (m) ----
  const long cz = (long)z * g.cStride;
  #pragma unroll
  for (int i = 0; i < 4; ++i) {
    int rbase = m0 + wr * 64 + i * 16 + ((lane >> 4) << 2);
    #pragma unroll
    for (int j = 0; j < 4; ++j) {
      int col = n0 + wc * 64 + j * 16 + (lane & 15);
      #pragma unroll
      for (int r = 0; r < 4; ++r) {
        int row = rbase + r;
        float v = acc[i][j][r];
        if (OUT == 0) {
          if (row < g.M && col < g.N)
            ((float*)g.C)[cz + (long)row * g.ldc + col] = v;
        } else if (OUT == 1) {
          if (row < g.M && col < g.N) {
            v += g.bias[(long)z * g.biasStride + col];
            ((__hip_bfloat16*)g.C)[cz + (long)row * g.ldc + col] = __float2bfloat16(v);
          }
        } else if (OUT == 2) {
          if (row < g.M && col < g.N) {
            v += __bfloat162float(((const __hip_bfloat16*)g.Res)
                     [(long)z * g.rStride + (long)row * g.ldc + col]);
            v = fmaxf(v, 0.f);
            ((float*)g.C)[cz + (long)row * g.ldc + col] = v;
            ((__hip_bfloat16*)g.C2)[(long)z * g.c2Stride + (long)row * g.ldc + col] =
                __float2bfloat16(v);
          }
        } else if (OUT == 3) {
          if (row < g.M)
            ((__hip_bfloat16*)g.C)[cz + (long)row * g.ldc + col] =
                __float2bfloat16(col < g.N ? v : 0.f);
        } else {  // OUT == 4: f32 res (in-place safe), relu, f32 out
          if (row < g.M && col < g.N) {
            v += ((const float*)g.Res)[(long)z * g.rStride + (long)row * g.ldc + col];
            v = fmaxf(v, 0.f);
            ((float*)g.C)[cz + (long)row * g.ldc + col] = v;
          }
        }
      }
    }
  }
}

// ---------------- conversions ----------------
__global__ __launch_bounds__(256) void convwhh_k(const float* tt, const float* tc,
                                                 const float* st, const float* sc,
                                                 __hip_bfloat16* o) {
  long i = (long)blockIdx.x * blockDim.x + threadIdx.x;
  const long per = 768L * 256;
  if (i >= 8 * per) return;
  int z = (int)(i / per);
  long rem = i - (long)z * per;
  const float* src = (z < 2) ? tt : (z < 4) ? tc : (z < 6) ? st : sc;
  o[i] = __float2bfloat16(src[(long)(z & 1) * per + rem]);
}

__global__ __launch_bounds__(256) void convpad_k(const float* src, __hip_bfloat16* dst,
                                                 int K, int Kp) {
  int c = blockIdx.x * 256 + threadIdx.x;
  long r = blockIdx.y;
  if (c < Kp) dst[r * Kp + c] = __float2bfloat16(c < K ? src[r * K + c] : 0.f);
}

__global__ __launch_bounds__(256) void convf2b4_k(const float* src, __hip_bfloat16* dst,
                                                  long n4) {
  long i = (long)blockIdx.x * 256 + threadIdx.x;
  if (i >= n4) return;
  float4 v = ((const float4*)src)[i];
  ushort4 o;
  o.x = bfbits(v.x); o.y = bfbits(v.y); o.z = bfbits(v.z); o.w = bfbits(v.w);
  ((ushort4*)dst)[i] = o;
}

// ---------------- GRU recurrence: MFMA persistent-RNN, ALL 8 chains ----------
// grid (8,1,8): z = side*4 + sq*2 + dir; blockIdx.x = 16-batch group (64 blocks).
// Node written directly as bf16 (hi half of the hi+lo fp32-quality state).
struct RecArgs {
  const __hip_bfloat16* whhbf;    // [8][768][256], order tgt01,tgc01,sgt01,sgc01
  const __hip_bfloat16* gi[4];    // {task_t, task_c, shared_t, shared_c}
  const float* bhh[4];
  __hip_bfloat16* nodebf;         // [2][128][250][512]
};

__global__ __launch_bounds__(512, 2) void gru_rec_k(RecArgs a) {
  __shared__ __align__(16) char hbuf[2][2][8192];
  __shared__ __align__(16) float bhhS[768];
  const int z = blockIdx.z;
  const int side = z >> 2, sq = (z >> 1) & 1, dir = z & 1;
  const int gidx = side * 2 + sq;
  const int T = sq ? CL : TL;
  const int toff = sq ? TL : 0;
  const __hip_bfloat16* gi = a.gi[gidx] + (long)dir * B_ * T * 768;
  const float* bhh = a.bhh[gidx] + dir * 768;
  const __hip_bfloat16* whh = a.whhbf + (long)z * 768 * 256;
  __hip_bfloat16* nodeb = a.nodebf + (long)side * NODE_ELE;
  const int b0 = blockIdx.x * 16;
  const int tid = threadIdx.x;
  const int lane = tid & 63, wv = tid >> 6;
  const int bcol = lane & 15, g4 = lane >> 4;
  const int u0 = wv * 32 + g4 * 4;
  const int swz = (bcol & 7) << 4;

  bf16x8 Af[3][2][8];
  #pragma unroll
  for (int g = 0; g < 3; ++g)
    #pragma unroll
    for (int h = 0; h < 2; ++h)
      #pragma unroll
      for (int kt = 0; kt < 8; ++kt) {
        int row = g * 256 + wv * 32 + h * 16 + bcol;
        int col = kt * 32 + g4 * 8;
        Af[g][h][kt] = *(const bf16x8*)(whh + (long)row * 256 + col);
      }
  *(uint4*)&hbuf[0][0][tid * 16] = make_uint4(0, 0, 0, 0);
  *(uint4*)&hbuf[0][1][tid * 16] = make_uint4(0, 0, 0, 0);
  for (int i = tid; i < 768; i += 512) bhhS[i] = bhh[i];
  __syncthreads();

  const __hip_bfloat16* gip = gi + ((long)(b0 + bcol) * T + (dir ? T - 1 : 0)) * 768 + u0;
  __hip_bfloat16* np = nodeb + ((long)(b0 + bcol) * NNODE + toff + (dir ? T - 1 : 0)) * D_
                       + dir * H_ + u0;
  const long gistep = (dir ? -768L : 768L);
  const long nstep  = (dir ? -(long)D_ : (long)D_);
  int cur = 0;

  for (int t = 0; t < T; ++t) {
    uint2 gv[3][2];
    #pragma unroll
    for (int g = 0; g < 3; ++g)
      #pragma unroll
      for (int h = 0; h < 2; ++h)
        gv[g][h] = *(const uint2*)(gip + g * 256 + h * 16);

    const char* hib = &hbuf[cur][0][0];
    const char* lob = &hbuf[cur][1][0];
    f32x4 c[3][2];
    #pragma unroll
    for (int g = 0; g < 3; ++g)
      #pragma unroll
      for (int h = 0; h < 2; ++h) c[g][h] = (f32x4){0.f, 0.f, 0.f, 0.f};
    const int rb = bcol * 512 + g4 * 16;
    #pragma unroll
    for (int kt = 0; kt < 8; ++kt) {
      bf16x8 bh = *(const bf16x8*)(hib + ((rb + kt * 64) ^ swz));
      bf16x8 bl = *(const bf16x8*)(lob + ((rb + kt * 64) ^ swz));
      #pragma unroll
      for (int g = 0; g < 3; ++g)
        #pragma unroll
        for (int h = 0; h < 2; ++h) {
          c[g][h] = __builtin_amdgcn_mfma_f32_16x16x32_bf16(Af[g][h][kt], bh, c[g][h], 0, 0, 0);
          c[g][h] = __builtin_amdgcn_mfma_f32_16x16x32_bf16(Af[g][h][kt], bl, c[g][h], 0, 0, 0);
        }
    }

    const int ob0 = bcol * 512 + u0 * 2;
    uint2 hh0 = *(const uint2*)(hib + (ob0 ^ swz));
    uint2 hl0 = *(const uint2*)(lob + (ob0 ^ swz));
    uint2 hh1 = *(const uint2*)(hib + ((ob0 + 32) ^ swz));
    uint2 hl1 = *(const uint2*)(lob + ((ob0 + 32) ^ swz));
    uint2 hiA[2], loA[2];
    #pragma unroll
    for (int h = 0; h < 2; ++h) {
      float4 br = *(const float4*)&bhhS[u0 + h * 16];
      float4 bz = *(const float4*)&bhhS[256 + u0 + h * 16];
      float4 bn = *(const float4*)&bhhS[512 + u0 + h * 16];
      uint2 hh = h ? hh1 : hh0;
      uint2 hl = h ? hl1 : hl0;
      float hn[4];
      #pragma unroll
      for (int r = 0; r < 4; ++r) {
        float brv = (r == 0) ? br.x : (r == 1) ? br.y : (r == 2) ? br.z : br.w;
        float bzv = (r == 0) ? bz.x : (r == 1) ? bz.y : (r == 2) ? bz.z : bz.w;
        float bnv = (r == 0) ? bn.x : (r == 1) ? bn.y : (r == 2) ? bn.z : bn.w;
        float hold = bfsel(hh, r) + bfsel(hl, r);
        float rr = sigf(bfsel(gv[0][h], r) + c[0][h][r] + brv);
        float zz = sigf(bfsel(gv[1][h], r) + c[1][h][r] + bzv);
        float nn = tanhf_(bfsel(gv[2][h], r) + rr * (c[2][h][r] + bnv));
        hn[r] = (1.f - zz) * nn + zz * hold;
      }
      unsigned short s0 = bfbits(hn[0]), s1 = bfbits(hn[1]);
      unsigned short s2 = bfbits(hn[2]), s3 = bfbits(hn[3]);
      float r0 = hn[0] - bits2f((unsigned)s0 << 16);
      float r1 = hn[1] - bits2f((unsigned)s1 << 16);
      float r2 = hn[2] - bits2f((unsigned)s2 << 16);
      float r3 = hn[3] - bits2f((unsigned)s3 << 16);
      hiA[h].x = (unsigned)s0 | ((unsigned)s1 << 16);
      hiA[h].y = (unsigned)s2 | ((unsigned)s3 << 16);
      loA[h].x = (unsigned)bfbits(r0) | ((unsigned)bfbits(r1) << 16);
      loA[h].y = (unsigned)bfbits(r2) | ((unsigned)bfbits(r3) << 16);
    }
    // node stores (bf16 = hi half; fire-and-forget)
    *(uint2*)np        = hiA[0];
    *(uint2*)(np + 16) = hiA[1];
    char* hibn = &hbuf[cur ^ 1][0][0];
    char* lobn = &hbuf[cur ^ 1][1][0];
    #pragma unroll
    for (int h = 0; h < 2; ++h) {
      *(uint2*)(hibn + ((ob0 + h * 32) ^ swz)) = hiA[h];
      *(uint2*)(lobn + ((ob0 + h * 32) ^ swz)) = loA[h];
    }
    gip += gistep;
    np  += nstep;
    asm volatile("s_waitcnt lgkmcnt(0)" ::: "memory");
    __builtin_amdgcn_sched_barrier(0);
    __builtin_amdgcn_s_barrier();
    cur ^= 1;
  }
}

// ---------------- attention over claims (bf16 node, both sides) ----------------
__global__ __launch_bounds__(256) void attn_k(const __hip_bfloat16* nodeAll,
                                              float* wT, float* wS) {
  int b = blockIdx.x, side = blockIdx.y;
  const __hip_bfloat16* node = nodeAll + (long)side * NODE_ELE;
  float* w = side ? wS : wT;
  __shared__ float tl[512];
  __shared__ float sc[CL];
  int tid = threadIdx.x;
  {
    const __hip_bfloat16* tr = node + ((long)b * NNODE + (TL - 1)) * D_;
    tl[tid]       = __bfloat162float(tr[tid]);
    tl[tid + 256] = __bfloat162float(tr[tid + 256]);
  }
  __syncthreads();
  int wid = tid >> 6, lane = tid & 63;
  for (int c = wid; c < CL; c += 4) {
    const __hip_bfloat16* row = node + ((long)b * NNODE + TL + c) * D_;
    uint4 v = *(const uint4*)(row + lane * 8);
    const float* tp = &tl[lane * 8];
    float acc = bits2f(v.x << 16)         * tp[0] + bits2f(v.x & 0xFFFF0000u) * tp[1]
              + bits2f(v.y << 16)         * tp[2] + bits2f(v.y & 0xFFFF0000u) * tp[3]
              + bits2f(v.z << 16)         * tp[4] + bits2f(v.z & 0xFFFF0000u) * tp[5]
              + bits2f(v.w << 16)         * tp[6] + bits2f(v.w & 0xFFFF0000u) * tp[7];
    #pragma unroll
    for (int o = 32; o; o >>= 1) acc += __shfl_xor(acc, o, 64);
    if (lane == 0) sc[c] = acc;
  }
  __syncthreads();
  if (wid == 0) {
    float v[4]; float m = -1e30f;
    #pragma unroll
    for (int i = 0; i < 4; ++i) {
      int c = lane + 64 * i;
      v[i] = (c < CL) ? sc[c] : -1e30f;
      m = fmaxf(m, v[i]);
    }
    #pragma unroll
    for (int o = 32; o; o >>= 1) m = fmaxf(m, __shfl_xor(m, o, 64));
    float s = 0.f;
    #pragma unroll
    for (int i = 0; i < 4; ++i) {
      int c = lane + 64 * i;
      v[i] = (c < CL) ? expf(v[i] - m) : 0.f;
      s += v[i];
    }
    #pragma unroll
    for (int o = 32; o; o >>= 1) s += __shfl_xor(s, o, 64);
    float inv = 1.f / s;
    #pragma unroll
    for (int i = 0; i < 4; ++i) {
      int c = lane + 64 * i;
      if (c < CL) w[(long)b * CL + c] = v[i] * inv;
    }
  }
}

// ---------------- row softmax: f32 in (ld 256, len 250) -> bf16 out, 0-pad ----
__global__ __launch_bounds__(256) void softmaxbf_k(const float* in, __hip_bfloat16* out) {
  int row = blockIdx.x * 4 + (threadIdx.x >> 6);
  int lane = threadIdx.x & 63;
  const float* p = in + (long)row * 256;
  __hip_bfloat16* q = out + (long)row * 256;
  float v[4]; float m = -1e30f;
  #pragma unroll
  for (int i = 0; i < 4; ++i) {
    int c = lane + i * 64;
    v[i] = (c < 250) ? p[c] : -1e30f;
    m = fmaxf(m, v[i]);
  }
  #pragma unroll
  for (int o = 32; o; o >>= 1) m = fmaxf(m, __shfl_xor(m, o, 64));
  float s = 0.f;
  #pragma unroll
  for (int i = 0; i < 4; ++i) {
    int c = lane + i * 64;
    if (c < 250) { v[i] = __expf(v[i] - m); s += v[i]; }
  }
  #pragma unroll
  for (int o = 32; o; o >>= 1) s += __shfl_xor(s, o, 64);
  float inv = 1.f / s;
  #pragma unroll
  for (int i = 0; i < 4; ++i) {
    int c = lane + i * 64;
    q[c] = __float2bfloat16((c < 250) ? v[i] * inv : 0.f);
  }
}

// ---------------- weighted claim pooling (f32 post-GCN node) ----------------
__global__ __launch_bounds__(256) void rep_k(const float* node, const float* w,
                                             float* repSide) {
  int b = blockIdx.x;
  __shared__ float wl[CL];
  int tid = threadIdx.x;
  if (tid < CL) wl[tid] = w[(long)b * CL + tid];
  __syncthreads();
  #pragma unroll
  for (int h = 0; h < 2; ++h) {
    int d = tid + h * 256;
    float acc = 0.f;
    for (int c = 0; c < CL; ++c)
      acc = fmaf(wl[c], node[((long)b * NNODE + TL + c) * D_ + d], acc);
    repSide[(long)b * D_ + d] = acc;
  }
}

// ---------------- final linear ----------------
__global__ __launch_bounds__(256) void final_k(const float* rep, const float* linW,
                                               const float* linb, float* out) {
  int b = blockIdx.x, tid = threadIdx.x;
  float a0 = 0.f, a1 = 0.f, a2 = 0.f;
  for (int d = tid; d < 1024; d += 256) {
    float x = rep[(long)(d >> 9) * (B_ * D_) + (long)b * D_ + (d & 511)];
    a0 = fmaf(x, linW[d], a0);
    a1 = fmaf(x, linW[1024 + d], a1);
    a2 = fmaf(x, linW[2048 + d], a2);
  }
  #pragma unroll
  for (int o = 32; o; o >>= 1) {
    a0 += __shfl_xor(a0, o, 64);
    a1 += __shfl_xor(a1, o, 64);
    a2 += __shfl_xor(a2, o, 64);
  }
  __shared__ float red[3][4];
  int wid = tid >> 6, lane = tid & 63;
  if (lane == 0) { red[0][wid] = a0; red[1][wid] = a1; red[2][wid] = a2; }
  __syncthreads();
  if (tid == 0) {
    out[b * 3 + 0] = red[0][0] + red[0][1] + red[0][2] + red[0][3] + linb[0];
    out[b * 3 + 1] = red[1][0] + red[1][1] + red[1][2] + red[1][3] + linb[1];
    out[b * 3 + 2] = red[2][0] + red[2][1] + red[2][2] + red[2][3] + linb[2];
  }
}

// ---------------- diagnostic ----------------
__global__ void diag_k(float* out, int n, float v) {
  int i = blockIdx.x * blockDim.x + threadIdx.x;
  if (i < n) out[i] = v;
}

} // namespace

extern "C" void kernel_launch(void* const* d_in, const int* in_sizes, int n_in,
                              void* d_out, int out_size, void* d_ws, size_t ws_size,
                              hipStream_t stream) {
  const int* task_target   = (const int*)d_in[1];
  const int* shared_target = (const int*)d_in[2];
  const int* task_claim    = (const int*)d_in[3];
  const int* shared_claim  = (const int*)d_in[4];
  const float* emb      = (const float*)d_in[9];
  const float* tgt_wih  = (const float*)d_in[10];
  const float* tgt_whh  = (const float*)d_in[11];
  const float* tgt_bih  = (const float*)d_in[12];
  const float* tgt_bhh  = (const float*)d_in[13];
  const float* tgc_wih  = (const float*)d_in[14];
  const float* tgc_whh  = (const float*)d_in[15];
  const float* tgc_bih  = (const float*)d_in[16];
  const float* tgc_bhh  = (const float*)d_in[17];
  const float* sgt_wih  = (const float*)d_in[18];
  const float* sgt_whh  = (const float*)d_in[19];
  const float* sgt_bih  = (const float*)d_in[20];
  const float* sgt_bhh  = (const float*)d_in[21];
  const float* sgc_wih  = (const float*)d_in[22];
  const float* sgc_whh  = (const float*)d_in[23];
  const float* sgc_bih  = (const float*)d_in[24];
  const float* sgc_bhh  = (const float*)d_in[25];
  const float* gcnW_task   = (const float*)d_in[26];
  const float* gcnW_shared = (const float*)d_in[27];
  const float* linW = (const float*)d_in[28];
  const float* linb = (const float*)d_in[29];
  float* out = (float*)d_out;

  // ---- workspace plan (bytes); total 268,115,968 <= 256 MiB ----
  const size_t SZ_WHH   = 3145728;
  const size_t SZ_GCNW  = 2097152;
  const size_t SZ_ARENA = 196608000;    // gi all 4 (phase A) / GCN scratch (phase B)
  const size_t SZ_NODE  = 65536000;     // 2 sides x 128x250x512 bf16
  const size_t SZ_W     = 102400;
  const size_t SZ_REP   = 524288;
  const size_t NEED = SZ_WHH + SZ_GCNW + SZ_ARENA + SZ_NODE + 2 * SZ_W + SZ_REP + 4096;

  if (ws_size < NEED) {
    diag_k<<<(out_size + 255) / 256, 256, 0, stream>>>(out, out_size,
                                                       (float)(ws_size >> 20));
    return;
  }

  char* p = (char*)d_ws;
  auto alloc = [&](size_t bytes) { char* r = p; p += (bytes + 255) & ~(size_t)255; return r; };
  __hip_bfloat16* whhbf  = (__hip_bfloat16*)alloc(SZ_WHH);
  __hip_bfloat16* gcnWbf = (__hip_bfloat16*)alloc(SZ_GCNW);   // [side][layer][512][512]
  char* arena  = alloc(SZ_ARENA);
  char* nodeC  = alloc(SZ_NODE);
  float* wT    = (float*)alloc(SZ_W);
  float* wS    = (float*)alloc(SZ_W);
  float* rep   = (float*)alloc(SZ_REP);
  __hip_bfloat16* nodebf = (__hip_bfloat16*)nodeC;

  // phase-A views: gi for all 4 GRUs in arena; emb/wih conversions alias nodebf
  __hip_bfloat16* gi_tt = (__hip_bfloat16*)(arena);                  // 19,660,800
  __hip_bfloat16* gi_tc = (__hip_bfloat16*)(arena + 19660800);       // 78,643,200
  __hip_bfloat16* gi_st = (__hip_bfloat16*)(arena + 98304000);
  __hip_bfloat16* gi_sc = (__hip_bfloat16*)(arena + 117964800);
  __hip_bfloat16* embbf = (__hip_bfloat16*)(nodeC);                  // [30000][304]
  __hip_bfloat16* wihbf[4] = {                                       // [2][768][304] each
    (__hip_bfloat16*)(nodeC + 18240000),
    (__hip_bfloat16*)(nodeC + 19173888),
    (__hip_bfloat16*)(nodeC + 20107776),
    (__hip_bfloat16*)(nodeC + 21041664)};
  // phase-B (GCN) views of arena
  float*          tmpF   = (float*)(arena);                          // [z][250][512] f32
  __hip_bfloat16* tmpbf  = (__hip_bfloat16*)(arena + 65536000);
  float*          corrF  = (float*)(arena + 98304000);               // [z][250][256] f32
  __hip_bfloat16* corrbf = (__hip_bfloat16*)(arena + 131072000);
  __hip_bfloat16* transT = (__hip_bfloat16*)(arena + 147456000);     // [z][512][256]
  __hip_bfloat16* dump   = (__hip_bfloat16*)(arena + 98304000);      // layer-2 C2 sink

  // ---- conversions (once) ----
  convwhh_k<<<6144, 256, 0, stream>>>(tgt_whh, tgc_whh, sgt_whh, sgc_whh, whhbf);
  convf2b4_k<<<512, 256, 0, stream>>>(gcnW_task,   gcnWbf,          131072);
  convf2b4_k<<<512, 256, 0, stream>>>(gcnW_shared, gcnWbf + 524288, 131072);
  convpad_k<<<dim3(2, 30000), 256, 0, stream>>>(emb, embbf, 300, 304);
  convpad_k<<<dim3(2, 1536), 256, 0, stream>>>(tgt_wih, wihbf[0], 300, 304);
  convpad_k<<<dim3(2, 1536), 256, 0, stream>>>(tgc_wih, wihbf[1], 300, 304);
  convpad_k<<<dim3(2, 1536), 256, 0, stream>>>(sgt_wih, wihbf[2], 300, 304);
  convpad_k<<<dim3(2, 1536), 256, 0, stream>>>(sgc_wih, wihbf[3], 300, 304);

  // ---- projections: gi = emb[tok] @ Wih^T + bih (bf16) ----
  auto proj = [&](const int* idx, __hip_bfloat16* wih, const float* bih,
                  __hip_bfloat16* gi, int Mrows, int gx) {
    BGemmArgs ga{};
    ga.A = embbf; ga.idx = idx; ga.B = wih; ga.bias = bih; ga.C = gi;
    ga.aStride = 0; ga.bStride = 768L * 304; ga.biasStride = 768;
    ga.cStride = (long)Mrows * 768;
    ga.M = Mrows; ga.N = 768; ga.Kreal = 304; ga.lda = 304; ga.ldb = 304; ga.ldc = 768;
    bgemm_k<true, 1><<<dim3(gx, 6, 2), 256, 0, stream>>>(ga);
  };
  proj(task_target,   wihbf[0], tgt_bih, gi_tt, 6400, 50);
  proj(task_claim,    wihbf[1], tgc_bih, gi_tc, 25600, 200);
  proj(shared_target, wihbf[2], sgt_bih, gi_st, 6400, 50);
  proj(shared_claim,  wihbf[3], sgc_bih, gi_sc, 25600, 200);

  // ---- all 8 GRU chains in ONE dispatch (writes nodebf over emb/wih alias) ----
  RecArgs ra;
  ra.whhbf = whhbf;
  ra.gi[0] = gi_tt; ra.gi[1] = gi_tc; ra.gi[2] = gi_st; ra.gi[3] = gi_sc;
  ra.bhh[0] = tgt_bhh; ra.bhh[1] = tgc_bhh; ra.bhh[2] = sgt_bhh; ra.bhh[3] = sgc_bhh;
  ra.nodebf = nodebf;
  gru_rec_k<<<dim3(8, 1, 8), 512, 0, stream>>>(ra);

  // ---- stance attention, both sides ----
  attn_k<<<dim3(128, 2), 256, 0, stream>>>(nodebf, wT, wS);

  // ---- GCN 2 layers per side + pooling (arena phase B; gi dead) ----
  for (int s = 0; s < 2; ++s) {
    const __hip_bfloat16* nbf = nodebf + (long)s * NODE_ELE;
    for (int layer = 0; layer < 2; ++layer) {
      const __hip_bfloat16* inbf = layer ? tmpbf : nbf;
      const __hip_bfloat16* Wl = gcnWbf + ((long)s * 2 + layer) * 262144;
      BGemmArgs ca{};   // corr = in @ in^T (f32)
      ca.A = inbf; ca.B = inbf; ca.C = corrF;
      ca.aStride = 128000; ca.bStride = 128000; ca.cStride = 64000;
      ca.M = 250; ca.N = 250; ca.Kreal = 512; ca.lda = 512; ca.ldb = 512; ca.ldc = 256;
      bgemm_k<false, 0><<<dim3(2, 2, 128), 256, 0, stream>>>(ca);
      softmaxbf_k<<<8000, 256, 0, stream>>>(corrF, corrbf);
      BGemmArgs ta{};   // trans^T = W @ in^T (bf16, 0-pad cols 250..255)
      ta.A = Wl; ta.B = inbf; ta.C = transT;
      ta.aStride = 0; ta.bStride = 128000; ta.cStride = 131072;
      ta.M = 512; ta.N = 250; ta.Kreal = 512; ta.lda = 512; ta.ldb = 512; ta.ldc = 256;
      bgemm_k<false, 3><<<dim3(4, 2, 128), 256, 0, stream>>>(ta);
      BGemmArgs aa{};   // out = relu(res + corr @ trans)
      aa.A = corrbf; aa.B = transT;
      aa.aStride = 64000; aa.bStride = 131072; aa.cStride = 128000;
      aa.c2Stride = 128000; aa.rStride = 128000;
      aa.M = 250; aa.N = 512; aa.Kreal = 256; aa.lda = 256; aa.ldb = 256; aa.ldc = 512;
      if (layer == 0) {   // res = pre-GCN node (bf16); out -> f32 tmpF + bf16 tmpbf
        aa.Res = nbf; aa.C = tmpF; aa.C2 = tmpbf;
        bgemm_k<false, 2><<<dim3(2, 4, 128), 256, 0, stream>>>(aa);
      } else {            // res = tmpF (f32); out -> tmpF in-place (f32 for pooling)
        aa.Res = tmpF; aa.C = tmpF; aa.C2 = dump;
        bgemm_k<false, 4><<<dim3(2, 4, 128), 256, 0, stream>>>(aa);
      }
    }
    rep_k<<<dim3(128), 256, 0, stream>>>(tmpF, s ? wS : wT, rep + (long)s * 128 * 512);
  }

  final_k<<<dim3(128), 256, 0, stream>>>(rep, linW, linb, out);
}

// Round 9
// 1985.544 us; speedup vs baseline: 21.7979x; 1.0207x over previous
//
#include <hip/hip_runtime.h>
#include <hip/hip_bf16.h>

namespace {

constexpr int B_  = 128;
constexpr int TL  = 50, CL = 200, NNODE = 250;
constexpr int H_  = 256, D_ = 512;
constexpr long NODE_ELE = 128L * 250 * 512;   // per side

typedef __attribute__((ext_vector_type(8))) short bf16x8;
typedef __attribute__((ext_vector_type(4))) float f32x4;

__device__ inline float bits2f(unsigned v) { union { unsigned u; float f; } c; c.u = v; return c.f; }
__device__ inline unsigned f2bits(float x) { union { float f; unsigned u; } c; c.f = x; return c.u; }
__device__ inline unsigned short bfbits(float x) {
  __hip_bfloat16 b = __float2bfloat16(x);
  return *(unsigned short*)&b;
}
__device__ inline float bfsel(uint2 v, int r) {        // r-th bf16 of a 4-pack
  unsigned w = (r < 2) ? v.x : v.y;
  return bits2f((r & 1) ? (w & 0xFFFF0000u) : (w << 16));
}
__device__ inline float sigf(float x)  { return 1.f / (1.f + __expf(-x)); }
__device__ inline float tanhf_(float x){ return 1.f - 2.f / (__expf(2.f * x) + 1.f); }

// =============== bf16 MFMA GEMM: C[z] = A[z] @ B[z]^T (B is [N][K]) ===========
// OUT 0: f32 out. 1: +bias -> bf16. 2: +bf16 Res, relu -> f32 C AND bf16 C2.
// 3: bf16 out, zero-fill cols [N, 256). 4: +f32 Res, relu -> f32 C (in-place ok).
struct BGemmArgs {
  const __hip_bfloat16* A; const __hip_bfloat16* B;
  const int* idx; const float* bias; const void* Res;
  void* C; void* C2;
  long aStride, bStride, biasStride, cStride, c2Stride, rStride;
  int M, N, Kreal, lda, ldb, ldc;
};

template<bool GATHER, int OUT>
__global__ __launch_bounds__(256) void bgemm_k(BGemmArgs g) {
  __shared__ __align__(16) __hip_bfloat16 As[128 * 64];   // [r][k] XOR-swizzled
  __shared__ __align__(16) __hip_bfloat16 Bs[128 * 64];
  const int z = blockIdx.z;
  const int m0 = blockIdx.x * 128, n0 = blockIdx.y * 128;
  const int tid = threadIdx.x;
  const int lane = tid & 63, wv = tid >> 6;
  const int wr = wv >> 1, wc = wv & 1;                    // wave -> 64x64 quadrant
  const __hip_bfloat16* Ab = GATHER ? g.A : g.A + (long)z * g.aStride;
  const __hip_bfloat16* Bb = g.B + (long)z * g.bStride;
  const int sr = tid >> 3, so = tid & 7;                  // staging: row, col-octet
  f32x4 acc[4][4];
  #pragma unroll
  for (int i = 0; i < 4; ++i)
    #pragma unroll
    for (int j = 0; j < 4; ++j) acc[i][j] = (f32x4){0.f, 0.f, 0.f, 0.f};

  const int ktiles = (g.Kreal + 63) >> 6;
  for (int kt = 0; kt < ktiles; ++kt) {
    const int k0 = kt * 64;
    __syncthreads();
    #pragma unroll
    for (int p = 0; p < 4; ++p) {           // A tile 128x64
      int r = p * 32 + sr;
      int row = m0 + r;
      int kg = k0 + so * 8;
      uint4 v = make_uint4(0, 0, 0, 0);
      if (row < g.M && kg + 8 <= g.Kreal) {
        long ao = GATHER ? (long)g.idx[row] * g.lda : (long)row * g.lda;
        v = *(const uint4*)(Ab + ao + kg);
      }
      *(uint4*)((char*)As + ((r * 128 + so * 16) ^ ((r & 7) << 4))) = v;
    }
    #pragma unroll
    for (int p = 0; p < 4; ++p) {           // B tile 128x64 (rows = n)
      int r = p * 32 + sr;
      int row = n0 + r;
      int kg = k0 + so * 8;
      uint4 v = make_uint4(0, 0, 0, 0);
      if (row < g.N && kg + 8 <= g.Kreal)
        v = *(const uint4*)(Bb + (long)row * g.ldb + kg);
      *(uint4*)((char*)Bs + ((r * 128 + so * 16) ^ ((r & 7) << 4))) = v;
    }
    __syncthreads();
    #pragma unroll
    for (int ks = 0; ks < 2; ++ks) {
      bf16x8 af[4], bfr[4];
      #pragma unroll
      for (int i = 0; i < 4; ++i) {
        int ra = wr * 64 + i * 16 + (lane & 15);
        af[i] = *(const bf16x8*)((const char*)As +
                 ((ra * 128 + ks * 64 + (lane >> 4) * 16) ^ ((ra & 7) << 4)));
        int rb = wc * 64 + i * 16 + (lane & 15);
        bfr[i] = *(const bf16x8*)((const char*)Bs +
                 ((rb * 128 + ks * 64 + (lane >> 4) * 16) ^ ((rb & 7) << 4)));
      }
      #pragma unroll
      for (int i = 0; i < 4; ++i)
        #pragma unroll
        for (int j = 0; j < 4; ++j)
          acc[i][j] = __builtin_amdgcn_mfma_f32_16x16x32_bf16(af[i], bfr[j], acc[i][j], 0, 0, 0);
    }
  }
  // ---- epilogue: D col = lane&15 (n), row = (lane>>4)*4 + r (m) ----
  const long cz = (long)z * g.cStride;
  #pragma unroll
  for (int i = 0; i < 4; ++i) {
    int rbase = m0 + wr * 64 + i * 16 + ((lane >> 4) << 2);
    #pragma unroll
    for (int j = 0; j < 4; ++j) {
      int col = n0 + wc * 64 + j * 16 + (lane & 15);
      #pragma unroll
      for (int r = 0; r < 4; ++r) {
        int row = rbase + r;
        float v = acc[i][j][r];
        if (OUT == 0) {
          if (row < g.M && col < g.N)
            ((float*)g.C)[cz + (long)row * g.ldc + col] = v;
        } else if (OUT == 1) {
          if (row < g.M && col < g.N) {
            v += g.bias[(long)z * g.biasStride + col];
            ((__hip_bfloat16*)g.C)[cz + (long)row * g.ldc + col] = __float2bfloat16(v);
          }
        } else if (OUT == 2) {
          if (row < g.M && col < g.N) {
            v += __bfloat162float(((const __hip_bfloat16*)g.Res)
                     [(long)z * g.rStride + (long)row * g.ldc + col]);
            v = fmaxf(v, 0.f);
            ((float*)g.C)[cz + (long)row * g.ldc + col] = v;
            ((__hip_bfloat16*)g.C2)[(long)z * g.c2Stride + (long)row * g.ldc + col] =
                __float2bfloat16(v);
          }
        } else if (OUT == 3) {
          if (row < g.M)
            ((__hip_bfloat16*)g.C)[cz + (long)row * g.ldc + col] =
                __float2bfloat16(col < g.N ? v : 0.f);
        } else {  // OUT == 4: f32 res (in-place safe), relu, f32 out
          if (row < g.M && col < g.N) {
            v += ((const float*)g.Res)[(long)z * g.rStride + (long)row * g.ldc + col];
            v = fmaxf(v, 0.f);
            ((float*)g.C)[cz + (long)row * g.ldc + col] = v;
          }
        }
      }
    }
  }
}

// ---------------- conversions ----------------
__global__ __launch_bounds__(256) void convwhh_k(const float* tt, const float* tc,
                                                 const float* st, const float* sc,
                                                 __hip_bfloat16* o) {
  long i = (long)blockIdx.x * blockDim.x + threadIdx.x;
  const long per = 768L * 256;
  if (i >= 8 * per) return;
  int z = (int)(i / per);
  long rem = i - (long)z * per;
  const float* src = (z < 2) ? tt : (z < 4) ? tc : (z < 6) ? st : sc;
  o[i] = __float2bfloat16(src[(long)(z & 1) * per + rem]);
}

__global__ __launch_bounds__(256) void convpad_k(const float* src, __hip_bfloat16* dst,
                                                 int K, int Kp) {
  int c = blockIdx.x * 256 + threadIdx.x;
  long r = blockIdx.y;
  if (c < Kp) dst[r * Kp + c] = __float2bfloat16(c < K ? src[r * K + c] : 0.f);
}

__global__ __launch_bounds__(256) void convf2b4_k(const float* src, __hip_bfloat16* dst,
                                                  long n4) {
  long i = (long)blockIdx.x * 256 + threadIdx.x;
  if (i >= n4) return;
  float4 v = ((const float4*)src)[i];
  ushort4 o;
  o.x = bfbits(v.x); o.y = bfbits(v.y); o.z = bfbits(v.z); o.w = bfbits(v.w);
  ((ushort4*)dst)[i] = o;
}

// ---------------- GRU recurrence: MFMA persistent-RNN, ALL 8 chains ----------
// grid (8,1,8): z = side*4 + sq*2 + dir; blockIdx.x = 16-batch group (64 blocks).
// Thread keeps its 8 h-units in f32 registers across steps (no LDS read-back);
// h mirrored to LDS as bf16 hi+lo (cheap round-half-up + residual packing) for
// the MFMA B operand. gi for step t+1 issued right after activation -> HBM
// latency hides under pack + barrier + next MFMA phase.
struct RecArgs {
  const __hip_bfloat16* whhbf;    // [8][768][256], order tgt01,tgc01,sgt01,sgc01
  const __hip_bfloat16* gi[4];    // {task_t, task_c, shared_t, shared_c}
  const float* bhh[4];
  __hip_bfloat16* nodebf;         // [2][128][250][512]
};

__global__ __launch_bounds__(512, 2) void gru_rec_k(RecArgs a) {
  __shared__ __align__(16) char hbuf[2][2][8192];
  __shared__ __align__(16) float bhhS[768];
  const int z = blockIdx.z;
  const int side = z >> 2, sq = (z >> 1) & 1, dir = z & 1;
  const int gidx = side * 2 + sq;
  const int T = sq ? CL : TL;
  const int toff = sq ? TL : 0;
  const __hip_bfloat16* gi = a.gi[gidx] + (long)dir * B_ * T * 768;
  const float* bhh = a.bhh[gidx] + dir * 768;
  const __hip_bfloat16* whh = a.whhbf + (long)z * 768 * 256;
  __hip_bfloat16* nodeb = a.nodebf + (long)side * NODE_ELE;
  const int b0 = blockIdx.x * 16;
  const int tid = threadIdx.x;
  const int lane = tid & 63, wv = tid >> 6;
  const int bcol = lane & 15, g4 = lane >> 4;
  const int u0 = wv * 32 + g4 * 4;
  const int swz = (bcol & 15) << 4;   // full 4-bit XOR: bijective within 512B row

  bf16x8 Af[3][2][8];
  #pragma unroll
  for (int g = 0; g < 3; ++g)
    #pragma unroll
    for (int h = 0; h < 2; ++h)
      #pragma unroll
      for (int kt = 0; kt < 8; ++kt) {
        int row = g * 256 + wv * 32 + h * 16 + bcol;
        int col = kt * 32 + g4 * 8;
        Af[g][h][kt] = *(const bf16x8*)(whh + (long)row * 256 + col);
      }
  *(uint4*)&hbuf[0][0][tid * 16] = make_uint4(0, 0, 0, 0);
  *(uint4*)&hbuf[0][1][tid * 16] = make_uint4(0, 0, 0, 0);
  for (int i = tid; i < 768; i += 512) bhhS[i] = bhh[i];
  __syncthreads();

  const __hip_bfloat16* gip = gi + ((long)(b0 + bcol) * T + (dir ? T - 1 : 0)) * 768 + u0;
  __hip_bfloat16* np = nodeb + ((long)(b0 + bcol) * NNODE + toff + (dir ? T - 1 : 0)) * D_
                       + dir * H_ + u0;
  const long gistep = (dir ? -768L : 768L);
  const long nstep  = (dir ? -(long)D_ : (long)D_);
  int cur = 0;

  float hreg[2][4];                      // this thread's 8 h-units, exact f32
  #pragma unroll
  for (int h = 0; h < 2; ++h)
    #pragma unroll
    for (int r = 0; r < 4; ++r) hreg[h][r] = 0.f;

  // gi preload for t=0
  uint2 gv[3][2];
  #pragma unroll
  for (int g = 0; g < 3; ++g)
    #pragma unroll
    for (int h = 0; h < 2; ++h)
      gv[g][h] = *(const uint2*)(gip + g * 256 + h * 16);

  for (int t = 0; t < T; ++t) {
    // ---- MFMA: gates for (this wave's 32 units) x (16 batch) ----
    const char* hib = &hbuf[cur][0][0];
    const char* lob = &hbuf[cur][1][0];
    f32x4 c[3][2];
    #pragma unroll
    for (int g = 0; g < 3; ++g)
      #pragma unroll
      for (int h = 0; h < 2; ++h) c[g][h] = (f32x4){0.f, 0.f, 0.f, 0.f};
    const int rb = bcol * 512 + g4 * 16;
    #pragma unroll
    for (int kt = 0; kt < 8; ++kt) {
      bf16x8 bh = *(const bf16x8*)(hib + ((rb + kt * 64) ^ swz));
      bf16x8 bl = *(const bf16x8*)(lob + ((rb + kt * 64) ^ swz));
      #pragma unroll
      for (int g = 0; g < 3; ++g)
        #pragma unroll
        for (int h = 0; h < 2; ++h) {
          c[g][h] = __builtin_amdgcn_mfma_f32_16x16x32_bf16(Af[g][h][kt], bh, c[g][h], 0, 0, 0);
          c[g][h] = __builtin_amdgcn_mfma_f32_16x16x32_bf16(Af[g][h][kt], bl, c[g][h], 0, 0, 0);
        }
    }

    // ---- activation (h_old from registers; D-frag in-lane) ----
    #pragma unroll
    for (int h = 0; h < 2; ++h) {
      float4 br = *(const float4*)&bhhS[u0 + h * 16];
      float4 bz = *(const float4*)&bhhS[256 + u0 + h * 16];
      float4 bn = *(const float4*)&bhhS[512 + u0 + h * 16];
      #pragma unroll
      for (int r = 0; r < 4; ++r) {
        float brv = (r == 0) ? br.x : (r == 1) ? br.y : (r == 2) ? br.z : br.w;
        float bzv = (r == 0) ? bz.x : (r == 1) ? bz.y : (r == 2) ? bz.z : bz.w;
        float bnv = (r == 0) ? bn.x : (r == 1) ? bn.y : (r == 2) ? bn.z : bn.w;
        float rr = sigf(bfsel(gv[0][h], r) + c[0][h][r] + brv);
        float zz = sigf(bfsel(gv[1][h], r) + c[1][h][r] + bzv);
        float nn = tanhf_(bfsel(gv[2][h], r) + rr * (c[2][h][r] + bnv));
        hreg[h][r] = (1.f - zz) * nn + zz * hreg[h][r];
      }
    }

    // ---- issue gi loads for t+1 (in flight across pack+barrier+next MFMA) ----
    {
      const __hip_bfloat16* gn = (t + 1 < T) ? gip + gistep : gip;
      gip = gn;
      #pragma unroll
      for (int g = 0; g < 3; ++g)
        #pragma unroll
        for (int h = 0; h < 2; ++h)
          gv[g][h] = *(const uint2*)(gn + g * 256 + h * 16);
    }

    // ---- pack hi (round-half-up) + lo (exact residual, trunc); store ----
    const int ob0 = bcol * 512 + u0 * 2;
    char* hibn = &hbuf[cur ^ 1][0][0];
    char* lobn = &hbuf[cur ^ 1][1][0];
    #pragma unroll
    for (int h = 0; h < 2; ++h) {
      unsigned hb[4], u[4];
      #pragma unroll
      for (int r = 0; r < 4; ++r) {
        u[r] = f2bits(hreg[h][r]);
        hb[r] = (u[r] + 0x8000u) & 0xFFFF0000u;
      }
      uint2 hiw, low;
      hiw.x = (hb[0] >> 16) | hb[1];
      hiw.y = (hb[2] >> 16) | hb[3];
      unsigned l0 = f2bits(hreg[h][0] - bits2f(hb[0]));
      unsigned l1 = f2bits(hreg[h][1] - bits2f(hb[1]));
      unsigned l2 = f2bits(hreg[h][2] - bits2f(hb[2]));
      unsigned l3 = f2bits(hreg[h][3] - bits2f(hb[3]));
      low.x = (l0 >> 16) | (l1 & 0xFFFF0000u);
      low.y = (l2 >> 16) | (l3 & 0xFFFF0000u);
      // node store (bf16 = hi half; fire-and-forget)
      *(uint2*)(np + h * 16) = hiw;
      *(uint2*)(hibn + ((ob0 + h * 32) ^ swz)) = hiw;
      *(uint2*)(lobn + ((ob0 + h * 32) ^ swz)) = low;
    }
    np += nstep;
    asm volatile("s_waitcnt lgkmcnt(0)" ::: "memory");
    __builtin_amdgcn_sched_barrier(0);
    __builtin_amdgcn_s_barrier();
    cur ^= 1;
  }
}

// ---------------- attention over claims (bf16 node, both sides) ----------------
__global__ __launch_bounds__(256) void attn_k(const __hip_bfloat16* nodeAll,
                                              float* wT, float* wS) {
  int b = blockIdx.x, side = blockIdx.y;
  const __hip_bfloat16* node = nodeAll + (long)side * NODE_ELE;
  float* w = side ? wS : wT;
  __shared__ float tl[512];
  __shared__ float sc[CL];
  int tid = threadIdx.x;
  {
    const __hip_bfloat16* tr = node + ((long)b * NNODE + (TL - 1)) * D_;
    tl[tid]       = __bfloat162float(tr[tid]);
    tl[tid + 256] = __bfloat162float(tr[tid + 256]);
  }
  __syncthreads();
  int wid = tid >> 6, lane = tid & 63;
  for (int c = wid; c < CL; c += 4) {
    const __hip_bfloat16* row = node + ((long)b * NNODE + TL + c) * D_;
    uint4 v = *(const uint4*)(row + lane * 8);
    const float* tp = &tl[lane * 8];
    float acc = bits2f(v.x << 16)         * tp[0] + bits2f(v.x & 0xFFFF0000u) * tp[1]
              + bits2f(v.y << 16)         * tp[2] + bits2f(v.y & 0xFFFF0000u) * tp[3]
              + bits2f(v.z << 16)         * tp[4] + bits2f(v.z & 0xFFFF0000u) * tp[5]
              + bits2f(v.w << 16)         * tp[6] + bits2f(v.w & 0xFFFF0000u) * tp[7];
    #pragma unroll
    for (int o = 32; o; o >>= 1) acc += __shfl_xor(acc, o, 64);
    if (lane == 0) sc[c] = acc;
  }
  __syncthreads();
  if (wid == 0) {
    float v[4]; float m = -1e30f;
    #pragma unroll
    for (int i = 0; i < 4; ++i) {
      int c = lane + 64 * i;
      v[i] = (c < CL) ? sc[c] : -1e30f;
      m = fmaxf(m, v[i]);
    }
    #pragma unroll
    for (int o = 32; o; o >>= 1) m = fmaxf(m, __shfl_xor(m, o, 64));
    float s = 0.f;
    #pragma unroll
    for (int i = 0; i < 4; ++i) {
      int c = lane + 64 * i;
      v[i] = (c < CL) ? expf(v[i] - m) : 0.f;
      s += v[i];
    }
    #pragma unroll
    for (int o = 32; o; o >>= 1) s += __shfl_xor(s, o, 64);
    float inv = 1.f / s;
    #pragma unroll
    for (int i = 0; i < 4; ++i) {
      int c = lane + 64 * i;
      if (c < CL) w[(long)b * CL + c] = v[i] * inv;
    }
  }
}

// ---------------- row softmax: f32 in (ld 256, len 250) -> bf16 out, 0-pad ----
__global__ __launch_bounds__(256) void softmaxbf_k(const float* in, __hip_bfloat16* out) {
  int row = blockIdx.x * 4 + (threadIdx.x >> 6);
  int lane = threadIdx.x & 63;
  const float* p = in + (long)row * 256;
  __hip_bfloat16* q = out + (long)row * 256;
  float v[4]; float m = -1e30f;
  #pragma unroll
  for (int i = 0; i < 4; ++i) {
    int c = lane + i * 64;
    v[i] = (c < 250) ? p[c] : -1e30f;
    m = fmaxf(m, v[i]);
  }
  #pragma unroll
  for (int o = 32; o; o >>= 1) m = fmaxf(m, __shfl_xor(m, o, 64));
  float s = 0.f;
  #pragma unroll
  for (int i = 0; i < 4; ++i) {
    int c = lane + i * 64;
    if (c < 250) { v[i] = __expf(v[i] - m); s += v[i]; }
  }
  #pragma unroll
  for (int o = 32; o; o >>= 1) s += __shfl_xor(s, o, 64);
  float inv = 1.f / s;
  #pragma unroll
  for (int i = 0; i < 4; ++i) {
    int c = lane + i * 64;
    q[c] = __float2bfloat16((c < 250) ? v[i] * inv : 0.f);
  }
}

// ---------------- weighted claim pooling (f32 post-GCN node) ----------------
__global__ __launch_bounds__(256) void rep_k(const float* node, const float* w,
                                             float* repSide) {
  int b = blockIdx.x;
  __shared__ float wl[CL];
  int tid = threadIdx.x;
  if (tid < CL) wl[tid] = w[(long)b * CL + tid];
  __syncthreads();
  #pragma unroll
  for (int h = 0; h < 2; ++h) {
    int d = tid + h * 256;
    float acc = 0.f;
    for (int c = 0; c < CL; ++c)
      acc = fmaf(wl[c], node[((long)b * NNODE + TL + c) * D_ + d], acc);
    repSide[(long)b * D_ + d] = acc;
  }
}

// ---------------- final linear ----------------
__global__ __launch_bounds__(256) void final_k(const float* rep, const float* linW,
                                               const float* linb, float* out) {
  int b = blockIdx.x, tid = threadIdx.x;
  float a0 = 0.f, a1 = 0.f, a2 = 0.f;
  for (int d = tid; d < 1024; d += 256) {
    float x = rep[(long)(d >> 9) * (B_ * D_) + (long)b * D_ + (d & 511)];
    a0 = fmaf(x, linW[d], a0);
    a1 = fmaf(x, linW[1024 + d], a1);
    a2 = fmaf(x, linW[2048 + d], a2);
  }
  #pragma unroll
  for (int o = 32; o; o >>= 1) {
    a0 += __shfl_xor(a0, o, 64);
    a1 += __shfl_xor(a1, o, 64);
    a2 += __shfl_xor(a2, o, 64);
  }
  __shared__ float red[3][4];
  int wid = tid >> 6, lane = tid & 63;
  if (lane == 0) { red[0][wid] = a0; red[1][wid] = a1; red[2][wid] = a2; }
  __syncthreads();
  if (tid == 0) {
    out[b * 3 + 0] = red[0][0] + red[0][1] + red[0][2] + red[0][3] + linb[0];
    out[b * 3 + 1] = red[1][0] + red[1][1] + red[1][2] + red[1][3] + linb[1];
    out[b * 3 + 2] = red[2][0] + red[2][1] + red[2][2] + red[2][3] + linb[2];
  }
}

// ---------------- diagnostic ----------------
__global__ void diag_k(float* out, int n, float v) {
  int i = blockIdx.x * blockDim.x + threadIdx.x;
  if (i < n) out[i] = v;
}

} // namespace

extern "C" void kernel_launch(void* const* d_in, const int* in_sizes, int n_in,
                              void* d_out, int out_size, void* d_ws, size_t ws_size,
                              hipStream_t stream) {
  const int* task_target   = (const int*)d_in[1];
  const int* shared_target = (const int*)d_in[2];
  const int* task_claim    = (const int*)d_in[3];
  const int* shared_claim  = (const int*)d_in[4];
  const float* emb      = (const float*)d_in[9];
  const float* tgt_wih  = (const float*)d_in[10];
  const float* tgt_whh  = (const float*)d_in[11];
  const float* tgt_bih  = (const float*)d_in[12];
  const float* tgt_bhh  = (const float*)d_in[13];
  const float* tgc_wih  = (const float*)d_in[14];
  const float* tgc_whh  = (const float*)d_in[15];
  const float* tgc_bih  = (const float*)d_in[16];
  const float* tgc_bhh  = (const float*)d_in[17];
  const float* sgt_wih  = (const float*)d_in[18];
  const float* sgt_whh  = (const float*)d_in[19];
  const float* sgt_bih  = (const float*)d_in[20];
  const float* sgt_bhh  = (const float*)d_in[21];
  const float* sgc_wih  = (const float*)d_in[22];
  const float* sgc_whh  = (const float*)d_in[23];
  const float* sgc_bih  = (const float*)d_in[24];
  const float* sgc_bhh  = (const float*)d_in[25];
  const float* gcnW_task   = (const float*)d_in[26];
  const float* gcnW_shared = (const float*)d_in[27];
  const float* linW = (const float*)d_in[28];
  const float* linb = (const float*)d_in[29];
  float* out = (float*)d_out;

  // ---- workspace plan (bytes); total 268,115,968 <= 256 MiB ----
  const size_t SZ_WHH   = 3145728;
  const size_t SZ_GCNW  = 2097152;
  const size_t SZ_ARENA = 196608000;    // gi all 4 (phase A) / GCN scratch (phase B)
  const size_t SZ_NODE  = 65536000;     // 2 sides x 128x250x512 bf16
  const size_t SZ_W     = 102400;
  const size_t SZ_REP   = 524288;
  const size_t NEED = SZ_WHH + SZ_GCNW + SZ_ARENA + SZ_NODE + 2 * SZ_W + SZ_REP + 4096;

  if (ws_size < NEED) {
    diag_k<<<(out_size + 255) / 256, 256, 0, stream>>>(out, out_size,
                                                       (float)(ws_size >> 20));
    return;
  }

  char* p = (char*)d_ws;
  auto alloc = [&](size_t bytes) { char* r = p; p += (bytes + 255) & ~(size_t)255; return r; };
  __hip_bfloat16* whhbf  = (__hip_bfloat16*)alloc(SZ_WHH);
  __hip_bfloat16* gcnWbf = (__hip_bfloat16*)alloc(SZ_GCNW);   // [side][layer][512][512]
  char* arena  = alloc(SZ_ARENA);
  char* nodeC  = alloc(SZ_NODE);
  float* wT    = (float*)alloc(SZ_W);
  float* wS    = (float*)alloc(SZ_W);
  float* rep   = (float*)alloc(SZ_REP);
  __hip_bfloat16* nodebf = (__hip_bfloat16*)nodeC;

  // phase-A views: gi for all 4 GRUs in arena; emb/wih conversions alias nodebf
  __hip_bfloat16* gi_tt = (__hip_bfloat16*)(arena);                  // 19,660,800
  __hip_bfloat16* gi_tc = (__hip_bfloat16*)(arena + 19660800);       // 78,643,200
  __hip_bfloat16* gi_st = (__hip_bfloat16*)(arena + 98304000);
  __hip_bfloat16* gi_sc = (__hip_bfloat16*)(arena + 117964800);
  __hip_bfloat16* embbf = (__hip_bfloat16*)(nodeC);                  // [30000][304]
  __hip_bfloat16* wihbf[4] = {                                       // [2][768][304] each
    (__hip_bfloat16*)(nodeC + 18240000),
    (__hip_bfloat16*)(nodeC + 19173888),
    (__hip_bfloat16*)(nodeC + 20107776),
    (__hip_bfloat16*)(nodeC + 21041664)};
  // phase-B (GCN) views of arena
  float*          tmpF   = (float*)(arena);                          // [z][250][512] f32
  __hip_bfloat16* tmpbf  = (__hip_bfloat16*)(arena + 65536000);
  float*          corrF  = (float*)(arena + 98304000);               // [z][250][256] f32
  __hip_bfloat16* corrbf = (__hip_bfloat16*)(arena + 131072000);
  __hip_bfloat16* transT = (__hip_bfloat16*)(arena + 147456000);     // [z][512][256]
  __hip_bfloat16* dump   = (__hip_bfloat16*)(arena + 98304000);      // unused sink

  // ---- conversions (once) ----
  convwhh_k<<<6144, 256, 0, stream>>>(tgt_whh, tgc_whh, sgt_whh, sgc_whh, whhbf);
  convf2b4_k<<<512, 256, 0, stream>>>(gcnW_task,   gcnWbf,          131072);
  convf2b4_k<<<512, 256, 0, stream>>>(gcnW_shared, gcnWbf + 524288, 131072);
  convpad_k<<<dim3(2, 30000), 256, 0, stream>>>(emb, embbf, 300, 304);
  convpad_k<<<dim3(2, 1536), 256, 0, stream>>>(tgt_wih, wihbf[0], 300, 304);
  convpad_k<<<dim3(2, 1536), 256, 0, stream>>>(tgc_wih, wihbf[1], 300, 304);
  convpad_k<<<dim3(2, 1536), 256, 0, stream>>>(sgt_wih, wihbf[2], 300, 304);
  convpad_k<<<dim3(2, 1536), 256, 0, stream>>>(sgc_wih, wihbf[3], 300, 304);

  // ---- projections: gi = emb[tok] @ Wih^T + bih (bf16) ----
  auto proj = [&](const int* idx, __hip_bfloat16* wih, const float* bih,
                  __hip_bfloat16* gi, int Mrows, int gx) {
    BGemmArgs ga{};
    ga.A = embbf; ga.idx = idx; ga.B = wih; ga.bias = bih; ga.C = gi;
    ga.aStride = 0; ga.bStride = 768L * 304; ga.biasStride = 768;
    ga.cStride = (long)Mrows * 768;
    ga.M = Mrows; ga.N = 768; ga.Kreal = 304; ga.lda = 304; ga.ldb = 304; ga.ldc = 768;
    bgemm_k<true, 1><<<dim3(gx, 6, 2), 256, 0, stream>>>(ga);
  };
  proj(task_target,   wihbf[0], tgt_bih, gi_tt, 6400, 50);
  proj(task_claim,    wihbf[1], tgc_bih, gi_tc, 25600, 200);
  proj(shared_target, wihbf[2], sgt_bih, gi_st, 6400, 50);
  proj(shared_claim,  wihbf[3], sgc_bih, gi_sc, 25600, 200);

  // ---- all 8 GRU chains in ONE dispatch (writes nodebf over emb/wih alias) ----
  RecArgs ra;
  ra.whhbf = whhbf;
  ra.gi[0] = gi_tt; ra.gi[1] = gi_tc; ra.gi[2] = gi_st; ra.gi[3] = gi_sc;
  ra.bhh[0] = tgt_bhh; ra.bhh[1] = tgc_bhh; ra.bhh[2] = sgt_bhh; ra.bhh[3] = sgc_bhh;
  ra.nodebf = nodebf;
  gru_rec_k<<<dim3(8, 1, 8), 512, 0, stream>>>(ra);

  // ---- stance attention, both sides ----
  attn_k<<<dim3(128, 2), 256, 0, stream>>>(nodebf, wT, wS);

  // ---- GCN 2 layers per side + pooling (arena phase B; gi dead) ----
  for (int s = 0; s < 2; ++s) {
    const __hip_bfloat16* nbf = nodebf + (long)s * NODE_ELE;
    for (int layer = 0; layer < 2; ++layer) {
      const __hip_bfloat16* inbf = layer ? tmpbf : nbf;
      const __hip_bfloat16* Wl = gcnWbf + ((long)s * 2 + layer) * 262144;
      BGemmArgs ca{};   // corr = in @ in^T (f32)
      ca.A = inbf; ca.B = inbf; ca.C = corrF;
      ca.aStride = 128000; ca.bStride = 128000; ca.cStride = 64000;
      ca.M = 250; ca.N = 250; ca.Kreal = 512; ca.lda = 512; ca.ldb = 512; ca.ldc = 256;
      bgemm_k<false, 0><<<dim3(2, 2, 128), 256, 0, stream>>>(ca);
      softmaxbf_k<<<8000, 256, 0, stream>>>(corrF, corrbf);
      BGemmArgs ta{};   // trans^T = W @ in^T (bf16, 0-pad cols 250..255)
      ta.A = Wl; ta.B = inbf; ta.C = transT;
      ta.aStride = 0; ta.bStride = 128000; ta.cStride = 131072;
      ta.M = 512; ta.N = 250; ta.Kreal = 512; ta.lda = 512; ta.ldb = 512; ta.ldc = 256;
      bgemm_k<false, 3><<<dim3(4, 2, 128), 256, 0, stream>>>(ta);
      BGemmArgs aa{};   // out = relu(res + corr @ trans)
      aa.A = corrbf; aa.B = transT;
      aa.aStride = 64000; aa.bStride = 131072; aa.cStride = 128000;
      aa.c2Stride = 128000; aa.rStride = 128000;
      aa.M = 250; aa.N = 512; aa.Kreal = 256; aa.lda = 256; aa.ldb = 256; aa.ldc = 512;
      if (layer == 0) {   // res = pre-GCN node (bf16); out -> f32 tmpF + bf16 tmpbf
        aa.Res = nbf; aa.C = tmpF; aa.C2 = tmpbf;
        bgemm_k<false, 2><<<dim3(2, 4, 128), 256, 0, stream>>>(aa);
      } else {            // res = tmpF (f32); out -> tmpF in-place (f32 for pooling)
        aa.Res = tmpF; aa.C = tmpF; aa.C2 = dump;
        bgemm_k<false, 4><<<dim3(2, 4, 128), 256, 0, stream>>>(aa);
      }
    }
    rep_k<<<dim3(128), 256, 0, stream>>>(tmpF, s ? wS : wT, rep + (long)s * 128 * 512);
  }

  final_k<<<dim3(128), 256, 0, stream>>>(rep, linW, linb, out);
}

// Round 10
// 1915.883 us; speedup vs baseline: 22.5905x; 1.0364x over previous
//
#include <hip/hip_runtime.h>
#include <hip/hip_bf16.h>

namespace {

constexpr int B_  = 128;
constexpr int TL  = 50, CL = 200, NNODE = 250;
constexpr int H_  = 256, D_ = 512;
constexpr long NODE_ELE = 128L * 250 * 512;   // per side

typedef __attribute__((ext_vector_type(8))) short bf16x8;
typedef __attribute__((ext_vector_type(4))) float f32x4;

__device__ inline float bits2f(unsigned v) { union { unsigned u; float f; } c; c.u = v; return c.f; }
__device__ inline unsigned f2bits(float x) { union { float f; unsigned u; } c; c.f = x; return c.u; }
__device__ inline unsigned short bfbits(float x) {
  __hip_bfloat16 b = __float2bfloat16(x);
  return *(unsigned short*)&b;
}
__device__ inline float bfsel(uint2 v, int r) {        // r-th bf16 of a 4-pack
  unsigned w = (r < 2) ? v.x : v.y;
  return bits2f((r & 1) ? (w & 0xFFFF0000u) : (w << 16));
}
__device__ inline float sigf(float x)  { return 1.f / (1.f + __expf(-x)); }
__device__ inline float tanhf_(float x){ return 1.f - 2.f / (__expf(2.f * x) + 1.f); }

// =============== bf16 MFMA GEMM: C[z] = A[z] @ B[z]^T (B is [N][K]) ===========
// OUT 0: f32 out. 1: +bias -> bf16. 2: +bf16 Res, relu -> f32 C AND bf16 C2.
// 3: bf16 out, zero-fill cols [N, 256). 4: +f32 Res, relu -> f32 C (in-place ok).
struct BGemmArgs {
  const __hip_bfloat16* A; const __hip_bfloat16* B;
  const int* idx; const float* bias; const void* Res;
  void* C; void* C2;
  long aStride, bStride, biasStride, cStride, c2Stride, rStride;
  int M, N, Kreal, lda, ldb, ldc;
};

template<bool GATHER, int OUT>
__global__ __launch_bounds__(256) void bgemm_k(BGemmArgs g) {
  __shared__ __align__(16) __hip_bfloat16 As[128 * 64];   // [r][k] XOR-swizzled
  __shared__ __align__(16) __hip_bfloat16 Bs[128 * 64];
  const int z = blockIdx.z;
  const int m0 = blockIdx.x * 128, n0 = blockIdx.y * 128;
  const int tid = threadIdx.x;
  const int lane = tid & 63, wv = tid >> 6;
  const int wr = wv >> 1, wc = wv & 1;                    // wave -> 64x64 quadrant
  const __hip_bfloat16* Ab = GATHER ? g.A : g.A + (long)z * g.aStride;
  const __hip_bfloat16* Bb = g.B + (long)z * g.bStride;
  const int sr = tid >> 3, so = tid & 7;                  // staging: row, col-octet
  f32x4 acc[4][4];
  #pragma unroll
  for (int i = 0; i < 4; ++i)
    #pragma unroll
    for (int j = 0; j < 4; ++j) acc[i][j] = (f32x4){0.f, 0.f, 0.f, 0.f};

  const int ktiles = (g.Kreal + 63) >> 6;
  for (int kt = 0; kt < ktiles; ++kt) {
    const int k0 = kt * 64;
    __syncthreads();
    #pragma unroll
    for (int p = 0; p < 4; ++p) {           // A tile 128x64
      int r = p * 32 + sr;
      int row = m0 + r;
      int kg = k0 + so * 8;
      uint4 v = make_uint4(0, 0, 0, 0);
      if (row < g.M && kg + 8 <= g.Kreal) {
        long ao = GATHER ? (long)g.idx[row] * g.lda : (long)row * g.lda;
        v = *(const uint4*)(Ab + ao + kg);
      }
      *(uint4*)((char*)As + ((r * 128 + so * 16) ^ ((r & 7) << 4))) = v;
    }
    #pragma unroll
    for (int p = 0; p < 4; ++p) {           // B tile 128x64 (rows = n)
      int r = p * 32 + sr;
      int row = n0 + r;
      int kg = k0 + so * 8;
      uint4 v = make_uint4(0, 0, 0, 0);
      if (row < g.N && kg + 8 <= g.Kreal)
        v = *(const uint4*)(Bb + (long)row * g.ldb + kg);
      *(uint4*)((char*)Bs + ((r * 128 + so * 16) ^ ((r & 7) << 4))) = v;
    }
    __syncthreads();
    #pragma unroll
    for (int ks = 0; ks < 2; ++ks) {
      bf16x8 af[4], bfr[4];
      #pragma unroll
      for (int i = 0; i < 4; ++i) {
        int ra = wr * 64 + i * 16 + (lane & 15);
        af[i] = *(const bf16x8*)((const char*)As +
                 ((ra * 128 + ks * 64 + (lane >> 4) * 16) ^ ((ra & 7) << 4)));
        int rb = wc * 64 + i * 16 + (lane & 15);
        bfr[i] = *(const bf16x8*)((const char*)Bs +
                 ((rb * 128 + ks * 64 + (lane >> 4) * 16) ^ ((rb & 7) << 4)));
      }
      #pragma unroll
      for (int i = 0; i < 4; ++i)
        #pragma unroll
        for (int j = 0; j < 4; ++j)
          acc[i][j] = __builtin_amdgcn_mfma_f32_16x16x32_bf16(af[i], bfr[j], acc[i][j], 0, 0, 0);
    }
  }
  // ---- epilogue: D col = lane&15 (n), row = (lane>>4)*4 + r (m) ----
  const long cz = (long)z * g.cStride;
  #pragma unroll
  for (int i = 0; i < 4; ++i) {
    int rbase = m0 + wr * 64 + i * 16 + ((lane >> 4) << 2);
    #pragma unroll
    for (int j = 0; j < 4; ++j) {
      int col = n0 + wc * 64 + j * 16 + (lane & 15);
      #pragma unroll
      for (int r = 0; r < 4; ++r) {
        int row = rbase + r;
        float v = acc[i][j][r];
        if (OUT == 0) {
          if (row < g.M && col < g.N)
            ((float*)g.C)[cz + (long)row * g.ldc + col] = v;
        } else if (OUT == 1) {
          if (row < g.M && col < g.N) {
            v += g.bias[(long)z * g.biasStride + col];
            ((__hip_bfloat16*)g.C)[cz + (long)row * g.ldc + col] = __float2bfloat16(v);
          }
        } else if (OUT == 2) {
          if (row < g.M && col < g.N) {
            v += __bfloat162float(((const __hip_bfloat16*)g.Res)
                     [(long)z * g.rStride + (long)row * g.ldc + col]);
            v = fmaxf(v, 0.f);
            ((float*)g.C)[cz + (long)row * g.ldc + col] = v;
            ((__hip_bfloat16*)g.C2)[(long)z * g.c2Stride + (long)row * g.ldc + col] =
                __float2bfloat16(v);
          }
        } else if (OUT == 3) {
          if (row < g.M)
            ((__hip_bfloat16*)g.C)[cz + (long)row * g.ldc + col] =
                __float2bfloat16(col < g.N ? v : 0.f);
        } else {  // OUT == 4: f32 res (in-place safe), relu, f32 out
          if (row < g.M && col < g.N) {
            v += ((const float*)g.Res)[(long)z * g.rStride + (long)row * g.ldc + col];
            v = fmaxf(v, 0.f);
            ((float*)g.C)[cz + (long)row * g.ldc + col] = v;
          }
        }
      }
    }
  }
}

// ---------------- conversions ----------------
__global__ __launch_bounds__(256) void convwhh_k(const float* tt, const float* tc,
                                                 const float* st, const float* sc,
                                                 __hip_bfloat16* o) {
  long i = (long)blockIdx.x * blockDim.x + threadIdx.x;
  const long per = 768L * 256;
  if (i >= 8 * per) return;
  int z = (int)(i / per);
  long rem = i - (long)z * per;
  const float* src = (z < 2) ? tt : (z < 4) ? tc : (z < 6) ? st : sc;
  o[i] = __float2bfloat16(src[(long)(z & 1) * per + rem]);
}

__global__ __launch_bounds__(256) void convpad_k(const float* src, __hip_bfloat16* dst,
                                                 int K, int Kp) {
  int c = blockIdx.x * 256 + threadIdx.x;
  long r = blockIdx.y;
  if (c < Kp) dst[r * Kp + c] = __float2bfloat16(c < K ? src[r * K + c] : 0.f);
}

__global__ __launch_bounds__(256) void convf2b4_k(const float* src, __hip_bfloat16* dst,
                                                  long n4) {
  long i = (long)blockIdx.x * 256 + threadIdx.x;
  if (i >= n4) return;
  float4 v = ((const float4*)src)[i];
  ushort4 o;
  o.x = bfbits(v.x); o.y = bfbits(v.y); o.z = bfbits(v.z); o.w = bfbits(v.w);
  ((ushort4*)dst)[i] = o;
}

// biasC[dir][j] = bih[dir][j] + (j<512 ? bhh[dir][j] : 0)  — folds r,z-gate bhh
// into the projection bias so the recurrence never touches them.
__global__ __launch_bounds__(256) void biasc_k(const float* bih, const float* bhh,
                                               float* o) {
  int i = blockIdx.x * 256 + threadIdx.x;
  if (i < 1536) o[i] = bih[i] + ((i % 768) < 512 ? bhh[i] : 0.f);
}

// ---------------- GRU recurrence: MFMA persistent-RNN, ALL 8 chains ----------
// grid (8,1,8): z = side*4 + sq*2 + dir; blockIdx.x = 16-batch group (64 blocks).
// h carried exactly in f32 registers; MFMA B-operand is bf16 h (hi only) in a
// single double-buffered swizzled LDS buffer. r,z bhh pre-folded into gi; only
// bhh_n (8 floats) lives in registers. One barrier per step.
struct RecArgs {
  const __hip_bfloat16* whhbf;    // [8][768][256], order tgt01,tgc01,sgt01,sgc01
  const __hip_bfloat16* gi[4];    // {task_t, task_c, shared_t, shared_c}
  const float* bhh[4];
  __hip_bfloat16* nodebf;         // [2][128][250][512]
};

__global__ __launch_bounds__(512, 2) void gru_rec_k(RecArgs a) {
  __shared__ __align__(16) char hbuf[2][8192];   // [buf][batch 16][k 256] bf16, swizzled
  const int z = blockIdx.z;
  const int side = z >> 2, sq = (z >> 1) & 1, dir = z & 1;
  const int gidx = side * 2 + sq;
  const int T = sq ? CL : TL;
  const int toff = sq ? TL : 0;
  const __hip_bfloat16* gi = a.gi[gidx] + (long)dir * B_ * T * 768;
  const float* bhh = a.bhh[gidx] + dir * 768;
  const __hip_bfloat16* whh = a.whhbf + (long)z * 768 * 256;
  __hip_bfloat16* nodeb = a.nodebf + (long)side * NODE_ELE;
  const int b0 = blockIdx.x * 16;
  const int tid = threadIdx.x;
  const int lane = tid & 63, wv = tid >> 6;
  const int bcol = lane & 15, g4 = lane >> 4;
  const int u0 = wv * 32 + g4 * 4;
  const int swz = (bcol & 15) << 4;   // full 4-bit XOR: bijective within 512B row

  bf16x8 Af[3][2][8];
  #pragma unroll
  for (int g = 0; g < 3; ++g)
    #pragma unroll
    for (int h = 0; h < 2; ++h)
      #pragma unroll
      for (int kt = 0; kt < 8; ++kt) {
        int row = g * 256 + wv * 32 + h * 16 + bcol;
        int col = kt * 32 + g4 * 8;
        Af[g][h][kt] = *(const bf16x8*)(whh + (long)row * 256 + col);
      }
  *(uint4*)&hbuf[0][tid * 16] = make_uint4(0, 0, 0, 0);
  // n-gate bhh only (r,z folded into gi at projection)
  const float4 bn0 = *(const float4*)&bhh[512 + u0];
  const float4 bn1 = *(const float4*)&bhh[512 + u0 + 16];
  __syncthreads();

  const __hip_bfloat16* gip = gi + ((long)(b0 + bcol) * T + (dir ? T - 1 : 0)) * 768 + u0;
  __hip_bfloat16* np = nodeb + ((long)(b0 + bcol) * NNODE + toff + (dir ? T - 1 : 0)) * D_
                       + dir * H_ + u0;
  const long gistep = (dir ? -768L : 768L);
  const long nstep  = (dir ? -(long)D_ : (long)D_);
  int cur = 0;

  float hreg[2][4];                      // this thread's 8 h-units, exact f32
  #pragma unroll
  for (int h = 0; h < 2; ++h)
    #pragma unroll
    for (int r = 0; r < 4; ++r) hreg[h][r] = 0.f;

  // gi preload for t=0
  uint2 gv[3][2];
  #pragma unroll
  for (int g = 0; g < 3; ++g)
    #pragma unroll
    for (int h = 0; h < 2; ++h)
      gv[g][h] = *(const uint2*)(gip + g * 256 + h * 16);

  for (int t = 0; t < T; ++t) {
    // ---- MFMA: gates for (this wave's 32 units) x (16 batch), bf16 h ----
    const char* hib = &hbuf[cur][0];
    f32x4 c[3][2];
    #pragma unroll
    for (int g = 0; g < 3; ++g)
      #pragma unroll
      for (int h = 0; h < 2; ++h) c[g][h] = (f32x4){0.f, 0.f, 0.f, 0.f};
    const int rb = bcol * 512 + g4 * 16;
    #pragma unroll
    for (int kt = 0; kt < 8; ++kt) {
      bf16x8 bh = *(const bf16x8*)(hib + ((rb + kt * 64) ^ swz));
      #pragma unroll
      for (int g = 0; g < 3; ++g)
        #pragma unroll
        for (int h = 0; h < 2; ++h)
          c[g][h] = __builtin_amdgcn_mfma_f32_16x16x32_bf16(Af[g][h][kt], bh, c[g][h], 0, 0, 0);
    }

    // ---- activation (h_old exact from registers; r,z bias pre-folded) ----
    #pragma unroll
    for (int h = 0; h < 2; ++h) {
      float4 bn = h ? bn1 : bn0;
      #pragma unroll
      for (int r = 0; r < 4; ++r) {
        float bnv = (r == 0) ? bn.x : (r == 1) ? bn.y : (r == 2) ? bn.z : bn.w;
        float rr = sigf(bfsel(gv[0][h], r) + c[0][h][r]);
        float zz = sigf(bfsel(gv[1][h], r) + c[1][h][r]);
        float nn = tanhf_(bfsel(gv[2][h], r) + rr * (c[2][h][r] + bnv));
        hreg[h][r] = (1.f - zz) * nn + zz * hreg[h][r];
      }
    }

    // ---- issue gi loads for t+1 (in flight across pack+barrier+next MFMA) ----
    {
      const __hip_bfloat16* gn = (t + 1 < T) ? gip + gistep : gip;
      gip = gn;
      #pragma unroll
      for (int g = 0; g < 3; ++g)
        #pragma unroll
        for (int h = 0; h < 2; ++h)
          gv[g][h] = *(const uint2*)(gn + g * 256 + h * 16);
    }

    // ---- pack h -> bf16 (round-half-up) ; store to node + next h-buffer ----
    const int ob0 = bcol * 512 + u0 * 2;
    char* hibn = &hbuf[cur ^ 1][0];
    #pragma unroll
    for (int h = 0; h < 2; ++h) {
      unsigned hb[4];
      #pragma unroll
      for (int r = 0; r < 4; ++r)
        hb[r] = (f2bits(hreg[h][r]) + 0x8000u) & 0xFFFF0000u;
      uint2 hiw;
      hiw.x = (hb[0] >> 16) | hb[1];
      hiw.y = (hb[2] >> 16) | hb[3];
      *(uint2*)(np + h * 16) = hiw;                      // node (fire-and-forget)
      *(uint2*)(hibn + ((ob0 + h * 32) ^ swz)) = hiw;    // next-step h
    }
    np += nstep;
    asm volatile("s_waitcnt lgkmcnt(0)" ::: "memory");
    __builtin_amdgcn_sched_barrier(0);
    __builtin_amdgcn_s_barrier();
    cur ^= 1;
  }
}

// ---------------- attention over claims (bf16 node, both sides) ----------------
__global__ __launch_bounds__(256) void attn_k(const __hip_bfloat16* nodeAll,
                                              float* wT, float* wS) {
  int b = blockIdx.x, side = blockIdx.y;
  const __hip_bfloat16* node = nodeAll + (long)side * NODE_ELE;
  float* w = side ? wS : wT;
  __shared__ float tl[512];
  __shared__ float sc[CL];
  int tid = threadIdx.x;
  {
    const __hip_bfloat16* tr = node + ((long)b * NNODE + (TL - 1)) * D_;
    tl[tid]       = __bfloat162float(tr[tid]);
    tl[tid + 256] = __bfloat162float(tr[tid + 256]);
  }
  __syncthreads();
  int wid = tid >> 6, lane = tid & 63;
  for (int c = wid; c < CL; c += 4) {
    const __hip_bfloat16* row = node + ((long)b * NNODE + TL + c) * D_;
    uint4 v = *(const uint4*)(row + lane * 8);
    const float* tp = &tl[lane * 8];
    float acc = bits2f(v.x << 16)         * tp[0] + bits2f(v.x & 0xFFFF0000u) * tp[1]
              + bits2f(v.y << 16)         * tp[2] + bits2f(v.y & 0xFFFF0000u) * tp[3]
              + bits2f(v.z << 16)         * tp[4] + bits2f(v.z & 0xFFFF0000u) * tp[5]
              + bits2f(v.w << 16)         * tp[6] + bits2f(v.w & 0xFFFF0000u) * tp[7];
    #pragma unroll
    for (int o = 32; o; o >>= 1) acc += __shfl_xor(acc, o, 64);
    if (lane == 0) sc[c] = acc;
  }
  __syncthreads();
  if (wid == 0) {
    float v[4]; float m = -1e30f;
    #pragma unroll
    for (int i = 0; i < 4; ++i) {
      int c = lane + 64 * i;
      v[i] = (c < CL) ? sc[c] : -1e30f;
      m = fmaxf(m, v[i]);
    }
    #pragma unroll
    for (int o = 32; o; o >>= 1) m = fmaxf(m, __shfl_xor(m, o, 64));
    float s = 0.f;
    #pragma unroll
    for (int i = 0; i < 4; ++i) {
      int c = lane + 64 * i;
      v[i] = (c < CL) ? expf(v[i] - m) : 0.f;
      s += v[i];
    }
    #pragma unroll
    for (int o = 32; o; o >>= 1) s += __shfl_xor(s, o, 64);
    float inv = 1.f / s;
    #pragma unroll
    for (int i = 0; i < 4; ++i) {
      int c = lane + 64 * i;
      if (c < CL) w[(long)b * CL + c] = v[i] * inv;
    }
  }
}

// ---------------- row softmax: f32 in (ld 256, len 250) -> bf16 out, 0-pad ----
__global__ __launch_bounds__(256) void softmaxbf_k(const float* in, __hip_bfloat16* out) {
  int row = blockIdx.x * 4 + (threadIdx.x >> 6);
  int lane = threadIdx.x & 63;
  const float* p = in + (long)row * 256;
  __hip_bfloat16* q = out + (long)row * 256;
  float v[4]; float m = -1e30f;
  #pragma unroll
  for (int i = 0; i < 4; ++i) {
    int c = lane + i * 64;
    v[i] = (c < 250) ? p[c] : -1e30f;
    m = fmaxf(m, v[i]);
  }
  #pragma unroll
  for (int o = 32; o; o >>= 1) m = fmaxf(m, __shfl_xor(m, o, 64));
  float s = 0.f;
  #pragma unroll
  for (int i = 0; i < 4; ++i) {
    int c = lane + i * 64;
    if (c < 250) { v[i] = __expf(v[i] - m); s += v[i]; }
  }
  #pragma unroll
  for (int o = 32; o; o >>= 1) s += __shfl_xor(s, o, 64);
  float inv = 1.f / s;
  #pragma unroll
  for (int i = 0; i < 4; ++i) {
    int c = lane + i * 64;
    q[c] = __float2bfloat16((c < 250) ? v[i] * inv : 0.f);
  }
}

// ---------------- weighted claim pooling (f32 post-GCN node) ----------------
__global__ __launch_bounds__(256) void rep_k(const float* node, const float* w,
                                             float* repSide) {
  int b = blockIdx.x;
  __shared__ float wl[CL];
  int tid = threadIdx.x;
  if (tid < CL) wl[tid] = w[(long)b * CL + tid];
  __syncthreads();
  #pragma unroll
  for (int h = 0; h < 2; ++h) {
    int d = tid + h * 256;
    float acc = 0.f;
    for (int c = 0; c < CL; ++c)
      acc = fmaf(wl[c], node[((long)b * NNODE + TL + c) * D_ + d], acc);
    repSide[(long)b * D_ + d] = acc;
  }
}

// ---------------- final linear ----------------
__global__ __launch_bounds__(256) void final_k(const float* rep, const float* linW,
                                               const float* linb, float* out) {
  int b = blockIdx.x, tid = threadIdx.x;
  float a0 = 0.f, a1 = 0.f, a2 = 0.f;
  for (int d = tid; d < 1024; d += 256) {
    float x = rep[(long)(d >> 9) * (B_ * D_) + (long)b * D_ + (d & 511)];
    a0 = fmaf(x, linW[d], a0);
    a1 = fmaf(x, linW[1024 + d], a1);
    a2 = fmaf(x, linW[2048 + d], a2);
  }
  #pragma unroll
  for (int o = 32; o; o >>= 1) {
    a0 += __shfl_xor(a0, o, 64);
    a1 += __shfl_xor(a1, o, 64);
    a2 += __shfl_xor(a2, o, 64);
  }
  __shared__ float red[3][4];
  int wid = tid >> 6, lane = tid & 63;
  if (lane == 0) { red[0][wid] = a0; red[1][wid] = a1; red[2][wid] = a2; }
  __syncthreads();
  if (tid == 0) {
    out[b * 3 + 0] = red[0][0] + red[0][1] + red[0][2] + red[0][3] + linb[0];
    out[b * 3 + 1] = red[1][0] + red[1][1] + red[1][2] + red[1][3] + linb[1];
    out[b * 3 + 2] = red[2][0] + red[2][1] + red[2][2] + red[2][3] + linb[2];
  }
}

// ---------------- diagnostic ----------------
__global__ void diag_k(float* out, int n, float v) {
  int i = blockIdx.x * blockDim.x + threadIdx.x;
  if (i < n) out[i] = v;
}

} // namespace

extern "C" void kernel_launch(void* const* d_in, const int* in_sizes, int n_in,
                              void* d_out, int out_size, void* d_ws, size_t ws_size,
                              hipStream_t stream) {
  const int* task_target   = (const int*)d_in[1];
  const int* shared_target = (const int*)d_in[2];
  const int* task_claim    = (const int*)d_in[3];
  const int* shared_claim  = (const int*)d_in[4];
  const float* emb      = (const float*)d_in[9];
  const float* tgt_wih  = (const float*)d_in[10];
  const float* tgt_whh  = (const float*)d_in[11];
  const float* tgt_bih  = (const float*)d_in[12];
  const float* tgt_bhh  = (const float*)d_in[13];
  const float* tgc_wih  = (const float*)d_in[14];
  const float* tgc_whh  = (const float*)d_in[15];
  const float* tgc_bih  = (const float*)d_in[16];
  const float* tgc_bhh  = (const float*)d_in[17];
  const float* sgt_wih  = (const float*)d_in[18];
  const float* sgt_whh  = (const float*)d_in[19];
  const float* sgt_bih  = (const float*)d_in[20];
  const float* sgt_bhh  = (const float*)d_in[21];
  const float* sgc_wih  = (const float*)d_in[22];
  const float* sgc_whh  = (const float*)d_in[23];
  const float* sgc_bih  = (const float*)d_in[24];
  const float* sgc_bhh  = (const float*)d_in[25];
  const float* gcnW_task   = (const float*)d_in[26];
  const float* gcnW_shared = (const float*)d_in[27];
  const float* linW = (const float*)d_in[28];
  const float* linb = (const float*)d_in[29];
  float* out = (float*)d_out;

  // ---- workspace plan (bytes); total ~268.15 MB <= 256 MiB ----
  const size_t SZ_WHH   = 3145728;
  const size_t SZ_GCNW  = 2097152;
  const size_t SZ_BIASC = 24576;        // 4 x [2][768] f32 combined proj bias
  const size_t SZ_ARENA = 196608000;    // gi all 4 (phase A) / GCN scratch (phase B)
  const size_t SZ_NODE  = 65536000;     // 2 sides x 128x250x512 bf16
  const size_t SZ_W     = 102400;
  const size_t SZ_REP   = 524288;
  const size_t NEED = SZ_WHH + SZ_GCNW + SZ_BIASC + SZ_ARENA + SZ_NODE
                      + 2 * SZ_W + SZ_REP + 4096;

  if (ws_size < NEED) {
    diag_k<<<(out_size + 255) / 256, 256, 0, stream>>>(out, out_size,
                                                       (float)(ws_size >> 20));
    return;
  }

  char* p = (char*)d_ws;
  auto alloc = [&](size_t bytes) { char* r = p; p += (bytes + 255) & ~(size_t)255; return r; };
  __hip_bfloat16* whhbf  = (__hip_bfloat16*)alloc(SZ_WHH);
  __hip_bfloat16* gcnWbf = (__hip_bfloat16*)alloc(SZ_GCNW);   // [side][layer][512][512]
  float* biasC = (float*)alloc(SZ_BIASC);                     // [4][2][768]
  char* arena  = alloc(SZ_ARENA);
  char* nodeC  = alloc(SZ_NODE);
  float* wT    = (float*)alloc(SZ_W);
  float* wS    = (float*)alloc(SZ_W);
  float* rep   = (float*)alloc(SZ_REP);
  __hip_bfloat16* nodebf = (__hip_bfloat16*)nodeC;

  // phase-A views: gi for all 4 GRUs in arena; emb/wih conversions alias nodebf
  __hip_bfloat16* gi_tt = (__hip_bfloat16*)(arena);                  // 19,660,800
  __hip_bfloat16* gi_tc = (__hip_bfloat16*)(arena + 19660800);       // 78,643,200
  __hip_bfloat16* gi_st = (__hip_bfloat16*)(arena + 98304000);
  __hip_bfloat16* gi_sc = (__hip_bfloat16*)(arena + 117964800);
  __hip_bfloat16* embbf = (__hip_bfloat16*)(nodeC);                  // [30000][304]
  __hip_bfloat16* wihbf[4] = {                                       // [2][768][304] each
    (__hip_bfloat16*)(nodeC + 18240000),
    (__hip_bfloat16*)(nodeC + 19173888),
    (__hip_bfloat16*)(nodeC + 20107776),
    (__hip_bfloat16*)(nodeC + 21041664)};
  // phase-B (GCN) views of arena
  float*          tmpF   = (float*)(arena);                          // [z][250][512] f32
  __hip_bfloat16* tmpbf  = (__hip_bfloat16*)(arena + 65536000);
  float*          corrF  = (float*)(arena + 98304000);               // [z][250][256] f32
  __hip_bfloat16* corrbf = (__hip_bfloat16*)(arena + 131072000);
  __hip_bfloat16* transT = (__hip_bfloat16*)(arena + 147456000);     // [z][512][256]
  __hip_bfloat16* dump   = (__hip_bfloat16*)(arena + 98304000);      // unused sink

  // ---- conversions (once) ----
  convwhh_k<<<6144, 256, 0, stream>>>(tgt_whh, tgc_whh, sgt_whh, sgc_whh, whhbf);
  convf2b4_k<<<512, 256, 0, stream>>>(gcnW_task,   gcnWbf,          131072);
  convf2b4_k<<<512, 256, 0, stream>>>(gcnW_shared, gcnWbf + 524288, 131072);
  convpad_k<<<dim3(2, 30000), 256, 0, stream>>>(emb, embbf, 300, 304);
  convpad_k<<<dim3(2, 1536), 256, 0, stream>>>(tgt_wih, wihbf[0], 300, 304);
  convpad_k<<<dim3(2, 1536), 256, 0, stream>>>(tgc_wih, wihbf[1], 300, 304);
  convpad_k<<<dim3(2, 1536), 256, 0, stream>>>(sgt_wih, wihbf[2], 300, 304);
  convpad_k<<<dim3(2, 1536), 256, 0, stream>>>(sgc_wih, wihbf[3], 300, 304);
  biasc_k<<<6, 256, 0, stream>>>(tgt_bih, tgt_bhh, biasC);
  biasc_k<<<6, 256, 0, stream>>>(tgc_bih, tgc_bhh, biasC + 1536);
  biasc_k<<<6, 256, 0, stream>>>(sgt_bih, sgt_bhh, biasC + 3072);
  biasc_k<<<6, 256, 0, stream>>>(sgc_bih, sgc_bhh, biasC + 4608);

  // ---- projections: gi = emb[tok] @ Wih^T + biasC (bf16) ----
  auto proj = [&](const int* idx, __hip_bfloat16* wih, const float* bias,
                  __hip_bfloat16* gi, int Mrows, int gx) {
    BGemmArgs ga{};
    ga.A = embbf; ga.idx = idx; ga.B = wih; ga.bias = bias; ga.C = gi;
    ga.aStride = 0; ga.bStride = 768L * 304; ga.biasStride = 768;
    ga.cStride = (long)Mrows * 768;
    ga.M = Mrows; ga.N = 768; ga.Kreal = 304; ga.lda = 304; ga.ldb = 304; ga.ldc = 768;
    bgemm_k<true, 1><<<dim3(gx, 6, 2), 256, 0, stream>>>(ga);
  };
  proj(task_target,   wihbf[0], biasC,        gi_tt, 6400, 50);
  proj(task_claim,    wihbf[1], biasC + 1536, gi_tc, 25600, 200);
  proj(shared_target, wihbf[2], biasC + 3072, gi_st, 6400, 50);
  proj(shared_claim,  wihbf[3], biasC + 4608, gi_sc, 25600, 200);

  // ---- all 8 GRU chains in ONE dispatch (writes nodebf over emb/wih alias) ----
  RecArgs ra;
  ra.whhbf = whhbf;
  ra.gi[0] = gi_tt; ra.gi[1] = gi_tc; ra.gi[2] = gi_st; ra.gi[3] = gi_sc;
  ra.bhh[0] = tgt_bhh; ra.bhh[1] = tgc_bhh; ra.bhh[2] = sgt_bhh; ra.bhh[3] = sgc_bhh;
  ra.nodebf = nodebf;
  gru_rec_k<<<dim3(8, 1, 8), 512, 0, stream>>>(ra);

  // ---- stance attention, both sides ----
  attn_k<<<dim3(128, 2), 256, 0, stream>>>(nodebf, wT, wS);

  // ---- GCN 2 layers per side + pooling (arena phase B; gi dead) ----
  for (int s = 0; s < 2; ++s) {
    const __hip_bfloat16* nbf = nodebf + (long)s * NODE_ELE;
    for (int layer = 0; layer < 2; ++layer) {
      const __hip_bfloat16* inbf = layer ? tmpbf : nbf;
      const __hip_bfloat16* Wl = gcnWbf + ((long)s * 2 + layer) * 262144;
      BGemmArgs ca{};   // corr = in @ in^T (f32)
      ca.A = inbf; ca.B = inbf; ca.C = corrF;
      ca.aStride = 128000; ca.bStride = 128000; ca.cStride = 64000;
      ca.M = 250; ca.N = 250; ca.Kreal = 512; ca.lda = 512; ca.ldb = 512; ca.ldc = 256;
      bgemm_k<false, 0><<<dim3(2, 2, 128), 256, 0, stream>>>(ca);
      softmaxbf_k<<<8000, 256, 0, stream>>>(corrF, corrbf);
      BGemmArgs ta{};   // trans^T = W @ in^T (bf16, 0-pad cols 250..255)
      ta.A = Wl; ta.B = inbf; ta.C = transT;
      ta.aStride = 0; ta.bStride = 128000; ta.cStride = 131072;
      ta.M = 512; ta.N = 250; ta.Kreal = 512; ta.lda = 512; ta.ldb = 512; ta.ldc = 256;
      bgemm_k<false, 3><<<dim3(4, 2, 128), 256, 0, stream>>>(ta);
      BGemmArgs aa{};   // out = relu(res + corr @ trans)
      aa.A = corrbf; aa.B = transT;
      aa.aStride = 64000; aa.bStride = 131072; aa.cStride = 128000;
      aa.c2Stride = 128000; aa.rStride = 128000;
      aa.M = 250; aa.N = 512; aa.Kreal = 256; aa.lda = 256; aa.ldb = 256; aa.ldc = 512;
      if (layer == 0) {   // res = pre-GCN node (bf16); out -> f32 tmpF + bf16 tmpbf
        aa.Res = nbf; aa.C = tmpF; aa.C2 = tmpbf;
        bgemm_k<false, 2><<<dim3(2, 4, 128), 256, 0, stream>>>(aa);
      } else {            // res = tmpF (f32); out -> tmpF in-place (f32 for pooling)
        aa.Res = tmpF; aa.C = tmpF; aa.C2 = dump;
        bgemm_k<false, 4><<<dim3(2, 4, 128), 256, 0, stream>>>(aa);
      }
    }
    rep_k<<<dim3(128), 256, 0, stream>>>(tmpF, s ? wS : wT, rep + (long)s * 128 * 512);
  }

  final_k<<<dim3(128), 256, 0, stream>>>(rep, linW, linb, out);
}

// Round 11
// 1736.344 us; speedup vs baseline: 24.9264x; 1.1034x over previous
//
#include <hip/hip_runtime.h>
#include <hip/hip_bf16.h>

namespace {

constexpr int B_  = 128;
constexpr int TL  = 50, CL = 200, NNODE = 250;
constexpr int H_  = 256, D_ = 512;
constexpr long NODE_ELE = 128L * 250 * 512;   // per side

typedef __attribute__((ext_vector_type(8))) short bf16x8;
typedef __attribute__((ext_vector_type(4))) float f32x4;

__device__ inline float bits2f(unsigned v) { union { unsigned u; float f; } c; c.u = v; return c.f; }
__device__ inline unsigned f2bits(float x) { union { float f; unsigned u; } c; c.f = x; return c.u; }
__device__ inline unsigned short bfbits(float x) {
  __hip_bfloat16 b = __float2bfloat16(x);
  return *(unsigned short*)&b;
}
__device__ inline float bfsel(uint2 v, int r) {        // r-th bf16 of a 4-pack
  unsigned w = (r < 2) ? v.x : v.y;
  return bits2f((r & 1) ? (w & 0xFFFF0000u) : (w << 16));
}
__device__ inline float sigf(float x)  { return 1.f / (1.f + __expf(-x)); }
__device__ inline float tanhf_(float x){ return 1.f - 2.f / (__expf(2.f * x) + 1.f); }

// =============== bf16 MFMA GEMM: C[z] = A[za] @ B[z]^T (B is [N][K]) ==========
// za = z >> zShiftA (per-side weights at zShiftA=7). OUT modes:
// 0: f32 out. 1: +bias -> bf16. 3: bf16 out, zero-fill cols [N,256).
// 5: +bf16 Res, relu -> bf16 out.
struct BGemmArgs {
  const __hip_bfloat16* A; const __hip_bfloat16* B;
  const int* idx; const float* bias; const __hip_bfloat16* Res;
  void* C;
  long aStride, bStride, biasStride, cStride, rStride;
  int M, N, Kreal, lda, ldb, ldc, zShiftA;
};

template<bool GATHER, int OUT>
__global__ __launch_bounds__(256) void bgemm_k(BGemmArgs g) {
  __shared__ __align__(16) __hip_bfloat16 As[128 * 64];   // [r][k] XOR-swizzled
  __shared__ __align__(16) __hip_bfloat16 Bs[128 * 64];
  const int z = blockIdx.z;
  const int m0 = blockIdx.x * 128, n0 = blockIdx.y * 128;
  const int tid = threadIdx.x;
  const int lane = tid & 63, wv = tid >> 6;
  const int wr = wv >> 1, wc = wv & 1;                    // wave -> 64x64 quadrant
  const __hip_bfloat16* Ab = GATHER ? g.A : g.A + (long)(z >> g.zShiftA) * g.aStride;
  const __hip_bfloat16* Bb = g.B + (long)z * g.bStride;
  const int sr = tid >> 3, so = tid & 7;                  // staging: row, col-octet
  f32x4 acc[4][4];
  #pragma unroll
  for (int i = 0; i < 4; ++i)
    #pragma unroll
    for (int j = 0; j < 4; ++j) acc[i][j] = (f32x4){0.f, 0.f, 0.f, 0.f};

  const int ktiles = (g.Kreal + 63) >> 6;
  for (int kt = 0; kt < ktiles; ++kt) {
    const int k0 = kt * 64;
    __syncthreads();
    #pragma unroll
    for (int p = 0; p < 4; ++p) {           // A tile 128x64
      int r = p * 32 + sr;
      int row = m0 + r;
      int kg = k0 + so * 8;
      uint4 v = make_uint4(0, 0, 0, 0);
      if (row < g.M && kg + 8 <= g.Kreal) {
        long ao = GATHER ? (long)g.idx[row] * g.lda : (long)row * g.lda;
        v = *(const uint4*)(Ab + ao + kg);
      }
      *(uint4*)((char*)As + ((r * 128 + so * 16) ^ ((r & 7) << 4))) = v;
    }
    #pragma unroll
    for (int p = 0; p < 4; ++p) {           // B tile 128x64 (rows = n)
      int r = p * 32 + sr;
      int row = n0 + r;
      int kg = k0 + so * 8;
      uint4 v = make_uint4(0, 0, 0, 0);
      if (row < g.N && kg + 8 <= g.Kreal)
        v = *(const uint4*)(Bb + (long)row * g.ldb + kg);
      *(uint4*)((char*)Bs + ((r * 128 + so * 16) ^ ((r & 7) << 4))) = v;
    }
    __syncthreads();
    #pragma unroll
    for (int ks = 0; ks < 2; ++ks) {
      bf16x8 af[4], bfr[4];
      #pragma unroll
      for (int i = 0; i < 4; ++i) {
        int ra = wr * 64 + i * 16 + (lane & 15);
        af[i] = *(const bf16x8*)((const char*)As +
                 ((ra * 128 + ks * 64 + (lane >> 4) * 16) ^ ((ra & 7) << 4)));
        int rb = wc * 64 + i * 16 + (lane & 15);
        bfr[i] = *(const bf16x8*)((const char*)Bs +
                 ((rb * 128 + ks * 64 + (lane >> 4) * 16) ^ ((rb & 7) << 4)));
      }
      #pragma unroll
      for (int i = 0; i < 4; ++i)
        #pragma unroll
        for (int j = 0; j < 4; ++j)
          acc[i][j] = __builtin_amdgcn_mfma_f32_16x16x32_bf16(af[i], bfr[j], acc[i][j], 0, 0, 0);
    }
  }
  // ---- epilogue: D col = lane&15 (n), row = (lane>>4)*4 + r (m) ----
  const long cz = (long)z * g.cStride;
  #pragma unroll
  for (int i = 0; i < 4; ++i) {
    int rbase = m0 + wr * 64 + i * 16 + ((lane >> 4) << 2);
    #pragma unroll
    for (int j = 0; j < 4; ++j) {
      int col = n0 + wc * 64 + j * 16 + (lane & 15);
      #pragma unroll
      for (int r = 0; r < 4; ++r) {
        int row = rbase + r;
        float v = acc[i][j][r];
        if (OUT == 0) {
          if (row < g.M && col < g.N)
            ((float*)g.C)[cz + (long)row * g.ldc + col] = v;
        } else if (OUT == 1) {
          if (row < g.M && col < g.N) {
            v += g.bias[(long)z * g.biasStride + col];
            ((__hip_bfloat16*)g.C)[cz + (long)row * g.ldc + col] = __float2bfloat16(v);
          }
        } else if (OUT == 3) {
          if (row < g.M)
            ((__hip_bfloat16*)g.C)[cz + (long)row * g.ldc + col] =
                __float2bfloat16(col < g.N ? v : 0.f);
        } else {  // OUT == 5: +bf16 res, relu, bf16 out
          if (row < g.M && col < g.N) {
            v += __bfloat162float(g.Res[(long)z * g.rStride + (long)row * g.ldc + col]);
            v = fmaxf(v, 0.f);
            ((__hip_bfloat16*)g.C)[cz + (long)row * g.ldc + col] = __float2bfloat16(v);
          }
        }
      }
    }
  }
}

// ---------------- fused prep: whh/gcnW/emb/wih -> bf16(+pad), biasC ----------
struct PrepArgs {
  const float* whh[4];    // tgt, tgc, sgt, sgc (each [2][768][256])
  const float* gcnW[2];   // task, shared (each [2][512][512])
  const float* emb;       // [30000][300]
  const float* wih[4];    // each [2][768][300]
  const float* bih[4];
  const float* bhh[4];
  __hip_bfloat16 *whhbf, *gcnWbf, *embbf;
  __hip_bfloat16* wihbf[4];
  float* biasC;           // [4][2][768]
};

constexpr long PR0 = 1572864;            // whh
constexpr long PR1 = PR0 + 1048576;      // gcnW
constexpr long PR2 = PR1 + 9120000;      // emb pad 304
constexpr long PR3 = PR2 + 1867776;      // wih pad 304 (4x 466944)
constexpr long PR4 = PR3 + 6144;         // biasC

__global__ __launch_bounds__(256) void prep_k(PrepArgs a) {
  long i = (long)blockIdx.x * 256 + threadIdx.x;
  if (i >= PR4) return;
  if (i < PR0) {
    int zz = (int)(i / 196608);
    long rem = i - (long)zz * 196608;
    a.whhbf[i] = __float2bfloat16(a.whh[zz >> 1][(long)(zz & 1) * 196608 + rem]);
  } else if (i < PR1) {
    long j = i - PR0;
    a.gcnWbf[j] = __float2bfloat16(a.gcnW[j / 524288][j % 524288]);
  } else if (i < PR2) {
    long j = i - PR1;
    long r = j / 304;
    int c = (int)(j - r * 304);
    a.embbf[j] = __float2bfloat16(c < 300 ? a.emb[r * 300 + c] : 0.f);
  } else if (i < PR3) {
    long j = i - PR2;
    int w = (int)(j / 466944);
    long k = j - (long)w * 466944;
    long r = k / 304;
    int c = (int)(k - r * 304);
    a.wihbf[w][k] = __float2bfloat16(c < 300 ? a.wih[w][r * 300 + c] : 0.f);
  } else {
    long j = i - PR3;
    int w = (int)(j / 1536);
    int k = (int)(j - (long)w * 1536);
    a.biasC[(long)w * 1536 + k] = a.bih[w][k] + ((k % 768) < 512 ? a.bhh[w][k] : 0.f);
  }
}

// ---------------- GRU recurrence: MFMA persistent-RNN, ALL 8 chains ----------
// grid (8,1,8): z = side*4 + sq*2 + dir; blockIdx.x = 16-batch group (64 blocks).
// h in f32 regs; bf16 h mirror in swizzled LDS for MFMA. gi streamed via
// global_load_lds (double-buffered, source-side XOR swizzle); counted vmcnt(2)
// end-of-step drain -> barrier gives cross-wave visibility; stores stay in
// flight. One barrier per step.
struct RecArgs {
  const __hip_bfloat16* whhbf;    // [8][768][256], z = side*4+sq*2+dir
  const __hip_bfloat16* gi[4];    // {task_t, task_c, shared_t, shared_c}
  const float* bhh[4];
  __hip_bfloat16* nodebf;         // [2][128][250][512]
};

__global__ __launch_bounds__(512, 2) void gru_rec_k(RecArgs a) {
  __shared__ __align__(16) char hbuf[2][8192];    // [buf][batch16][k256] bf16, swz
  __shared__ __align__(16) char gib[2][24576];    // [buf][batch16][768] bf16, swz
  const int z = blockIdx.z;
  const int side = z >> 2, sq = (z >> 1) & 1, dir = z & 1;
  const int gidx = side * 2 + sq;
  const int T = sq ? CL : TL;
  const int toff = sq ? TL : 0;
  const __hip_bfloat16* gi = a.gi[gidx] + (long)dir * B_ * T * 768;
  const float* bhh = a.bhh[gidx] + dir * 768;
  const __hip_bfloat16* whh = a.whhbf + (long)z * 768 * 256;
  __hip_bfloat16* nodeb = a.nodebf + (long)side * NODE_ELE;
  const int b0 = blockIdx.x * 16;
  const int tid = threadIdx.x;
  const int lane = tid & 63, wv = tid >> 6;
  const int bcol = lane & 15, g4 = lane >> 4;
  const int u0 = wv * 32 + g4 * 4;
  const int swzh = (bcol & 15) << 4;   // h-buffer swizzle (512B rows)
  const int swzg = (bcol & 7) << 4;    // gi-buffer swizzle (1536B rows)

  bf16x8 Af[3][2][8];
  #pragma unroll
  for (int g = 0; g < 3; ++g)
    #pragma unroll
    for (int h = 0; h < 2; ++h)
      #pragma unroll
      for (int kt = 0; kt < 8; ++kt) {
        int row = g * 256 + wv * 32 + h * 16 + bcol;
        int col = kt * 32 + g4 * 8;
        Af[g][h][kt] = *(const bf16x8*)(whh + (long)row * 256 + col);
      }
  *(uint4*)&hbuf[0][tid * 16] = make_uint4(0, 0, 0, 0);
  const float4 bn0 = *(const float4*)&bhh[512 + u0];
  const float4 bn1 = *(const float4*)&bhh[512 + u0 + 16];

  // ---- gi loader: 3 x 16B chunks per thread; source pre-swizzled (rule 21) --
  const __hip_bfloat16* gsrc[3];
  int ldsoff[3];
  #pragma unroll
  for (int c2 = 0; c2 < 3; ++c2) {
    int pch = tid + c2 * 512;            // 0..1535
    int batch = pch / 96;
    int kch = pch - batch * 96;
    int colel = 8 * (kch ^ (batch & 7));
    gsrc[c2] = gi + ((long)(b0 + batch) * T + (dir ? T - 1 : 0)) * 768 + colel;
    ldsoff[c2] = pch * 16;
  }
  #pragma unroll
  for (int c2 = 0; c2 < 3; ++c2)
    __builtin_amdgcn_global_load_lds(
        (const __attribute__((address_space(1))) unsigned*)gsrc[c2],
        (__attribute__((address_space(3))) unsigned*)(&gib[0][0] + ldsoff[c2]),
        16, 0, 0);
  const long gistep = dir ? -768L : 768L;
  #pragma unroll
  for (int c2 = 0; c2 < 3; ++c2) gsrc[c2] += gistep;
  asm volatile("s_waitcnt vmcnt(0)" ::: "memory");
  __syncthreads();                        // hbuf[0] + gib[0] ready

  __hip_bfloat16* np = nodeb + ((long)(b0 + bcol) * NNODE + toff + (dir ? T - 1 : 0)) * D_
                       + dir * H_ + u0;
  const long nstep = (dir ? -(long)D_ : (long)D_);
  int cur = 0;

  float hreg[2][4];
  #pragma unroll
  for (int h = 0; h < 2; ++h)
    #pragma unroll
    for (int r = 0; r < 4; ++r) hreg[h][r] = 0.f;

  for (int t = 0; t < T; ++t) {
    // ---- issue gi loads for t+1 into gib[cur^1] (drain at step end) ----
    {
      char* gdst = &gib[cur ^ 1][0];
      #pragma unroll
      for (int c2 = 0; c2 < 3; ++c2)
        __builtin_amdgcn_global_load_lds(
            (const __attribute__((address_space(1))) unsigned*)gsrc[c2],
            (__attribute__((address_space(3))) unsigned*)(gdst + ldsoff[c2]),
            16, 0, 0);
      #pragma unroll
      for (int c2 = 0; c2 < 3; ++c2) gsrc[c2] += gistep;   // last-step overrun stays in d_ws
    }

    // ---- MFMA: gates for (32 units) x (16 batch), bf16 h ----
    const char* hib = &hbuf[cur][0];
    f32x4 c[3][2];
    #pragma unroll
    for (int g = 0; g < 3; ++g)
      #pragma unroll
      for (int h = 0; h < 2; ++h) c[g][h] = (f32x4){0.f, 0.f, 0.f, 0.f};
    const int rb = bcol * 512 + g4 * 16;
    #pragma unroll
    for (int kt = 0; kt < 8; ++kt) {
      bf16x8 bh = *(const bf16x8*)(hib + ((rb + kt * 64) ^ swzh));
      #pragma unroll
      for (int g = 0; g < 3; ++g)
        #pragma unroll
        for (int h = 0; h < 2; ++h)
          c[g][h] = __builtin_amdgcn_mfma_f32_16x16x32_bf16(Af[g][h][kt], bh, c[g][h], 0, 0, 0);
    }

    // ---- activation (gi from gib[cur]; guaranteed by prev step's vmcnt+barrier) ----
    const char* gic = &gib[cur][0];
    #pragma unroll
    for (int h = 0; h < 2; ++h) {
      int cb = bcol * 1536 + u0 * 2 + h * 32;
      uint2 gv0 = *(const uint2*)(gic + ((cb) ^ swzg));
      uint2 gv1 = *(const uint2*)(gic + ((cb + 512) ^ swzg));
      uint2 gv2 = *(const uint2*)(gic + ((cb + 1024) ^ swzg));
      float4 bn = h ? bn1 : bn0;
      #pragma unroll
      for (int r = 0; r < 4; ++r) {
        float bnv = (r == 0) ? bn.x : (r == 1) ? bn.y : (r == 2) ? bn.z : bn.w;
        float rr = sigf(bfsel(gv0, r) + c[0][h][r]);
        float zz = sigf(bfsel(gv1, r) + c[1][h][r]);
        float nn = tanhf_(bfsel(gv2, r) + rr * (c[2][h][r] + bnv));
        hreg[h][r] = (1.f - zz) * nn + zz * hreg[h][r];
      }
    }

    // ---- pack h -> bf16 (round-half-up); store to node + next h-buffer ----
    const int ob0 = bcol * 512 + u0 * 2;
    char* hibn = &hbuf[cur ^ 1][0];
    #pragma unroll
    for (int h = 0; h < 2; ++h) {
      unsigned hb[4];
      #pragma unroll
      for (int r = 0; r < 4; ++r)
        hb[r] = (f2bits(hreg[h][r]) + 0x8000u) & 0xFFFF0000u;
      uint2 hiw;
      hiw.x = (hb[0] >> 16) | hb[1];
      hiw.y = (hb[2] >> 16) | hb[3];
      *(uint2*)(np + h * 16) = hiw;                       // node (fire-and-forget)
      *(uint2*)(hibn + ((ob0 + h * 32) ^ swzh)) = hiw;    // next-step h
    }
    np += nstep;
    // drain this step's gi loads (issued at step start, a full step old);
    // allow the 2 node stores to stay in flight. lgkm: h writes visible.
    asm volatile("s_waitcnt vmcnt(2) lgkmcnt(0)" ::: "memory");
    __builtin_amdgcn_sched_barrier(0);
    __builtin_amdgcn_s_barrier();
    cur ^= 1;
  }
}

// ---------------- attention over claims (bf16 node, both sides) ----------------
__global__ __launch_bounds__(256) void attn_k(const __hip_bfloat16* nodeAll,
                                              float* wT, float* wS) {
  int b = blockIdx.x, side = blockIdx.y;
  const __hip_bfloat16* node = nodeAll + (long)side * NODE_ELE;
  float* w = side ? wS : wT;
  __shared__ float tl[512];
  __shared__ float sc[CL];
  int tid = threadIdx.x;
  {
    const __hip_bfloat16* tr = node + ((long)b * NNODE + (TL - 1)) * D_;
    tl[tid]       = __bfloat162float(tr[tid]);
    tl[tid + 256] = __bfloat162float(tr[tid + 256]);
  }
  __syncthreads();
  int wid = tid >> 6, lane = tid & 63;
  for (int c = wid; c < CL; c += 4) {
    const __hip_bfloat16* row = node + ((long)b * NNODE + TL + c) * D_;
    uint4 v = *(const uint4*)(row + lane * 8);
    const float* tp = &tl[lane * 8];
    float acc = bits2f(v.x << 16)         * tp[0] + bits2f(v.x & 0xFFFF0000u) * tp[1]
              + bits2f(v.y << 16)         * tp[2] + bits2f(v.y & 0xFFFF0000u) * tp[3]
              + bits2f(v.z << 16)         * tp[4] + bits2f(v.z & 0xFFFF0000u) * tp[5]
              + bits2f(v.w << 16)         * tp[6] + bits2f(v.w & 0xFFFF0000u) * tp[7];
    #pragma unroll
    for (int o = 32; o; o >>= 1) acc += __shfl_xor(acc, o, 64);
    if (lane == 0) sc[c] = acc;
  }
  __syncthreads();
  if (wid == 0) {
    float v[4]; float m = -1e30f;
    #pragma unroll
    for (int i = 0; i < 4; ++i) {
      int c = lane + 64 * i;
      v[i] = (c < CL) ? sc[c] : -1e30f;
      m = fmaxf(m, v[i]);
    }
    #pragma unroll
    for (int o = 32; o; o >>= 1) m = fmaxf(m, __shfl_xor(m, o, 64));
    float s = 0.f;
    #pragma unroll
    for (int i = 0; i < 4; ++i) {
      int c = lane + 64 * i;
      v[i] = (c < CL) ? expf(v[i] - m) : 0.f;
      s += v[i];
    }
    #pragma unroll
    for (int o = 32; o; o >>= 1) s += __shfl_xor(s, o, 64);
    float inv = 1.f / s;
    #pragma unroll
    for (int i = 0; i < 4; ++i) {
      int c = lane + 64 * i;
      if (c < CL) w[(long)b * CL + c] = v[i] * inv;
    }
  }
}

// ---------------- row softmax: f32 in (ld 256, len 250) -> bf16 out, 0-pad ----
__global__ __launch_bounds__(256) void softmaxbf_k(const float* in, __hip_bfloat16* out) {
  int row = blockIdx.x * 4 + (threadIdx.x >> 6);
  int lane = threadIdx.x & 63;
  const float* p = in + (long)row * 256;
  __hip_bfloat16* q = out + (long)row * 256;
  float v[4]; float m = -1e30f;
  #pragma unroll
  for (int i = 0; i < 4; ++i) {
    int c = lane + i * 64;
    v[i] = (c < 250) ? p[c] : -1e30f;
    m = fmaxf(m, v[i]);
  }
  #pragma unroll
  for (int o = 32; o; o >>= 1) m = fmaxf(m, __shfl_xor(m, o, 64));
  float s = 0.f;
  #pragma unroll
  for (int i = 0; i < 4; ++i) {
    int c = lane + i * 64;
    if (c < 250) { v[i] = __expf(v[i] - m); s += v[i]; }
  }
  #pragma unroll
  for (int o = 32; o; o >>= 1) s += __shfl_xor(s, o, 64);
  float inv = 1.f / s;
  #pragma unroll
  for (int i = 0; i < 4; ++i) {
    int c = lane + i * 64;
    q[c] = __float2bfloat16((c < 250) ? v[i] * inv : 0.f);
  }
}

// ---------------- weighted claim pooling (bf16 node, both sides) ----------------
__global__ __launch_bounds__(256) void rep_k(const __hip_bfloat16* nodeAll,
                                             const float* wT, const float* wS,
                                             float* rep) {
  int b = blockIdx.x, side = blockIdx.y;
  const __hip_bfloat16* node = nodeAll + (long)side * NODE_ELE;
  const float* w = side ? wS : wT;
  __shared__ float wl[CL];
  int tid = threadIdx.x;
  if (tid < CL) wl[tid] = w[(long)b * CL + tid];
  __syncthreads();
  #pragma unroll
  for (int h = 0; h < 2; ++h) {
    int d = tid + h * 256;
    float acc = 0.f;
    for (int c = 0; c < CL; ++c)
      acc = fmaf(wl[c], __bfloat162float(node[((long)b * NNODE + TL + c) * D_ + d]), acc);
    rep[((long)side * B_ + b) * D_ + d] = acc;
  }
}

// ---------------- final linear ----------------
__global__ __launch_bounds__(256) void final_k(const float* rep, const float* linW,
                                               const float* linb, float* out) {
  int b = blockIdx.x, tid = threadIdx.x;
  float a0 = 0.f, a1 = 0.f, a2 = 0.f;
  for (int d = tid; d < 1024; d += 256) {
    float x = rep[(long)(d >> 9) * (B_ * D_) + (long)b * D_ + (d & 511)];
    a0 = fmaf(x, linW[d], a0);
    a1 = fmaf(x, linW[1024 + d], a1);
    a2 = fmaf(x, linW[2048 + d], a2);
  }
  #pragma unroll
  for (int o = 32; o; o >>= 1) {
    a0 += __shfl_xor(a0, o, 64);
    a1 += __shfl_xor(a1, o, 64);
    a2 += __shfl_xor(a2, o, 64);
  }
  __shared__ float red[3][4];
  int wid = tid >> 6, lane = tid & 63;
  if (lane == 0) { red[0][wid] = a0; red[1][wid] = a1; red[2][wid] = a2; }
  __syncthreads();
  if (tid == 0) {
    out[b * 3 + 0] = red[0][0] + red[0][1] + red[0][2] + red[0][3] + linb[0];
    out[b * 3 + 1] = red[1][0] + red[1][1] + red[1][2] + red[1][3] + linb[1];
    out[b * 3 + 2] = red[2][0] + red[2][1] + red[2][2] + red[2][3] + linb[2];
  }
}

// ---------------- diagnostic ----------------
__global__ void diag_k(float* out, int n, float v) {
  int i = blockIdx.x * blockDim.x + threadIdx.x;
  if (i < n) out[i] = v;
}

} // namespace

extern "C" void kernel_launch(void* const* d_in, const int* in_sizes, int n_in,
                              void* d_out, int out_size, void* d_ws, size_t ws_size,
                              hipStream_t stream) {
  const int* task_target   = (const int*)d_in[1];
  const int* shared_target = (const int*)d_in[2];
  const int* task_claim    = (const int*)d_in[3];
  const int* shared_claim  = (const int*)d_in[4];
  const float* emb      = (const float*)d_in[9];
  const float* tgt_wih  = (const float*)d_in[10];
  const float* tgt_whh  = (const float*)d_in[11];
  const float* tgt_bih  = (const float*)d_in[12];
  const float* tgt_bhh  = (const float*)d_in[13];
  const float* tgc_wih  = (const float*)d_in[14];
  const float* tgc_whh  = (const float*)d_in[15];
  const float* tgc_bih  = (const float*)d_in[16];
  const float* tgc_bhh  = (const float*)d_in[17];
  const float* sgt_wih  = (const float*)d_in[18];
  const float* sgt_whh  = (const float*)d_in[19];
  const float* sgt_bih  = (const float*)d_in[20];
  const float* sgt_bhh  = (const float*)d_in[21];
  const float* sgc_wih  = (const float*)d_in[22];
  const float* sgc_whh  = (const float*)d_in[23];
  const float* sgc_bih  = (const float*)d_in[24];
  const float* sgc_bhh  = (const float*)d_in[25];
  const float* gcnW_task   = (const float*)d_in[26];
  const float* gcnW_shared = (const float*)d_in[27];
  const float* linW = (const float*)d_in[28];
  const float* linb = (const float*)d_in[29];
  float* out = (float*)d_out;

  // ---- workspace plan (bytes); total ~268.1 MB <= 256 MiB ----
  const size_t SZ_WHH   = 3145728;
  const size_t SZ_GCNW  = 2097152;
  const size_t SZ_BIASC = 24576;
  const size_t SZ_ARENA = 196608000;    // gi all 4 (phase A) / GCN scratch (phase B)
  const size_t SZ_NODE  = 65536000;     // 2 sides x 128x250x512 bf16
  const size_t SZ_W     = 102400;
  const size_t SZ_REP   = 524288;
  const size_t NEED = SZ_WHH + SZ_GCNW + SZ_BIASC + SZ_ARENA + SZ_NODE
                      + 2 * SZ_W + SZ_REP + 4096;

  if (ws_size < NEED) {
    diag_k<<<(out_size + 255) / 256, 256, 0, stream>>>(out, out_size,
                                                       (float)(ws_size >> 20));
    return;
  }

  char* p = (char*)d_ws;
  auto alloc = [&](size_t bytes) { char* r = p; p += (bytes + 255) & ~(size_t)255; return r; };
  __hip_bfloat16* whhbf  = (__hip_bfloat16*)alloc(SZ_WHH);
  __hip_bfloat16* gcnWbf = (__hip_bfloat16*)alloc(SZ_GCNW);   // [side][layer][512][512]
  float* biasC = (float*)alloc(SZ_BIASC);                     // [4][2][768]
  char* arena  = alloc(SZ_ARENA);
  char* nodeC  = alloc(SZ_NODE);
  float* wT    = (float*)alloc(SZ_W);
  float* wS    = (float*)alloc(SZ_W);
  float* rep   = (float*)alloc(SZ_REP);
  __hip_bfloat16* nodebf = (__hip_bfloat16*)nodeC;

  // phase-A views: gi for all 4 GRUs in arena; emb/wih conversions alias nodebf
  __hip_bfloat16* gi_tt = (__hip_bfloat16*)(arena);
  __hip_bfloat16* gi_tc = (__hip_bfloat16*)(arena + 19660800);
  __hip_bfloat16* gi_st = (__hip_bfloat16*)(arena + 98304000);
  __hip_bfloat16* gi_sc = (__hip_bfloat16*)(arena + 117964800);
  __hip_bfloat16* embbf = (__hip_bfloat16*)(nodeC);                  // [30000][304]
  __hip_bfloat16* wihbf[4] = {                                       // [2][768][304] each
    (__hip_bfloat16*)(nodeC + 18240000),
    (__hip_bfloat16*)(nodeC + 19173888),
    (__hip_bfloat16*)(nodeC + 20107776),
    (__hip_bfloat16*)(nodeC + 21041664)};
  // phase-B (GCN) views of arena, both sides fused (z = 0..255)
  __hip_bfloat16* tmpbf  = (__hip_bfloat16*)(arena);                 // [256][250][512]
  __hip_bfloat16* corrbf = (__hip_bfloat16*)(arena + 65536000);      // [256][250][256]
  float*          corrF  = (float*)(arena + 98304000);               // [256][250][256] f32
  __hip_bfloat16* transT = (__hip_bfloat16*)(arena + 98304000);      // aliases corrF (dead)

  // ---- fused prep (1 dispatch replaces 13) ----
  {
    PrepArgs pa;
    pa.whh[0] = tgt_whh; pa.whh[1] = tgc_whh; pa.whh[2] = sgt_whh; pa.whh[3] = sgc_whh;
    pa.gcnW[0] = gcnW_task; pa.gcnW[1] = gcnW_shared;
    pa.emb = emb;
    pa.wih[0] = tgt_wih; pa.wih[1] = tgc_wih; pa.wih[2] = sgt_wih; pa.wih[3] = sgc_wih;
    pa.bih[0] = tgt_bih; pa.bih[1] = tgc_bih; pa.bih[2] = sgt_bih; pa.bih[3] = sgc_bih;
    pa.bhh[0] = tgt_bhh; pa.bhh[1] = tgc_bhh; pa.bhh[2] = sgt_bhh; pa.bhh[3] = sgc_bhh;
    pa.whhbf = whhbf; pa.gcnWbf = gcnWbf; pa.embbf = embbf;
    pa.wihbf[0] = wihbf[0]; pa.wihbf[1] = wihbf[1];
    pa.wihbf[2] = wihbf[2]; pa.wihbf[3] = wihbf[3];
    pa.biasC = biasC;
    prep_k<<<(int)((PR4 + 255) / 256), 256, 0, stream>>>(pa);
  }

  // ---- projections: gi = emb[tok] @ Wih^T + biasC (bf16) ----
  auto proj = [&](const int* idx, __hip_bfloat16* wih, const float* bias,
                  __hip_bfloat16* gi, int Mrows, int gx) {
    BGemmArgs ga{};
    ga.A = embbf; ga.idx = idx; ga.B = wih; ga.bias = bias; ga.C = gi;
    ga.aStride = 0; ga.bStride = 768L * 304; ga.biasStride = 768;
    ga.cStride = (long)Mrows * 768; ga.zShiftA = 0;
    ga.M = Mrows; ga.N = 768; ga.Kreal = 304; ga.lda = 304; ga.ldb = 304; ga.ldc = 768;
    bgemm_k<true, 1><<<dim3(gx, 6, 2), 256, 0, stream>>>(ga);
  };
  proj(task_target,   wihbf[0], biasC,        gi_tt, 6400, 50);
  proj(task_claim,    wihbf[1], biasC + 1536, gi_tc, 25600, 200);
  proj(shared_target, wihbf[2], biasC + 3072, gi_st, 6400, 50);
  proj(shared_claim,  wihbf[3], biasC + 4608, gi_sc, 25600, 200);

  // ---- all 8 GRU chains in ONE dispatch (writes nodebf over emb/wih alias) ----
  RecArgs ra;
  ra.whhbf = whhbf;
  ra.gi[0] = gi_tt; ra.gi[1] = gi_tc; ra.gi[2] = gi_st; ra.gi[3] = gi_sc;
  ra.bhh[0] = tgt_bhh; ra.bhh[1] = tgc_bhh; ra.bhh[2] = sgt_bhh; ra.bhh[3] = sgc_bhh;
  ra.nodebf = nodebf;
  gru_rec_k<<<dim3(8, 1, 8), 512, 0, stream>>>(ra);

  // ---- stance attention, both sides ----
  attn_k<<<dim3(128, 2), 256, 0, stream>>>(nodebf, wT, wS);

  // ---- GCN 2 layers, BOTH sides fused (z = 0..255; side = z>>7) ----
  for (int layer = 0; layer < 2; ++layer) {
    const __hip_bfloat16* inbf = layer ? tmpbf : nodebf;   // z-contiguous across sides
    BGemmArgs ca{};   // corr = in @ in^T (f32)
    ca.A = inbf; ca.B = inbf; ca.C = corrF;
    ca.aStride = 128000; ca.bStride = 128000; ca.cStride = 64000; ca.zShiftA = 0;
    ca.M = 250; ca.N = 250; ca.Kreal = 512; ca.lda = 512; ca.ldb = 512; ca.ldc = 256;
    bgemm_k<false, 0><<<dim3(2, 2, 256), 256, 0, stream>>>(ca);
    softmaxbf_k<<<16000, 256, 0, stream>>>(corrF, corrbf);
    BGemmArgs ta{};   // trans^T = W[side] @ in^T (bf16, 0-pad cols 250..255)
    ta.A = gcnWbf + (long)layer * 262144; ta.B = inbf; ta.C = transT;
    ta.aStride = 524288; ta.bStride = 128000; ta.cStride = 131072; ta.zShiftA = 7;
    ta.M = 512; ta.N = 250; ta.Kreal = 512; ta.lda = 512; ta.ldb = 512; ta.ldc = 256;
    bgemm_k<false, 3><<<dim3(4, 2, 256), 256, 0, stream>>>(ta);
    BGemmArgs aa{};   // out = relu(res + corr @ trans), all bf16
    aa.A = corrbf; aa.B = transT; aa.Res = inbf;
    aa.C = layer ? (void*)nodebf : (void*)tmpbf;
    aa.aStride = 64000; aa.bStride = 131072; aa.cStride = 128000;
    aa.rStride = 128000; aa.zShiftA = 0;
    aa.M = 250; aa.N = 512; aa.Kreal = 256; aa.lda = 256; aa.ldb = 256; aa.ldc = 512;
    bgemm_k<false, 5><<<dim3(2, 4, 256), 256, 0, stream>>>(aa);
  }

  // ---- pooling (post-GCN node in nodebf), final linear ----
  rep_k<<<dim3(128, 2), 256, 0, stream>>>(nodebf, wT, wS, rep);
  final_k<<<dim3(128), 256, 0, stream>>>(rep, linW, linb, out);
}